// Round 1
// baseline (1931.717 us; speedup 1.0000x reference)
//
#include <hip/hip_runtime.h>
#include <math.h>

// ---------------- dims ----------------
constexpr int E_ = 128, H_ = 4, D_ = 32, F_ = 512, B_ = 64, CIN_ = 256, N_ = 257;
constexpr int M_ = B_ * N_;      // 16448 tokens
constexpr int MT_ = M_ / 16;     // 1028 m-tiles

typedef short short8 __attribute__((ext_vector_type(8)));
typedef float f32x4 __attribute__((ext_vector_type(4)));

__device__ inline short f2bs(float f) {  // float -> bf16 bits, RNE
    unsigned u = __builtin_bit_cast(unsigned, f);
    unsigned r = (u + 0x7fffu + ((u >> 16) & 1u)) >> 16;
    return (short)r;
}

__device__ inline f32x4 mfma16(short8 a, short8 b, f32x4 c) {
    return __builtin_amdgcn_mfma_f32_16x16x32_bf16(a, b, c, 0, 0, 0);
}

// ---------------- weight conversion ----------------
__global__ void cvt_all(const float* __restrict__ qkvw, const float* __restrict__ projw,
                        const float* __restrict__ f1w, const float* __restrict__ f2w,
                        short* __restrict__ oq, short* __restrict__ op,
                        short* __restrict__ o1, short* __restrict__ o2) {
    int i = blockIdx.x * 256 + threadIdx.x;            // grid covers 786432
    if (i < 589824) oq[i] = f2bs(qkvw[i]);
    if (i < 196608) op[i] = f2bs(projw[i]);
    if (i < 786432) { o1[i] = f2bs(f1w[i]); o2[i] = f2bs(f2w[i]); }
}

// conv_w (E,CIN,3,3) -> wr[e][(ky*3+kx)*256 + cin]  (bf16)
__global__ void conv_w_perm(const float* __restrict__ w, short* __restrict__ wr) {
    int i = blockIdx.x * 256 + threadIdx.x;            // 294912
    if (i >= 128 * 2304) return;
    int e = i / 2304, r = i % 2304;
    int kykx = r >> 8, cin = r & 255;
    int ky = kykx / 3, kx = kykx % 3;
    wr[i] = f2bs(w[((e * 256 + cin) * 3 + ky) * 3 + kx]);
}

// feat (B,CIN,32,32) fp32 -> fp[b][y+1][x+1][cin] bf16 (34x34 zero-padded border via memset)
__global__ __launch_bounds__(256) void feat_nhwc(const float* __restrict__ feat, short* __restrict__ fp) {
    __shared__ float tile[32][33];
    int b = blockIdx.x >> 5, y = blockIdx.x & 31;
    int t = threadIdx.x;
    for (int c0 = 0; c0 < 256; c0 += 32) {
        int ci = t >> 5, x = t & 31;
        for (int cc = ci; cc < 32; cc += 8)
            tile[cc][x] = feat[((size_t)(b * 256 + c0 + cc) * 32 + y) * 32 + x];
        __syncthreads();
        for (int i = t; i < 1024; i += 256) {
            int c = i & 31, x2 = i >> 5;
            fp[((size_t)(b * 34 + y + 1) * 34 + x2 + 1) * 256 + c0 + c] = f2bs(tile[c][x2]);
        }
        __syncthreads();
    }
}

// conv as GEMM: M=B*256 (tile = one (b,oy) row, 16 ox), N=128, K=2304
__global__ __launch_bounds__(256) void conv_gemm(const short* __restrict__ fp, const short* __restrict__ wr,
                                                 const float* __restrict__ cb, const float* __restrict__ pos,
                                                 float* __restrict__ X) {
    int gid = blockIdx.x * 4 + (threadIdx.x >> 6);     // 0..1023
    int lane = threadIdx.x & 63;
    int b = gid >> 4, oy = gid & 15;
    int lo = lane & 15, qd = lane >> 4;
    int ox = lo;
    f32x4 acc[8] = {};
    for (int kykx = 0; kykx < 9; ++kykx) {
        int ky = (kykx >= 6) ? 2 : ((kykx >= 3) ? 1 : 0);
        int kx = kykx - 3 * ky;
        const short* abase = fp + ((size_t)(b * 34 + 2 * oy + ky) * 34 + 2 * ox + kx) * 256 + qd * 8;
        const short* wbase = wr + kykx * 256 + qd * 8;
#pragma unroll
        for (int cs = 0; cs < 8; ++cs) {
            short8 af = *(const short8*)(abase + cs * 32);
#pragma unroll
            for (int t = 0; t < 8; ++t) {
                short8 bfv = *(const short8*)(wbase + (size_t)(t * 16 + lo) * 2304 + cs * 32);
                acc[t] = mfma16(af, bfv, acc[t]);
            }
        }
    }
#pragma unroll
    for (int t = 0; t < 8; ++t) {
        int e = t * 16 + lo;
        float bias = cb[e];
#pragma unroll
        for (int r = 0; r < 4; ++r) {
            int tok = 1 + oy * 16 + qd * 4 + r;
            X[((size_t)b * 257 + tok) * 128 + e] = acc[t][r] + bias + pos[tok * 128 + e];
        }
    }
}

__global__ void cls_init(const float* __restrict__ cls, const float* __restrict__ pos, float* __restrict__ X) {
    int i = blockIdx.x * 128 + threadIdx.x;            // 64*128
    int b = i >> 7, e = i & 127;
    X[(size_t)b * 257 * 128 + e] = cls[e] + pos[e];
}

// LayerNorm over E=128, wave per row, bf16 output
__global__ __launch_bounds__(256) void ln_rows(const float* __restrict__ X, const float* __restrict__ s,
                                               const float* __restrict__ bb, short* __restrict__ Hh, float eps) {
    int row = blockIdx.x * 4 + (threadIdx.x >> 6);
    int lane = threadIdx.x & 63;
    float2 v = *(const float2*)(X + (size_t)row * 128 + lane * 2);
    float sum = v.x + v.y;
#pragma unroll
    for (int m = 1; m < 64; m <<= 1) sum += __shfl_xor(sum, m);
    float mean = sum * (1.f / 128.f);
    float d0 = v.x - mean, d1 = v.y - mean;
    float vs = d0 * d0 + d1 * d1;
#pragma unroll
    for (int m = 1; m < 64; m <<= 1) vs += __shfl_xor(vs, m);
    float rs = rsqrtf(vs * (1.f / 128.f) + eps);
    int e = lane * 2;
    short2 o = make_short2(f2bs(d0 * rs * s[e] + bb[e]), f2bs(d1 * rs * s[e + 1] + bb[e + 1]));
    *(short2*)(Hh + (size_t)row * 128 + e) = o;
}

// GEMM: Out[M x Nn] = A(MxK) @ W(Nn x K)^T + bias.  MODE 0: bf16 out. 1: gelu->bf16. 2: fp32 X += .
template <int NT, int MODE>
__global__ __launch_bounds__(256) void gemm_bt(const short* __restrict__ A, const short* __restrict__ W,
                                               const float* __restrict__ bias, short* __restrict__ Ob,
                                               float* __restrict__ X, int K, int Nn) {
    int gid = blockIdx.x * 4 + (threadIdx.x >> 6);
    int lane = threadIdx.x & 63;
    int mt = gid % MT_;
    int ng = gid / MT_;
    int lo = lane & 15, qd = lane >> 4;
    int n0 = ng * NT * 16;
    const short* arow = A + (size_t)(mt * 16 + lo) * K + qd * 8;
    const short* wbase = W + (size_t)n0 * K + qd * 8;
    f32x4 acc[NT] = {};
    for (int kk = 0; kk < K; kk += 32) {
        short8 af = *(const short8*)(arow + kk);
#pragma unroll
        for (int t = 0; t < NT; ++t) {
            short8 bfv = *(const short8*)(wbase + (size_t)(t * 16 + lo) * K + kk);
            acc[t] = mfma16(af, bfv, acc[t]);
        }
    }
    int m0 = mt * 16 + qd * 4;
#pragma unroll
    for (int t = 0; t < NT; ++t) {
        int n = n0 + t * 16 + lo;
        float bv = bias[n];
#pragma unroll
        for (int r = 0; r < 4; ++r) {
            float v = acc[t][r] + bv;
            size_t idx = (size_t)(m0 + r) * Nn + n;
            if (MODE == 0) {
                Ob[idx] = f2bs(v);
            } else if (MODE == 1) {
                Ob[idx] = f2bs(0.5f * v * (1.f + erff(v * 0.70710678118654752f)));
            } else {
                X[idx] += v;
            }
        }
    }
}

// Fused attention per (b,h): K,V^T in LDS, scores in regs, softmax, P->LDS roundtrip, PV
__global__ __launch_bounds__(256) void attn(const short* __restrict__ qkv, short* __restrict__ O) {
    __shared__ __align__(16) short Kl[288 * 40];       // K row-major, padded stride 40
    __shared__ __align__(16) short Vt[32 * 296];       // V^T [d][key], stride 296
    __shared__ __align__(16) short Pl[4][16 * 296];    // per-wave P stage
    int b = blockIdx.x >> 2, h = blockIdx.x & 3;
    int tid = threadIdx.x;
    const short* base = qkv + (size_t)b * 257 * 384 + h * 32;
    for (int i = tid; i < 288 * 32; i += 256) {
        int key = i >> 5, d = i & 31;
        Kl[key * 40 + d] = (key < 257) ? base[(size_t)key * 384 + 128 + d] : (short)0;
    }
    for (int i = tid; i < 32 * 288; i += 256) {
        int d = i / 288, key = i - d * 288;
        Vt[d * 296 + key] = (key < 257) ? base[(size_t)key * 384 + 256 + d] : (short)0;
    }
    __syncthreads();
    int wave = tid >> 6, lane = tid & 63;
    int lo = lane & 15, qd = lane >> 4;
    const float scale = 0.17677669529663687f;          // 32^-0.5
    for (int it = 0; it < 5; ++it) {
        int qt = it * 4 + wave;
        bool owner = qt < 17;
        if (qt > 16) qt = 16;
        int q = qt * 16 + lo;
        short8 qf = {};
        if (q < 257) qf = *(const short8*)(base + (size_t)q * 384 + qd * 8);
        f32x4 sc[18];
#pragma unroll
        for (int kt = 0; kt < 18; ++kt) {
            short8 kf = *(const short8*)(&Kl[(kt * 16 + lo) * 40 + qd * 8]);
            f32x4 z = {};
            sc[kt] = mfma16(qf, kf, z);
        }
        float mx[4] = {-1e30f, -1e30f, -1e30f, -1e30f};
#pragma unroll
        for (int kt = 0; kt < 18; ++kt) {
            bool valid = (kt * 16 + lo) < 257;
#pragma unroll
            for (int r = 0; r < 4; ++r) {
                float v2 = valid ? sc[kt][r] * scale : -1e30f;
                sc[kt][r] = v2;
                mx[r] = fmaxf(mx[r], v2);
            }
        }
#pragma unroll
        for (int r = 0; r < 4; ++r) {
            mx[r] = fmaxf(mx[r], __shfl_xor(mx[r], 1));
            mx[r] = fmaxf(mx[r], __shfl_xor(mx[r], 2));
            mx[r] = fmaxf(mx[r], __shfl_xor(mx[r], 4));
            mx[r] = fmaxf(mx[r], __shfl_xor(mx[r], 8));
        }
        float l[4] = {0.f, 0.f, 0.f, 0.f};
#pragma unroll
        for (int kt = 0; kt < 18; ++kt)
#pragma unroll
            for (int r = 0; r < 4; ++r) {
                float p = __expf(sc[kt][r] - mx[r]);
                sc[kt][r] = p;
                l[r] += p;
            }
#pragma unroll
        for (int r = 0; r < 4; ++r) {
            l[r] += __shfl_xor(l[r], 1);
            l[r] += __shfl_xor(l[r], 2);
            l[r] += __shfl_xor(l[r], 4);
            l[r] += __shfl_xor(l[r], 8);
        }
        float rl[4];
#pragma unroll
        for (int r = 0; r < 4; ++r) rl[r] = 1.f / l[r];
#pragma unroll
        for (int kt = 0; kt < 18; ++kt)
#pragma unroll
            for (int r = 0; r < 4; ++r)
                Pl[wave][(qd * 4 + r) * 296 + kt * 16 + lo] = f2bs(sc[kt][r] * rl[r]);
        __syncthreads();
        f32x4 oa[2] = {};
#pragma unroll
        for (int ks = 0; ks < 9; ++ks) {
            short8 pf = *(const short8*)(&Pl[wave][lo * 296 + ks * 32 + qd * 8]);
#pragma unroll
            for (int nt = 0; nt < 2; ++nt) {
                short8 vf = *(const short8*)(&Vt[(nt * 16 + lo) * 296 + ks * 32 + qd * 8]);
                oa[nt] = mfma16(pf, vf, oa[nt]);
            }
        }
        __syncthreads();
        if (owner) {
#pragma unroll
            for (int nt = 0; nt < 2; ++nt)
#pragma unroll
                for (int r = 0; r < 4; ++r) {
                    int qq = qt * 16 + qd * 4 + r;
                    if (qq < 257)
                        O[((size_t)b * 257 + qq) * 128 + h * 32 + nt * 16 + lo] = f2bs(oa[nt][r]);
                }
        }
    }
}

// final LN (token 0 only, eps 1e-6) + fc head
__global__ __launch_bounds__(64) void final_head(const float* __restrict__ X, const float* __restrict__ fs,
                                                 const float* __restrict__ fb, const float* __restrict__ fcw,
                                                 const float* __restrict__ fcb, float* __restrict__ out) {
    int b = blockIdx.x, lane = threadIdx.x;
    float2 v = *(const float2*)(X + (size_t)b * 257 * 128 + lane * 2);
    float sum = v.x + v.y;
#pragma unroll
    for (int m = 1; m < 64; m <<= 1) sum += __shfl_xor(sum, m);
    float mean = sum * (1.f / 128.f);
    float d0 = v.x - mean, d1 = v.y - mean;
    float vs = d0 * d0 + d1 * d1;
#pragma unroll
    for (int m = 1; m < 64; m <<= 1) vs += __shfl_xor(vs, m);
    float rs = rsqrtf(vs * (1.f / 128.f) + 1e-6f);
    int e = lane * 2;
    float f0 = d0 * rs * fs[e] + fb[e];
    float f1 = d1 * rs * fs[e + 1] + fb[e + 1];
    out[128 + b * 128 + e] = f0;
    out[128 + b * 128 + e + 1] = f1;
    float p0 = f0 * fcw[e] + f1 * fcw[e + 1];
    float p1 = f0 * fcw[128 + e] + f1 * fcw[128 + e + 1];
#pragma unroll
    for (int m = 1; m < 64; m <<= 1) {
        p0 += __shfl_xor(p0, m);
        p1 += __shfl_xor(p1, m);
    }
    if (lane == 0) {
        out[b * 2 + 0] = p0 + fcb[0];
        out[b * 2 + 1] = p1 + fcb[1];
    }
}

extern "C" void kernel_launch(void* const* d_in, const int* in_sizes, int n_in,
                              void* d_out, int out_size, void* d_ws, size_t ws_size,
                              hipStream_t stream) {
    const float* feat    = (const float*)d_in[0];
    const float* conv_w  = (const float*)d_in[1];
    const float* conv_b  = (const float*)d_in[2];
    const float* pos_emb = (const float*)d_in[3];
    const float* cls_tok = (const float*)d_in[4];
    const float* ln1_s   = (const float*)d_in[5];
    const float* ln1_b   = (const float*)d_in[6];
    const float* qkv_w   = (const float*)d_in[7];
    const float* qkv_b   = (const float*)d_in[8];
    const float* proj_w  = (const float*)d_in[9];
    const float* proj_b  = (const float*)d_in[10];
    const float* ln2_s   = (const float*)d_in[11];
    const float* ln2_b   = (const float*)d_in[12];
    const float* ffn1_w  = (const float*)d_in[13];
    const float* ffn1_b  = (const float*)d_in[14];
    const float* ffn2_w  = (const float*)d_in[15];
    const float* ffn2_b  = (const float*)d_in[16];
    const float* fn_s    = (const float*)d_in[17];
    const float* fn_b    = (const float*)d_in[18];
    const float* fc_w    = (const float*)d_in[19];
    const float* fc_b    = (const float*)d_in[20];

    char* p = (char*)d_ws;
    auto alloc = [&](size_t bytes) { char* r = p; p += (bytes + 255) & ~(size_t)255; return r; };
    short* wq  = (short*)alloc((size_t)589824 * 2);
    short* wp  = (short*)alloc((size_t)196608 * 2);
    short* w1  = (short*)alloc((size_t)786432 * 2);
    short* w2  = (short*)alloc((size_t)786432 * 2);
    short* wc  = (short*)alloc((size_t)294912 * 2);
    short* fpd = (short*)alloc((size_t)64 * 34 * 34 * 256 * 2);
    float* X   = (float*)alloc((size_t)M_ * 128 * 4);
    short* Hb  = (short*)alloc((size_t)M_ * 128 * 2);
    short* QKV = (short*)alloc((size_t)M_ * 384 * 2);
    short* Ob  = (short*)alloc((size_t)M_ * 128 * 2);
    short* U   = (short*)alloc((size_t)M_ * 512 * 2);

    hipMemsetAsync(fpd, 0, (size_t)64 * 34 * 34 * 256 * 2, stream);
    cvt_all<<<3072, 256, 0, stream>>>(qkv_w, proj_w, ffn1_w, ffn2_w, wq, wp, w1, w2);
    conv_w_perm<<<1152, 256, 0, stream>>>(conv_w, wc);
    feat_nhwc<<<64 * 32, 256, 0, stream>>>(feat, fpd);
    conv_gemm<<<256, 256, 0, stream>>>(fpd, wc, conv_b, pos_emb, X);
    cls_init<<<64, 128, 0, stream>>>(cls_tok, pos_emb, X);

    for (int l = 0; l < 12; ++l) {
        ln_rows<<<4112, 256, 0, stream>>>(X, ln1_s + l * 128, ln1_b + l * 128, Hb, 1e-5f);
        gemm_bt<6, 0><<<1028, 256, 0, stream>>>(Hb, wq + (size_t)l * 384 * 128, qkv_b + l * 384, QKV, nullptr, 128, 384);
        attn<<<256, 256, 0, stream>>>(QKV, Ob);
        gemm_bt<2, 2><<<1028, 256, 0, stream>>>(Ob, wp + (size_t)l * 128 * 128, proj_b + l * 128, nullptr, X, 128, 128);
        ln_rows<<<4112, 256, 0, stream>>>(X, ln2_s + l * 128, ln2_b + l * 128, Hb, 1e-5f);
        gemm_bt<8, 1><<<1028, 256, 0, stream>>>(Hb, w1 + (size_t)l * 512 * 128, ffn1_b + l * 512, U, nullptr, 128, 512);
        gemm_bt<2, 2><<<1028, 256, 0, stream>>>(U, w2 + (size_t)l * 128 * 512, ffn2_b + l * 128, nullptr, X, 512, 128);
    }
    final_head<<<64, 64, 0, stream>>>(X, fn_s, fn_b, fc_w, fc_b, (float*)d_out);
}

// Round 2
// 1182.274 us; speedup vs baseline: 1.6339x; 1.6339x over previous
//
#include <hip/hip_runtime.h>
#include <math.h>

// ---------------- dims ----------------
constexpr int E_ = 128, H_ = 4, D_ = 32, F_ = 512, B_ = 64, CIN_ = 256, N_ = 257;
constexpr int M_ = B_ * N_;      // 16448 tokens
constexpr int MT_ = M_ / 16;     // 1028 m-tiles

typedef short short8 __attribute__((ext_vector_type(8)));
typedef float f32x4 __attribute__((ext_vector_type(4)));

__device__ inline short f2bs(float f) {  // float -> bf16 bits, RNE
    unsigned u = __builtin_bit_cast(unsigned, f);
    unsigned r = (u + 0x7fffu + ((u >> 16) & 1u)) >> 16;
    return (short)r;
}

__device__ inline f32x4 mfma16(short8 a, short8 b, f32x4 c) {
    return __builtin_amdgcn_mfma_f32_16x16x32_bf16(a, b, c, 0, 0, 0);
}

// ---------------- weight repack: W[l][n][k] fp32 -> packed [l][(k/8)][n][8] bf16 ----------------
__global__ void repack_w(const float* __restrict__ in, short* __restrict__ out, int Nn, int K, int total) {
    int o = blockIdx.x * 256 + threadIdx.x;
    if (o >= total) return;
    int per = Nn * K;
    int l = o / per, r = o % per;
    int chunk = r / (Nn * 8);
    int w = r % (Nn * 8);
    int n = w >> 3, j = w & 7;
    int k = chunk * 8 + j;
    out[o] = f2bs(in[(size_t)l * per + (size_t)n * K + k]);
}

// conv_w (E,CIN,3,3) -> packed [(kykx*8+cs)*4+qd][col 0..127][j 0..7], k = cs*32+qd*8+j over cin
__global__ void conv_w_perm(const float* __restrict__ w, short* __restrict__ wr) {
    int o = blockIdx.x * 256 + threadIdx.x;            // 294912
    if (o >= 128 * 2304) return;
    int j = o & 7;
    int col = (o >> 3) & 127;
    int c = o >> 10;                                   // 0..287
    int qd = c & 3, cscb = c >> 2;
    int cs = cscb & 7, kykx = cscb >> 3;
    int cin = cs * 32 + qd * 8 + j;
    int ky = kykx / 3, kx = kykx % 3;
    wr[o] = f2bs(w[((col * 256 + cin) * 3 + ky) * 3 + kx]);
}

// feat (B,CIN,32,32) fp32 -> fp[b][y+1][x+1][cin] bf16 (34x34 zero-padded border via memset)
__global__ __launch_bounds__(256) void feat_nhwc(const float* __restrict__ feat, short* __restrict__ fp) {
    __shared__ float tile[32][33];
    int b = blockIdx.x >> 5, y = blockIdx.x & 31;
    int t = threadIdx.x;
    for (int c0 = 0; c0 < 256; c0 += 32) {
        int ci = t >> 5, x = t & 31;
        for (int cc = ci; cc < 32; cc += 8)
            tile[cc][x] = feat[((size_t)(b * 256 + c0 + cc) * 32 + y) * 32 + x];
        __syncthreads();
        for (int i = t; i < 1024; i += 256) {
            int c = i & 31, x2 = i >> 5;
            fp[((size_t)(b * 34 + y + 1) * 34 + x2 + 1) * 256 + c0 + c] = f2bs(tile[c][x2]);
        }
        __syncthreads();
    }
}

// conv as GEMM: block = (b, oy); wave = ng over 32 cols; M-tile = 16 ox
__global__ __launch_bounds__(256) void conv_gemm(const short* __restrict__ fp, const short* __restrict__ wr,
                                                 const float* __restrict__ cb, const float* __restrict__ pos,
                                                 float* __restrict__ X) {
    int b = blockIdx.x >> 4, oy = blockIdx.x & 15;
    int wave = threadIdx.x >> 6, lane = threadIdx.x & 63;
    int ng = wave, lo = lane & 15, qd = lane >> 4;
    f32x4 acc[2] = {};
#pragma unroll
    for (int ky = 0; ky < 3; ++ky)
#pragma unroll
        for (int kx = 0; kx < 3; ++kx) {
            const short* ab = fp + ((size_t)(b * 34 + 2 * oy + ky) * 34 + 2 * lo + kx) * 256 + qd * 8;
            const short* wb = wr + (((size_t)((ky * 3 + kx) * 32) + qd) * 128 + ng * 32 + lo) * 8;
#pragma unroll
            for (int cs = 0; cs < 8; ++cs) {
                short8 af = *(const short8*)(ab + cs * 32);
                short8 b0 = *(const short8*)(wb + cs * 4096);
                short8 b1 = *(const short8*)(wb + cs * 4096 + 128);
                acc[0] = mfma16(af, b0, acc[0]);
                acc[1] = mfma16(af, b1, acc[1]);
            }
        }
#pragma unroll
    for (int t = 0; t < 2; ++t) {
        int e = ng * 32 + t * 16 + lo;
        float bias = cb[e];
#pragma unroll
        for (int r = 0; r < 4; ++r) {
            int tok = 1 + oy * 16 + qd * 4 + r;
            X[((size_t)b * 257 + tok) * 128 + e] = acc[t][r] + bias + pos[tok * 128 + e];
        }
    }
}

__global__ void cls_init(const float* __restrict__ cls, const float* __restrict__ pos, float* __restrict__ X) {
    int i = blockIdx.x * 128 + threadIdx.x;            // 64*128
    int b = i >> 7, e = i & 127;
    X[(size_t)b * 257 * 128 + e] = cls[e] + pos[e];
}

// GEMM with fused LayerNorm prologue: Out = postproc(LN(X) @ W^T + bias), K=128 fixed.
// VSPLIT: cols >= 256 (the V third of qkv) go transposed into Vg[b*128 + (n-256)][tok] (stride 264)
template <int NT, int GELU, int VSPLIT>
__global__ __launch_bounds__(256) void gemm_ln(const float* __restrict__ X, const short* __restrict__ W,
                                               const float* __restrict__ bias, const float* __restrict__ ls,
                                               const float* __restrict__ lb, short* __restrict__ Out,
                                               short* __restrict__ Vg, int Nn) {
    int gid = blockIdx.x * 4 + (threadIdx.x >> 6);
    int lane = threadIdx.x & 63;
    int mt = gid % MT_;
    int ng = gid / MT_;
    int lo = lane & 15, qd = lane >> 4;
    const float* xrow = X + (size_t)(mt * 16 + lo) * 128 + qd * 8;
    float v[4][8];
    float sum = 0.f;
#pragma unroll
    for (int ki = 0; ki < 4; ++ki) {
        float4 a = *(const float4*)(xrow + ki * 32);
        float4 bq = *(const float4*)(xrow + ki * 32 + 4);
        v[ki][0] = a.x; v[ki][1] = a.y; v[ki][2] = a.z; v[ki][3] = a.w;
        v[ki][4] = bq.x; v[ki][5] = bq.y; v[ki][6] = bq.z; v[ki][7] = bq.w;
        sum += a.x + a.y + a.z + a.w + bq.x + bq.y + bq.z + bq.w;
    }
    sum += __shfl_xor(sum, 16);
    sum += __shfl_xor(sum, 32);
    float mean = sum * (1.f / 128.f);
    float vs = 0.f;
#pragma unroll
    for (int ki = 0; ki < 4; ++ki)
#pragma unroll
        for (int j = 0; j < 8; ++j) {
            float d = v[ki][j] - mean;
            vs += d * d;
        }
    vs += __shfl_xor(vs, 16);
    vs += __shfl_xor(vs, 32);
    float rs = rsqrtf(vs * (1.f / 128.f) + 1e-5f);
    short8 af[4];
#pragma unroll
    for (int ki = 0; ki < 4; ++ki) {
        float4 s0 = *(const float4*)(ls + ki * 32 + qd * 8);
        float4 s1 = *(const float4*)(ls + ki * 32 + qd * 8 + 4);
        float4 b0 = *(const float4*)(lb + ki * 32 + qd * 8);
        float4 b1 = *(const float4*)(lb + ki * 32 + qd * 8 + 4);
        float sv[8] = {s0.x, s0.y, s0.z, s0.w, s1.x, s1.y, s1.z, s1.w};
        float bv[8] = {b0.x, b0.y, b0.z, b0.w, b1.x, b1.y, b1.z, b1.w};
#pragma unroll
        for (int j = 0; j < 8; ++j)
            af[ki][j] = f2bs((v[ki][j] - mean) * rs * sv[j] + bv[j]);
    }
    // K loop (K=128), packed B: index ((ki*4+qd)*Nn + n)*8
    f32x4 acc[NT] = {};
    const short* wb = W + ((size_t)qd * Nn + ng * NT * 16 + lo) * 8;
#pragma unroll
    for (int ki = 0; ki < 4; ++ki) {
        const short* wk = wb + (size_t)ki * 4 * Nn * 8;
#pragma unroll
        for (int t = 0; t < NT; ++t) {
            short8 bf = *(const short8*)(wk + t * 128);
            acc[t] = mfma16(af[ki], bf, acc[t]);
        }
    }
    int m0 = mt * 16 + qd * 4;
#pragma unroll
    for (int t = 0; t < NT; ++t) {
        int n = ng * NT * 16 + t * 16 + lo;
        float bv = bias[n];
#pragma unroll
        for (int r = 0; r < 4; ++r) {
            float x = acc[t][r] + bv;
            if (GELU) {
                float u = x * (0.7978845608f + 0.0356774081f * x * x);
                x = x / (1.f + __expf(-2.f * u));
            }
            int row = m0 + r;
            if (VSPLIT && n >= 256) {
                int bb = row / 257, tok = row % 257;
                Vg[(size_t)(bb * 128 + (n - 256)) * 264 + tok] = f2bs(x);
            } else {
                Out[(size_t)row * Nn + n] = f2bs(x);
            }
        }
    }
}

// GEMM + residual add: X[M x 128] += A(M x K) @ W(128 x K)^T + bias  (packed W)
template <int NT, int MB, int K>
__global__ __launch_bounds__(256) void gemm_add(const short* __restrict__ A, const short* __restrict__ W,
                                                const float* __restrict__ bias, float* __restrict__ X) {
    constexpr int MG = MT_ / MB;
    constexpr int Nn = 128;
    int gid = blockIdx.x * 4 + (threadIdx.x >> 6);
    int lane = threadIdx.x & 63;
    int mg = gid % MG, ng = gid / MG;
    int lo = lane & 15, qd = lane >> 4;
    const short* ar[MB];
#pragma unroll
    for (int m = 0; m < MB; ++m)
        ar[m] = A + (size_t)((mg * MB + m) * 16 + lo) * K + qd * 8;
    const short* wb = W + ((size_t)qd * Nn + ng * NT * 16 + lo) * 8;
    f32x4 acc[MB][NT] = {};
#pragma unroll 4
    for (int ki = 0; ki < K / 32; ++ki) {
        short8 af[MB];
#pragma unroll
        for (int m = 0; m < MB; ++m) af[m] = *(const short8*)(ar[m] + ki * 32);
        const short* wk = wb + (size_t)ki * 4 * Nn * 8;
#pragma unroll
        for (int t = 0; t < NT; ++t) {
            short8 bf = *(const short8*)(wk + t * 128);
#pragma unroll
            for (int m = 0; m < MB; ++m) acc[m][t] = mfma16(af[m], bf, acc[m][t]);
        }
    }
#pragma unroll
    for (int m = 0; m < MB; ++m) {
        int m0 = (mg * MB + m) * 16 + qd * 4;
#pragma unroll
        for (int t = 0; t < NT; ++t) {
            int n = ng * NT * 16 + t * 16 + lo;
            float bv = bias[n];
#pragma unroll
            for (int r = 0; r < 4; ++r)
                X[(size_t)(m0 + r) * Nn + n] += acc[m][t][r] + bv;
        }
    }
}

// Fused attention: block = (b, h, half); K rows + V^T (from Vg) staged in LDS; no inner barriers.
__global__ __launch_bounds__(256) void attn(const short* __restrict__ qkv, const short* __restrict__ Vg,
                                            short* __restrict__ O) {
    __shared__ __align__(16) short Kl[288 * 40];       // K row-major, stride 40
    __shared__ __align__(16) short Vt[32 * 296];       // V^T [d][key], stride 296
    __shared__ __align__(16) short Pl[4][16 * 296];    // per-wave P stage
    int b = blockIdx.x >> 3, r3 = blockIdx.x & 7;
    int h = r3 >> 1, half = r3 & 1;
    int tid = threadIdx.x;
    const short* base = qkv + (size_t)b * 257 * 384 + h * 32;
    const short* vgb = Vg + (size_t)(b * 4 + h) * 32 * 264;
    for (int i = tid; i < 288 * 4; i += 256) {         // K: vec8 loads
        int key = i >> 2, dc = i & 3;
        short8 val = {};
        if (key < 257) val = *(const short8*)(base + (size_t)key * 384 + 128 + dc * 8);
        *(short8*)(Kl + key * 40 + dc * 8) = val;
    }
    for (int i = tid; i < 32 * 37; i += 256) {         // V^T: coalesced vec8 from Vg
        int d = i / 37, c8 = i - d * 37;
        short8 val = {};
        if (c8 < 33) val = *(const short8*)(vgb + d * 264 + c8 * 8);
        *(short8*)(Vt + d * 296 + c8 * 8) = val;
    }
    __syncthreads();
    int wave = tid >> 6, lane = tid & 63;
    int lo = lane & 15, qd = lane >> 4;
    const float scale = 0.17677669529663687f;          // 32^-0.5
    for (int it = 0; it < 3; ++it) {
        int qt = it * 8 + half * 4 + wave;
        if (qt > 16) break;                            // wave-uniform
        int q = qt * 16 + lo;
        short8 qf = {};
        if (q < 257) qf = *(const short8*)(base + (size_t)q * 384 + qd * 8);
        f32x4 sc[18];
#pragma unroll
        for (int kt = 0; kt < 18; ++kt) {
            short8 kf = *(const short8*)(&Kl[(kt * 16 + lo) * 40 + qd * 8]);
            f32x4 z = {};
            sc[kt] = mfma16(qf, kf, z);
        }
        float mx[4] = {-1e30f, -1e30f, -1e30f, -1e30f};
#pragma unroll
        for (int kt = 0; kt < 18; ++kt) {
            bool valid = (kt * 16 + lo) < 257;
#pragma unroll
            for (int r = 0; r < 4; ++r) {
                float v2 = valid ? sc[kt][r] * scale : -1e30f;
                sc[kt][r] = v2;
                mx[r] = fmaxf(mx[r], v2);
            }
        }
#pragma unroll
        for (int r = 0; r < 4; ++r) {
            mx[r] = fmaxf(mx[r], __shfl_xor(mx[r], 1));
            mx[r] = fmaxf(mx[r], __shfl_xor(mx[r], 2));
            mx[r] = fmaxf(mx[r], __shfl_xor(mx[r], 4));
            mx[r] = fmaxf(mx[r], __shfl_xor(mx[r], 8));
        }
        float l[4] = {0.f, 0.f, 0.f, 0.f};
#pragma unroll
        for (int kt = 0; kt < 18; ++kt)
#pragma unroll
            for (int r = 0; r < 4; ++r) {
                float p = __expf(sc[kt][r] - mx[r]);
                sc[kt][r] = p;
                l[r] += p;
            }
#pragma unroll
        for (int r = 0; r < 4; ++r) {
            l[r] += __shfl_xor(l[r], 1);
            l[r] += __shfl_xor(l[r], 2);
            l[r] += __shfl_xor(l[r], 4);
            l[r] += __shfl_xor(l[r], 8);
        }
        float rl[4];
#pragma unroll
        for (int r = 0; r < 4; ++r) rl[r] = 1.f / l[r];
#pragma unroll
        for (int kt = 0; kt < 18; ++kt)
#pragma unroll
            for (int r = 0; r < 4; ++r)
                Pl[wave][(qd * 4 + r) * 296 + kt * 16 + lo] = f2bs(sc[kt][r] * rl[r]);
        f32x4 oa[2] = {};
#pragma unroll
        for (int ks = 0; ks < 9; ++ks) {
            short8 pf = *(const short8*)(&Pl[wave][lo * 296 + ks * 32 + qd * 8]);
#pragma unroll
            for (int nt = 0; nt < 2; ++nt) {
                short8 vf = *(const short8*)(&Vt[(nt * 16 + lo) * 296 + ks * 32 + qd * 8]);
                oa[nt] = mfma16(pf, vf, oa[nt]);
            }
        }
#pragma unroll
        for (int nt = 0; nt < 2; ++nt)
#pragma unroll
            for (int r = 0; r < 4; ++r) {
                int qq = qt * 16 + qd * 4 + r;
                if (qq < 257)
                    O[((size_t)b * 257 + qq) * 128 + h * 32 + nt * 16 + lo] = f2bs(oa[nt][r]);
            }
    }
}

// final LN (token 0 only, eps 1e-6) + fc head
__global__ __launch_bounds__(64) void final_head(const float* __restrict__ X, const float* __restrict__ fs,
                                                 const float* __restrict__ fb, const float* __restrict__ fcw,
                                                 const float* __restrict__ fcb, float* __restrict__ out) {
    int b = blockIdx.x, lane = threadIdx.x;
    float2 v = *(const float2*)(X + (size_t)b * 257 * 128 + lane * 2);
    float sum = v.x + v.y;
#pragma unroll
    for (int m = 1; m < 64; m <<= 1) sum += __shfl_xor(sum, m);
    float mean = sum * (1.f / 128.f);
    float d0 = v.x - mean, d1 = v.y - mean;
    float vs = d0 * d0 + d1 * d1;
#pragma unroll
    for (int m = 1; m < 64; m <<= 1) vs += __shfl_xor(vs, m);
    float rs = rsqrtf(vs * (1.f / 128.f) + 1e-6f);
    int e = lane * 2;
    float f0 = d0 * rs * fs[e] + fb[e];
    float f1 = d1 * rs * fs[e + 1] + fb[e + 1];
    out[128 + b * 128 + e] = f0;
    out[128 + b * 128 + e + 1] = f1;
    float p0 = f0 * fcw[e] + f1 * fcw[e + 1];
    float p1 = f0 * fcw[128 + e] + f1 * fcw[128 + e + 1];
#pragma unroll
    for (int m = 1; m < 64; m <<= 1) {
        p0 += __shfl_xor(p0, m);
        p1 += __shfl_xor(p1, m);
    }
    if (lane == 0) {
        out[b * 2 + 0] = p0 + fcb[0];
        out[b * 2 + 1] = p1 + fcb[1];
    }
}

extern "C" void kernel_launch(void* const* d_in, const int* in_sizes, int n_in,
                              void* d_out, int out_size, void* d_ws, size_t ws_size,
                              hipStream_t stream) {
    const float* feat    = (const float*)d_in[0];
    const float* conv_w  = (const float*)d_in[1];
    const float* conv_b  = (const float*)d_in[2];
    const float* pos_emb = (const float*)d_in[3];
    const float* cls_tok = (const float*)d_in[4];
    const float* ln1_s   = (const float*)d_in[5];
    const float* ln1_b   = (const float*)d_in[6];
    const float* qkv_w   = (const float*)d_in[7];
    const float* qkv_b   = (const float*)d_in[8];
    const float* proj_w  = (const float*)d_in[9];
    const float* proj_b  = (const float*)d_in[10];
    const float* ln2_s   = (const float*)d_in[11];
    const float* ln2_b   = (const float*)d_in[12];
    const float* ffn1_w  = (const float*)d_in[13];
    const float* ffn1_b  = (const float*)d_in[14];
    const float* ffn2_w  = (const float*)d_in[15];
    const float* ffn2_b  = (const float*)d_in[16];
    const float* fn_s    = (const float*)d_in[17];
    const float* fn_b    = (const float*)d_in[18];
    const float* fc_w    = (const float*)d_in[19];
    const float* fc_b    = (const float*)d_in[20];

    char* p = (char*)d_ws;
    auto alloc = [&](size_t bytes) { char* r = p; p += (bytes + 255) & ~(size_t)255; return r; };
    short* wq  = (short*)alloc((size_t)589824 * 2);
    short* wp  = (short*)alloc((size_t)196608 * 2);
    short* w1  = (short*)alloc((size_t)786432 * 2);
    short* w2  = (short*)alloc((size_t)786432 * 2);
    short* wc  = (short*)alloc((size_t)294912 * 2);
    short* fpd = (short*)alloc((size_t)64 * 34 * 34 * 256 * 2);
    float* X   = (float*)alloc((size_t)M_ * 128 * 4);
    short* QKV = (short*)alloc((size_t)M_ * 384 * 2);
    short* Vg  = (short*)alloc((size_t)64 * 128 * 264 * 2);
    short* Ob  = (short*)alloc((size_t)M_ * 128 * 2);
    short* U   = (short*)alloc((size_t)M_ * 512 * 2);

    hipMemsetAsync(fpd, 0, (size_t)64 * 34 * 34 * 256 * 2, stream);
    repack_w<<<2304, 256, 0, stream>>>(qkv_w, wq, 384, 128, 589824);
    repack_w<<<768, 256, 0, stream>>>(proj_w, wp, 128, 128, 196608);
    repack_w<<<3072, 256, 0, stream>>>(ffn1_w, w1, 512, 128, 786432);
    repack_w<<<3072, 256, 0, stream>>>(ffn2_w, w2, 128, 512, 786432);
    conv_w_perm<<<1152, 256, 0, stream>>>(conv_w, wc);
    feat_nhwc<<<64 * 32, 256, 0, stream>>>(feat, fpd);
    conv_gemm<<<1024, 256, 0, stream>>>(fpd, wc, conv_b, pos_emb, X);
    cls_init<<<64, 128, 0, stream>>>(cls_tok, pos_emb, X);

    for (int l = 0; l < 12; ++l) {
        gemm_ln<6, 0, 1><<<1028, 256, 0, stream>>>(X, wq + (size_t)l * 49152, qkv_b + l * 384,
                                                   ln1_s + l * 128, ln1_b + l * 128, QKV, Vg, 384);
        attn<<<512, 256, 0, stream>>>(QKV, Vg, Ob);
        gemm_add<4, 1, 128><<<514, 256, 0, stream>>>(Ob, wp + (size_t)l * 16384, proj_b + l * 128, X);
        gemm_ln<8, 1, 0><<<1028, 256, 0, stream>>>(X, w1 + (size_t)l * 65536, ffn1_b + l * 512,
                                                   ln2_s + l * 128, ln2_b + l * 128, U, nullptr, 512);
        gemm_add<4, 2, 512><<<257, 256, 0, stream>>>(U, w2 + (size_t)l * 65536, ffn2_b + l * 128, X);
    }
    final_head<<<64, 64, 0, stream>>>(X, fn_s, fn_b, fc_w, fc_b, (float*)d_out);
}

// Round 3
// 1117.696 us; speedup vs baseline: 1.7283x; 1.0578x over previous
//
#include <hip/hip_runtime.h>
#include <math.h>

// ---------------- dims ----------------
constexpr int E_ = 128, H_ = 4, D_ = 32, F_ = 512, B_ = 64, CIN_ = 256, N_ = 257;
constexpr int M_ = B_ * N_;      // 16448 tokens
constexpr int MT_ = M_ / 16;     // 1028 m-tiles

typedef short short8 __attribute__((ext_vector_type(8)));
typedef float f32x4 __attribute__((ext_vector_type(4)));

__device__ inline short f2bs(float f) {  // float -> bf16 bits, RNE
    unsigned u = __builtin_bit_cast(unsigned, f);
    unsigned r = (u + 0x7fffu + ((u >> 16) & 1u)) >> 16;
    return (short)r;
}

__device__ inline f32x4 mfma16(short8 a, short8 b, f32x4 c) {
    return __builtin_amdgcn_mfma_f32_16x16x32_bf16(a, b, c, 0, 0, 0);
}

// ---------------- weight repack: W[l][n][k] fp32 -> packed [l][(k/8)][n][8] bf16 ----------------
__global__ void repack_w(const float* __restrict__ in, short* __restrict__ out, int Nn, int K, int total) {
    int o = blockIdx.x * 256 + threadIdx.x;
    if (o >= total) return;
    int per = Nn * K;
    int l = o / per, r = o % per;
    int chunk = r / (Nn * 8);
    int w = r % (Nn * 8);
    int n = w >> 3, j = w & 7;
    int k = chunk * 8 + j;
    out[o] = f2bs(in[(size_t)l * per + (size_t)n * K + k]);
}

// conv_w (E,CIN,3,3) -> packed [(kykx*8+cs)*4+qd][col 0..127][j 0..7], k = cs*32+qd*8+j over cin
__global__ void conv_w_perm(const float* __restrict__ w, short* __restrict__ wr) {
    int o = blockIdx.x * 256 + threadIdx.x;            // 294912
    if (o >= 128 * 2304) return;
    int j = o & 7;
    int col = (o >> 3) & 127;
    int c = o >> 10;                                   // 0..287
    int qd = c & 3, cscb = c >> 2;
    int cs = cscb & 7, kykx = cscb >> 3;
    int cin = cs * 32 + qd * 8 + j;
    int ky = kykx / 3, kx = kykx % 3;
    wr[o] = f2bs(w[((col * 256 + cin) * 3 + ky) * 3 + kx]);
}

// feat (B,CIN,32,32) fp32 -> fp[b][y+1][x+1][cin] bf16 (34x34 zero-padded border via memset)
__global__ __launch_bounds__(256) void feat_nhwc(const float* __restrict__ feat, short* __restrict__ fp) {
    __shared__ float tile[32][33];
    int b = blockIdx.x >> 5, y = blockIdx.x & 31;
    int t = threadIdx.x;
    for (int c0 = 0; c0 < 256; c0 += 32) {
        int ci = t >> 5, x = t & 31;
        for (int cc = ci; cc < 32; cc += 8)
            tile[cc][x] = feat[((size_t)(b * 256 + c0 + cc) * 32 + y) * 32 + x];
        __syncthreads();
        for (int i = t; i < 1024; i += 256) {
            int c = i & 31, x2 = i >> 5;
            fp[((size_t)(b * 34 + y + 1) * 34 + x2 + 1) * 256 + c0 + c] = f2bs(tile[c][x2]);
        }
        __syncthreads();
    }
}

// conv as GEMM: block = (b, oy); 3 input rows staged in LDS (XOR-phase swizzle); wave = 32 cols
__global__ __launch_bounds__(256) void conv_gemm(const short* __restrict__ fp, const short* __restrict__ wr,
                                                 const float* __restrict__ cb, const float* __restrict__ pos,
                                                 float* __restrict__ X) {
    __shared__ __align__(16) short Ain[3 * 34 * 256];  // 51 KB
    int b = blockIdx.x >> 4, oy = blockIdx.x & 15;
    int tid = threadIdx.x;
    for (int idx = tid; idx < 3 * 34 * 32; idx += 256) {
        int r = idx / 1088, rem = idx - r * 1088;
        int x = rem >> 5, c = rem & 31;
        short8 v = *(const short8*)(fp + ((size_t)(b * 34 + 2 * oy + r) * 34 + x) * 256 + c * 8);
        *(short8*)(Ain + (r * 34 + x) * 256 + ((c ^ ((x >> 1) & 7)) * 8)) = v;
    }
    __syncthreads();
    int wave = tid >> 6, lane = tid & 63;
    int ng = wave, lo = lane & 15, qd = lane >> 4;
    f32x4 acc[2] = {};
#pragma unroll
    for (int ky = 0; ky < 3; ++ky)
#pragma unroll
        for (int kx = 0; kx < 3; ++kx) {
            int sx = 2 * lo + kx;
            int arow = (ky * 34 + sx) * 256;
            int sw = (sx >> 1) & 7;
            const short* wb = wr + (((size_t)((ky * 3 + kx) * 8) * 4 + qd) * 128 + ng * 32 + lo) * 8;
#pragma unroll
            for (int cs = 0; cs < 8; ++cs) {
                short8 af = *(const short8*)(Ain + arow + (((cs * 4 + qd) ^ sw) * 8));
                short8 b0 = *(const short8*)(wb + (size_t)cs * 4096);
                short8 b1 = *(const short8*)(wb + (size_t)cs * 4096 + 128);
                acc[0] = mfma16(af, b0, acc[0]);
                acc[1] = mfma16(af, b1, acc[1]);
            }
        }
#pragma unroll
    for (int t = 0; t < 2; ++t) {
        int e = ng * 32 + t * 16 + lo;
        float bias = cb[e];
#pragma unroll
        for (int r = 0; r < 4; ++r) {
            int tok = 1 + oy * 16 + qd * 4 + r;
            X[((size_t)b * 257 + tok) * 128 + e] = acc[t][r] + bias + pos[tok * 128 + e];
        }
    }
}

__global__ void cls_init(const float* __restrict__ cls, const float* __restrict__ pos, float* __restrict__ X) {
    int i = blockIdx.x * 128 + threadIdx.x;            // 64*128
    int b = i >> 7, e = i & 127;
    X[(size_t)b * 257 * 128 + e] = cls[e] + pos[e];
}

// Fused LN + GEMM, block = 64 tokens (4 m-tiles), grid = 257 * 2 (ng over N halves).
// MODE 0: qkv (row-major Out, V-split into Vg). MODE 1: ffn1 (gelu, fragment-layout Uf out).
template <int NT, int MODE>
__global__ __launch_bounds__(256) void gemm_ln4(const float* __restrict__ X, const short* __restrict__ W,
                                                const float* __restrict__ bias, const float* __restrict__ ls,
                                                const float* __restrict__ lb, short* __restrict__ Out,
                                                short* __restrict__ Vg, int Nn) {
    __shared__ __align__(16) float Xl[64 * 132];       // 33 KB, padded rows
    __shared__ __align__(16) short aF[4 * 16 * 16 * 8];// 16 KB fragment tile
    int mg = blockIdx.x % 257, ng = blockIdx.x / 257;
    int tid = threadIdx.x;
    for (int idx = tid; idx < 2048; idx += 256) {
        int tok = idx >> 5, c = idx & 31;
        *(float4*)(Xl + tok * 132 + c * 4) = *(const float4*)(X + (size_t)(mg * 64 + tok) * 128 + c * 4);
    }
    __syncthreads();
    int wave = tid >> 6, lane = tid & 63;
    int lo = lane & 15, qd = lane >> 4;
    const float* xr = Xl + (wave * 16 + lo) * 132 + qd * 8;
    float v[4][8];
    float sum = 0.f;
#pragma unroll
    for (int ki = 0; ki < 4; ++ki) {
        float4 a = *(const float4*)(xr + ki * 32);
        float4 bq = *(const float4*)(xr + ki * 32 + 4);
        v[ki][0] = a.x; v[ki][1] = a.y; v[ki][2] = a.z; v[ki][3] = a.w;
        v[ki][4] = bq.x; v[ki][5] = bq.y; v[ki][6] = bq.z; v[ki][7] = bq.w;
        sum += a.x + a.y + a.z + a.w + bq.x + bq.y + bq.z + bq.w;
    }
    sum += __shfl_xor(sum, 16);
    sum += __shfl_xor(sum, 32);
    float mean = sum * (1.f / 128.f);
    float vs = 0.f;
#pragma unroll
    for (int ki = 0; ki < 4; ++ki)
#pragma unroll
        for (int j = 0; j < 8; ++j) {
            float d = v[ki][j] - mean;
            vs += d * d;
        }
    vs += __shfl_xor(vs, 16);
    vs += __shfl_xor(vs, 32);
    float rs = rsqrtf(vs * (1.f / 128.f) + 1e-5f);
#pragma unroll
    for (int ki = 0; ki < 4; ++ki) {
        float4 s0 = *(const float4*)(ls + ki * 32 + qd * 8);
        float4 s1 = *(const float4*)(ls + ki * 32 + qd * 8 + 4);
        float4 b0 = *(const float4*)(lb + ki * 32 + qd * 8);
        float4 b1 = *(const float4*)(lb + ki * 32 + qd * 8 + 4);
        float sv[8] = {s0.x, s0.y, s0.z, s0.w, s1.x, s1.y, s1.z, s1.w};
        float bv[8] = {b0.x, b0.y, b0.z, b0.w, b1.x, b1.y, b1.z, b1.w};
        short8 af;
#pragma unroll
        for (int j = 0; j < 8; ++j)
            af[j] = f2bs((v[ki][j] - mean) * rs * sv[j] + bv[j]);
        *(short8*)(aF + ((wave * 16 + ki * 4 + qd) * 16 + lo) * 8) = af;
    }
    __syncthreads();
    int n0 = ng * (NT * 64) + wave * (NT * 16);
    f32x4 acc[4][NT] = {};
#pragma unroll
    for (int ki = 0; ki < 4; ++ki) {
        int kq = ki * 4 + qd;
        short8 bf[NT];
#pragma unroll
        for (int t = 0; t < NT; ++t)
            bf[t] = *(const short8*)(W + ((size_t)kq * Nn + n0 + t * 16 + lo) * 8);
#pragma unroll
        for (int mt = 0; mt < 4; ++mt) {
            short8 a = *(const short8*)(aF + ((mt * 16 + kq) * 16 + lo) * 8);
#pragma unroll
            for (int t = 0; t < NT; ++t) acc[mt][t] = mfma16(a, bf[t], acc[mt][t]);
        }
    }
#pragma unroll
    for (int mt = 0; mt < 4; ++mt) {
        int MT2 = mg * 4 + mt;
#pragma unroll
        for (int t = 0; t < NT; ++t) {
            int n = n0 + t * 16 + lo;
            float bv = bias[n];
#pragma unroll
            for (int r = 0; r < 4; ++r) {
                float x = acc[mt][t][r] + bv;
                int row = MT2 * 16 + qd * 4 + r;
                if (MODE == 1) {
                    float u = x * (0.7978845608f + 0.0356774081f * x * x);
                    x = x / (1.f + __expf(-2.f * u));
                    Out[(size_t)MT2 * 8192 + (n >> 3) * 128 + (qd * 4 + r) * 8 + (n & 7)] = f2bs(x);
                } else {
                    if (n >= 256) {
                        int bb = row / 257, tok = row % 257;
                        Vg[(size_t)(bb * 128 + (n - 256)) * 264 + tok] = f2bs(x);
                    } else {
                        Out[(size_t)row * Nn + n] = f2bs(x);
                    }
                }
            }
        }
    }
}

// GEMM over fragment-layout A + residual add: X[64 tok x 128] += A @ W^T + bias. Block = 64 tokens.
template <int K>
__global__ __launch_bounds__(256) void gemm_frag_add(const short* __restrict__ AF, const short* __restrict__ W,
                                                     const float* __restrict__ bias, float* __restrict__ X) {
    constexpr int KQ = K / 8;
    __shared__ __align__(16) short AL[4 * KQ * 16 * 8];
    int mg = blockIdx.x;
    const short* src = AF + (size_t)mg * (4 * KQ * 128);
    int tid = threadIdx.x;
    for (int idx = tid; idx < 4 * KQ * 16; idx += 256)
        *(short8*)(AL + idx * 8) = *(const short8*)(src + idx * 8);
    __syncthreads();
    int wave = tid >> 6, lane = tid & 63;
    int lo = lane & 15, qd = lane >> 4;
    int n = wave * 32;
    f32x4 acc[4][2] = {};
#pragma unroll 4
    for (int ki = 0; ki < KQ / 4; ++ki) {
        int kq = ki * 4 + qd;
        short8 b0 = *(const short8*)(W + ((size_t)kq * 128 + n + lo) * 8);
        short8 b1 = *(const short8*)(W + ((size_t)kq * 128 + n + 16 + lo) * 8);
#pragma unroll
        for (int mt = 0; mt < 4; ++mt) {
            short8 a = *(const short8*)(AL + ((mt * KQ + kq) * 16 + lo) * 8);
            acc[mt][0] = mfma16(a, b0, acc[mt][0]);
            acc[mt][1] = mfma16(a, b1, acc[mt][1]);
        }
    }
    float bv0 = bias[n + lo], bv1 = bias[n + 16 + lo];
#pragma unroll
    for (int mt = 0; mt < 4; ++mt) {
        int m0 = (mg * 4 + mt) * 16 + qd * 4;
#pragma unroll
        for (int r = 0; r < 4; ++r) {
            X[(size_t)(m0 + r) * 128 + n + lo] += acc[mt][0][r] + bv0;
            X[(size_t)(m0 + r) * 128 + n + 16 + lo] += acc[mt][1][r] + bv1;
        }
    }
}

// Fused attention: block = (b, h, half); K rows + V^T (from Vg) staged in LDS; O out in fragment layout.
__global__ __launch_bounds__(256) void attn(const short* __restrict__ qkv, const short* __restrict__ Vg,
                                            short* __restrict__ Of) {
    __shared__ __align__(16) short Kl[288 * 40];       // K row-major, stride 40
    __shared__ __align__(16) short Vt[32 * 296];       // V^T [d][key], stride 296
    __shared__ __align__(16) short Pl[4][16 * 296];    // per-wave P stage
    int b = blockIdx.x >> 3, r3 = blockIdx.x & 7;
    int h = r3 >> 1, half = r3 & 1;
    int tid = threadIdx.x;
    const short* base = qkv + (size_t)b * 257 * 384 + h * 32;
    const short* vgb = Vg + (size_t)(b * 4 + h) * 32 * 264;
    for (int i = tid; i < 288 * 4; i += 256) {         // K: vec8 loads
        int key = i >> 2, dc = i & 3;
        short8 val = {};
        if (key < 257) val = *(const short8*)(base + (size_t)key * 384 + 128 + dc * 8);
        *(short8*)(Kl + key * 40 + dc * 8) = val;
    }
    for (int i = tid; i < 32 * 37; i += 256) {         // V^T: coalesced vec8 from Vg
        int d = i / 37, c8 = i - d * 37;
        short8 val = {};
        if (c8 < 33) val = *(const short8*)(vgb + d * 264 + c8 * 8);
        *(short8*)(Vt + d * 296 + c8 * 8) = val;
    }
    __syncthreads();
    int wave = tid >> 6, lane = tid & 63;
    int lo = lane & 15, qd = lane >> 4;
    const float scale = 0.17677669529663687f;          // 32^-0.5
    for (int it = 0; it < 3; ++it) {
        int qt = it * 8 + half * 4 + wave;
        if (qt > 16) break;                            // wave-uniform
        int q = qt * 16 + lo;
        short8 qf = {};
        if (q < 257) qf = *(const short8*)(base + (size_t)q * 384 + qd * 8);
        f32x4 sc[18];
#pragma unroll
        for (int kt = 0; kt < 18; ++kt) {
            short8 kf = *(const short8*)(&Kl[(kt * 16 + lo) * 40 + qd * 8]);
            f32x4 z = {};
            sc[kt] = mfma16(qf, kf, z);
        }
        float mx[4] = {-1e30f, -1e30f, -1e30f, -1e30f};
#pragma unroll
        for (int kt = 0; kt < 18; ++kt) {
            bool valid = (kt * 16 + lo) < 257;
#pragma unroll
            for (int r = 0; r < 4; ++r) {
                float v2 = valid ? sc[kt][r] * scale : -1e30f;
                sc[kt][r] = v2;
                mx[r] = fmaxf(mx[r], v2);
            }
        }
#pragma unroll
        for (int r = 0; r < 4; ++r) {
            mx[r] = fmaxf(mx[r], __shfl_xor(mx[r], 1));
            mx[r] = fmaxf(mx[r], __shfl_xor(mx[r], 2));
            mx[r] = fmaxf(mx[r], __shfl_xor(mx[r], 4));
            mx[r] = fmaxf(mx[r], __shfl_xor(mx[r], 8));
        }
        float l[4] = {0.f, 0.f, 0.f, 0.f};
#pragma unroll
        for (int kt = 0; kt < 18; ++kt)
#pragma unroll
            for (int r = 0; r < 4; ++r) {
                float p = __expf(sc[kt][r] - mx[r]);
                sc[kt][r] = p;
                l[r] += p;
            }
#pragma unroll
        for (int r = 0; r < 4; ++r) {
            l[r] += __shfl_xor(l[r], 1);
            l[r] += __shfl_xor(l[r], 2);
            l[r] += __shfl_xor(l[r], 4);
            l[r] += __shfl_xor(l[r], 8);
        }
        float rl[4];
#pragma unroll
        for (int r = 0; r < 4; ++r) rl[r] = 1.f / l[r];
#pragma unroll
        for (int kt = 0; kt < 18; ++kt)
#pragma unroll
            for (int r = 0; r < 4; ++r)
                Pl[wave][(qd * 4 + r) * 296 + kt * 16 + lo] = f2bs(sc[kt][r] * rl[r]);
        f32x4 oa[2] = {};
#pragma unroll
        for (int ks = 0; ks < 9; ++ks) {
            short8 pf = *(const short8*)(&Pl[wave][lo * 296 + ks * 32 + qd * 8]);
#pragma unroll
            for (int nt = 0; nt < 2; ++nt) {
                short8 vf = *(const short8*)(&Vt[(nt * 16 + lo) * 296 + ks * 32 + qd * 8]);
                oa[nt] = mfma16(pf, vf, oa[nt]);
            }
        }
#pragma unroll
        for (int nt = 0; nt < 2; ++nt)
#pragma unroll
            for (int r = 0; r < 4; ++r) {
                int qq = qt * 16 + qd * 4 + r;
                if (qq < 257) {
                    int tt = b * 257 + qq;
                    int MT2 = tt >> 4, lp = tt & 15;
                    int col = h * 32 + nt * 16 + lo;
                    Of[(size_t)MT2 * 2048 + (col >> 3) * 128 + lp * 8 + (col & 7)] = f2bs(oa[nt][r]);
                }
            }
    }
}

// final LN (token 0 only, eps 1e-6) + fc head
__global__ __launch_bounds__(64) void final_head(const float* __restrict__ X, const float* __restrict__ fs,
                                                 const float* __restrict__ fb, const float* __restrict__ fcw,
                                                 const float* __restrict__ fcb, float* __restrict__ out) {
    int b = blockIdx.x, lane = threadIdx.x;
    float2 v = *(const float2*)(X + (size_t)b * 257 * 128 + lane * 2);
    float sum = v.x + v.y;
#pragma unroll
    for (int m = 1; m < 64; m <<= 1) sum += __shfl_xor(sum, m);
    float mean = sum * (1.f / 128.f);
    float d0 = v.x - mean, d1 = v.y - mean;
    float vs = d0 * d0 + d1 * d1;
#pragma unroll
    for (int m = 1; m < 64; m <<= 1) vs += __shfl_xor(vs, m);
    float rs = rsqrtf(vs * (1.f / 128.f) + 1e-6f);
    int e = lane * 2;
    float f0 = d0 * rs * fs[e] + fb[e];
    float f1 = d1 * rs * fs[e + 1] + fb[e + 1];
    out[128 + b * 128 + e] = f0;
    out[128 + b * 128 + e + 1] = f1;
    float p0 = f0 * fcw[e] + f1 * fcw[e + 1];
    float p1 = f0 * fcw[128 + e] + f1 * fcw[128 + e + 1];
#pragma unroll
    for (int m = 1; m < 64; m <<= 1) {
        p0 += __shfl_xor(p0, m);
        p1 += __shfl_xor(p1, m);
    }
    if (lane == 0) {
        out[b * 2 + 0] = p0 + fcb[0];
        out[b * 2 + 1] = p1 + fcb[1];
    }
}

extern "C" void kernel_launch(void* const* d_in, const int* in_sizes, int n_in,
                              void* d_out, int out_size, void* d_ws, size_t ws_size,
                              hipStream_t stream) {
    const float* feat    = (const float*)d_in[0];
    const float* conv_w  = (const float*)d_in[1];
    const float* conv_b  = (const float*)d_in[2];
    const float* pos_emb = (const float*)d_in[3];
    const float* cls_tok = (const float*)d_in[4];
    const float* ln1_s   = (const float*)d_in[5];
    const float* ln1_b   = (const float*)d_in[6];
    const float* qkv_w   = (const float*)d_in[7];
    const float* qkv_b   = (const float*)d_in[8];
    const float* proj_w  = (const float*)d_in[9];
    const float* proj_b  = (const float*)d_in[10];
    const float* ln2_s   = (const float*)d_in[11];
    const float* ln2_b   = (const float*)d_in[12];
    const float* ffn1_w  = (const float*)d_in[13];
    const float* ffn1_b  = (const float*)d_in[14];
    const float* ffn2_w  = (const float*)d_in[15];
    const float* ffn2_b  = (const float*)d_in[16];
    const float* fn_s    = (const float*)d_in[17];
    const float* fn_b    = (const float*)d_in[18];
    const float* fc_w    = (const float*)d_in[19];
    const float* fc_b    = (const float*)d_in[20];

    char* p = (char*)d_ws;
    auto alloc = [&](size_t bytes) { char* r = p; p += (bytes + 255) & ~(size_t)255; return r; };
    short* wq  = (short*)alloc((size_t)589824 * 2);
    short* wp  = (short*)alloc((size_t)196608 * 2);
    short* w1  = (short*)alloc((size_t)786432 * 2);
    short* w2  = (short*)alloc((size_t)786432 * 2);
    short* wc  = (short*)alloc((size_t)294912 * 2);
    short* fpd = (short*)alloc((size_t)64 * 34 * 34 * 256 * 2);
    float* X   = (float*)alloc((size_t)M_ * 128 * 4);
    short* QKV = (short*)alloc((size_t)M_ * 384 * 2);
    short* Vg  = (short*)alloc((size_t)64 * 128 * 264 * 2);
    short* Of  = (short*)alloc((size_t)M_ * 128 * 2);
    short* Uf  = (short*)alloc((size_t)M_ * 512 * 2);

    hipMemsetAsync(fpd, 0, (size_t)64 * 34 * 34 * 256 * 2, stream);
    repack_w<<<2304, 256, 0, stream>>>(qkv_w, wq, 384, 128, 589824);
    repack_w<<<768, 256, 0, stream>>>(proj_w, wp, 128, 128, 196608);
    repack_w<<<3072, 256, 0, stream>>>(ffn1_w, w1, 512, 128, 786432);
    repack_w<<<3072, 256, 0, stream>>>(ffn2_w, w2, 128, 512, 786432);
    conv_w_perm<<<1152, 256, 0, stream>>>(conv_w, wc);
    feat_nhwc<<<64 * 32, 256, 0, stream>>>(feat, fpd);
    conv_gemm<<<1024, 256, 0, stream>>>(fpd, wc, conv_b, pos_emb, X);
    cls_init<<<64, 128, 0, stream>>>(cls_tok, pos_emb, X);

    for (int l = 0; l < 12; ++l) {
        gemm_ln4<3, 0><<<514, 256, 0, stream>>>(X, wq + (size_t)l * 49152, qkv_b + l * 384,
                                                ln1_s + l * 128, ln1_b + l * 128, QKV, Vg, 384);
        attn<<<512, 256, 0, stream>>>(QKV, Vg, Of);
        gemm_frag_add<128><<<257, 256, 0, stream>>>(Of, wp + (size_t)l * 16384, proj_b + l * 128, X);
        gemm_ln4<4, 1><<<514, 256, 0, stream>>>(X, w1 + (size_t)l * 65536, ffn1_b + l * 512,
                                                ln2_s + l * 128, ln2_b + l * 128, Uf, nullptr, 512);
        gemm_frag_add<512><<<257, 256, 0, stream>>>(Uf, w2 + (size_t)l * 65536, ffn2_b + l * 128, X);
    }
    final_head<<<64, 64, 0, stream>>>(X, fn_s, fn_b, fc_w, fc_b, (float*)d_out);
}

// Round 4
// 1045.004 us; speedup vs baseline: 1.8485x; 1.0696x over previous
//
#include <hip/hip_runtime.h>
#include <math.h>

// ---------------- dims ----------------
constexpr int NP_ = 272;               // padded tokens per batch (17 tiles of 16)
constexpr int MP_ = 64 * NP_;          // 17408 padded rows
constexpr int TPB_ = 17;               // tiles per batch

typedef short short8 __attribute__((ext_vector_type(8)));
typedef float f32x4 __attribute__((ext_vector_type(4)));

__device__ inline short f2bs(float f) {  // float -> bf16 bits, RNE
    unsigned u = __builtin_bit_cast(unsigned, f);
    unsigned r = (u + 0x7fffu + ((u >> 16) & 1u)) >> 16;
    return (short)r;
}

__device__ inline f32x4 mfma16(short8 a, short8 b, f32x4 c) {
    return __builtin_amdgcn_mfma_f32_16x16x32_bf16(a, b, c, 0, 0, 0);
}

// ---------------- weight repack: W[l][n][k] fp32 -> packed [l][(k/8)][n][8] bf16 ----------------
__global__ void repack_w(const float* __restrict__ in, short* __restrict__ out, int Nn, int K, int total) {
    int o = blockIdx.x * 256 + threadIdx.x;
    if (o >= total) return;
    int per = Nn * K;
    int l = o / per, r = o % per;
    int chunk = r / (Nn * 8);
    int w = r % (Nn * 8);
    int n = w >> 3, j = w & 7;
    int k = chunk * 8 + j;
    out[o] = f2bs(in[(size_t)l * per + (size_t)n * K + k]);
}

// conv_w (E,CIN,3,3) -> packed [(kykx*8+cs)*4+qd][col 0..127][j 0..7]
__global__ void conv_w_perm(const float* __restrict__ w, short* __restrict__ wr) {
    int o = blockIdx.x * 256 + threadIdx.x;            // 294912
    if (o >= 128 * 2304) return;
    int j = o & 7;
    int col = (o >> 3) & 127;
    int c = o >> 10;                                   // 0..287
    int qd = c & 3, cscb = c >> 2;
    int cs = cscb & 7, kykx = cscb >> 3;
    int cin = cs * 32 + qd * 8 + j;
    int ky = kykx / 3, kx = kykx % 3;
    wr[o] = f2bs(w[((col * 256 + cin) * 3 + ky) * 3 + kx]);
}

// feat (B,CIN,32,32) fp32 -> fp[b][y+1][x+1][cin] bf16 (34x34 zero-padded border via memset)
__global__ __launch_bounds__(256) void feat_nhwc(const float* __restrict__ feat, short* __restrict__ fp) {
    __shared__ float tile[32][33];
    int b = blockIdx.x >> 5, y = blockIdx.x & 31;
    int t = threadIdx.x;
    for (int c0 = 0; c0 < 256; c0 += 32) {
        int ci = t >> 5, x = t & 31;
        for (int cc = ci; cc < 32; cc += 8)
            tile[cc][x] = feat[((size_t)(b * 256 + c0 + cc) * 32 + y) * 32 + x];
        __syncthreads();
        for (int i = t; i < 1024; i += 256) {
            int c = i & 31, x2 = i >> 5;
            fp[((size_t)(b * 34 + y + 1) * 34 + x2 + 1) * 256 + c0 + c] = f2bs(tile[c][x2]);
        }
        __syncthreads();
    }
}

// conv as GEMM: block = (b, oy); 3 input rows staged in LDS (XOR-phase swizzle)
__global__ __launch_bounds__(256) void conv_gemm(const short* __restrict__ fp, const short* __restrict__ wr,
                                                 const float* __restrict__ cb, const float* __restrict__ pos,
                                                 float* __restrict__ X) {
    __shared__ __align__(16) short Ain[3 * 34 * 256];  // 51 KB
    int b = blockIdx.x >> 4, oy = blockIdx.x & 15;
    int tid = threadIdx.x;
    for (int idx = tid; idx < 3 * 34 * 32; idx += 256) {
        int r = idx / 1088, rem = idx - r * 1088;
        int x = rem >> 5, c = rem & 31;
        short8 v = *(const short8*)(fp + ((size_t)(b * 34 + 2 * oy + r) * 34 + x) * 256 + c * 8);
        *(short8*)(Ain + (r * 34 + x) * 256 + ((c ^ ((x >> 1) & 7)) * 8)) = v;
    }
    __syncthreads();
    int wave = tid >> 6, lane = tid & 63;
    int ng = wave, lo = lane & 15, qd = lane >> 4;
    f32x4 acc[2] = {};
#pragma unroll
    for (int ky = 0; ky < 3; ++ky)
#pragma unroll
        for (int kx = 0; kx < 3; ++kx) {
            int sx = 2 * lo + kx;
            int arow = (ky * 34 + sx) * 256;
            int sw = (sx >> 1) & 7;
            const short* wb = wr + (((size_t)((ky * 3 + kx) * 8) * 4 + qd) * 128 + ng * 32 + lo) * 8;
#pragma unroll
            for (int cs = 0; cs < 8; ++cs) {
                short8 af = *(const short8*)(Ain + arow + (((cs * 4 + qd) ^ sw) * 8));
                short8 b0 = *(const short8*)(wb + (size_t)cs * 4096);
                short8 b1 = *(const short8*)(wb + (size_t)cs * 4096 + 128);
                acc[0] = mfma16(af, b0, acc[0]);
                acc[1] = mfma16(af, b1, acc[1]);
            }
        }
#pragma unroll
    for (int t = 0; t < 2; ++t) {
        int e = ng * 32 + t * 16 + lo;
        float bias = cb[e];
#pragma unroll
        for (int r = 0; r < 4; ++r) {
            int tok = 1 + oy * 16 + qd * 4 + r;
            X[((size_t)b * NP_ + tok) * 128 + e] = acc[t][r] + bias + pos[tok * 128 + e];
        }
    }
}

// cls token + zero the pad rows (257..271) per batch
__global__ __launch_bounds__(256) void cls_init(const float* __restrict__ cls, const float* __restrict__ pos,
                                                float* __restrict__ X) {
    int b = blockIdx.x, tid = threadIdx.x;
    if (tid < 128) X[(size_t)b * NP_ * 128 + tid] = cls[tid] + pos[tid];
    for (int idx = tid; idx < 15 * 128; idx += 256)
        X[((size_t)b * NP_ + 257) * 128 + idx] = 0.f;
}

// LayerNorm for a 64-row LDS tile (stride 132) -> A-fragment LDS tile [mt][kq][m][8].
// 512-thread block; wave w handles rows w*8..w*8+7; lane: r8=lane&7, c16=lane>>3 covers 16 cols.
__device__ inline void ln_to_frags(const float* Xl, const float* __restrict__ s, const float* __restrict__ bb,
                                   short* aF, int tid, float eps) {
    int wv = tid >> 6, lane = tid & 63;
    int r8 = lane & 7, c16 = lane >> 3;
    int row = wv * 8 + r8;
    const float* xr = Xl + row * 132 + c16 * 16;
    float v[16];
    float sum = 0.f;
#pragma unroll
    for (int p = 0; p < 4; ++p) {
        float4 a = *(const float4*)(xr + p * 4);
        v[p * 4 + 0] = a.x; v[p * 4 + 1] = a.y; v[p * 4 + 2] = a.z; v[p * 4 + 3] = a.w;
        sum += a.x + a.y + a.z + a.w;
    }
    sum += __shfl_xor(sum, 8); sum += __shfl_xor(sum, 16); sum += __shfl_xor(sum, 32);
    float mean = sum * (1.f / 128.f);
    float vs = 0.f;
#pragma unroll
    for (int j = 0; j < 16; ++j) {
        float d = v[j] - mean;
        vs += d * d;
    }
    vs += __shfl_xor(vs, 8); vs += __shfl_xor(vs, 16); vs += __shfl_xor(vs, 32);
    float rs = rsqrtf(vs * (1.f / 128.f) + eps);
    float sv[16], bv[16];
#pragma unroll
    for (int p = 0; p < 4; ++p) {
        float4 a = *(const float4*)(s + c16 * 16 + p * 4);
        float4 c = *(const float4*)(bb + c16 * 16 + p * 4);
        sv[p * 4 + 0] = a.x; sv[p * 4 + 1] = a.y; sv[p * 4 + 2] = a.z; sv[p * 4 + 3] = a.w;
        bv[p * 4 + 0] = c.x; bv[p * 4 + 1] = c.y; bv[p * 4 + 2] = c.z; bv[p * 4 + 3] = c.w;
    }
    short8 o0, o1;
#pragma unroll
    for (int j = 0; j < 8; ++j) {
        o0[j] = f2bs((v[j] - mean) * rs * sv[j] + bv[j]);
        o1[j] = f2bs((v[j + 8] - mean) * rs * sv[j + 8] + bv[j + 8]);
    }
    int mtr = row >> 4, mr = row & 15;
    *(short8*)(aF + ((mtr * 16 + c16 * 2) * 16 + mr) * 8) = o0;
    *(short8*)(aF + ((mtr * 16 + c16 * 2 + 1) * 16 + mr) * 8) = o1;
}

// scatter one qkv output element into attention-native layouts
__device__ inline void qkv_scatter(int row, int n, float val,
                                   short* __restrict__ Qf, short* __restrict__ Kf, short* __restrict__ Vt) {
    int b = row / NP_, q = row - b * NP_;
    short h16 = f2bs(val);
    if (n < 128) {
        int h = n >> 5, d = n & 31;
        Qf[((size_t)(b * 4 + h) * 4 + (d >> 3)) * (NP_ * 8) + q * 8 + (d & 7)] = h16;
    } else if (n < 256) {
        int m = n - 128, h = m >> 5, d = m & 31;
        Kf[((size_t)(b * 4 + h) * 4 + (d >> 3)) * (NP_ * 8) + q * 8 + (d & 7)] = h16;
    } else {
        int m = n - 256, h = m >> 5, d = m & 31;
        Vt[((size_t)(b * 4 + h) * 32 + d) * NP_ + q] = h16;
    }
}

// layer-0 qkv: LN1(X) @ Wq^T -> Qf/Kf/Vt
__global__ __launch_bounds__(512) void qkv0(const float* __restrict__ X, const short* __restrict__ wq,
                                            const float* __restrict__ qb, const float* __restrict__ ls,
                                            const float* __restrict__ lb,
                                            short* __restrict__ Qf, short* __restrict__ Kf, short* __restrict__ Vt) {
    __shared__ __align__(16) float Xl[64 * 132];
    __shared__ __align__(16) short aF[4 * 16 * 16 * 8];
    int mg = blockIdx.x, tid = threadIdx.x;
    for (int idx = tid; idx < 2048; idx += 512) {
        int tok = idx >> 5, c = idx & 31;
        *(float4*)(Xl + tok * 132 + c * 4) = *(const float4*)(X + (size_t)(mg * 64 + tok) * 128 + c * 4);
    }
    __syncthreads();
    ln_to_frags(Xl, ls, lb, aF, tid, 1e-5f);
    __syncthreads();
    int wv = tid >> 6, lane = tid & 63, lo = lane & 15, qd = lane >> 4;
    int n0 = wv * 48;
    f32x4 acc[4][3] = {};
#pragma unroll
    for (int ki = 0; ki < 4; ++ki) {
        int kq = ki * 4 + qd;
        short8 bf[3];
#pragma unroll
        for (int t = 0; t < 3; ++t)
            bf[t] = *(const short8*)(wq + ((size_t)kq * 384 + n0 + t * 16 + lo) * 8);
#pragma unroll
        for (int mt = 0; mt < 4; ++mt) {
            short8 a = *(const short8*)(aF + ((mt * 16 + kq) * 16 + lo) * 8);
#pragma unroll
            for (int t = 0; t < 3; ++t) acc[mt][t] = mfma16(a, bf[t], acc[mt][t]);
        }
    }
#pragma unroll
    for (int mt = 0; mt < 4; ++mt)
#pragma unroll
        for (int t = 0; t < 3; ++t) {
            int n = n0 + t * 16 + lo;
            float bvv = qb[n];
#pragma unroll
            for (int r = 0; r < 4; ++r) {
                int row = mg * 64 + mt * 16 + qd * 4 + r;
                qkv_scatter(row, n, acc[mt][t][r] + bvv, Qf, Kf, Vt);
            }
        }
}

// Fused layer tail: proj -> +X -> LN2 -> ffn1 -> gelu -> ffn2 -> +X -> [LN1' -> qkv'] (next layer)
template <int LAST>
__global__ __launch_bounds__(512) void layer_tail(
    const short* __restrict__ Of, const short* __restrict__ wp, const float* __restrict__ pb,
    const float* __restrict__ l2s, const float* __restrict__ l2b,
    const short* __restrict__ w1, const float* __restrict__ b1,
    const short* __restrict__ w2, const float* __restrict__ b2,
    float* __restrict__ X,
    const float* __restrict__ l1s, const float* __restrict__ l1b,
    const short* __restrict__ wq, const float* __restrict__ qb,
    short* __restrict__ Qf, short* __restrict__ Kf, short* __restrict__ Vt) {
    __shared__ __align__(16) short AL[4 * 16 * 16 * 8]; // 16 KB
    __shared__ __align__(16) float Xl[64 * 132];        // 33.8 KB
    __shared__ __align__(16) short aF[4 * 16 * 16 * 8]; // 16 KB
    __shared__ __align__(16) short U[4 * 64 * 16 * 8];  // 64 KB
    int mg = blockIdx.x, tid = threadIdx.x;
    const short* osrc = Of + (size_t)mg * 8192;
    for (int idx = tid; idx < 1024; idx += 512)
        *(short8*)(AL + idx * 8) = *(const short8*)(osrc + idx * 8);
    for (int idx = tid; idx < 2048; idx += 512) {
        int tok = idx >> 5, c = idx & 31;
        *(float4*)(Xl + tok * 132 + c * 4) = *(const float4*)(X + (size_t)(mg * 64 + tok) * 128 + c * 4);
    }
    __syncthreads();
    int wv = tid >> 6, lane = tid & 63, lo = lane & 15, qd = lane >> 4;
    // ---- proj (wave owns 16 cols) ----
    {
        int n0 = wv * 16;
        f32x4 pa[4] = {};
#pragma unroll
        for (int ki = 0; ki < 4; ++ki) {
            int kq = ki * 4 + qd;
            short8 bf = *(const short8*)(wp + ((size_t)kq * 128 + n0 + lo) * 8);
#pragma unroll
            for (int mt = 0; mt < 4; ++mt) {
                short8 a = *(const short8*)(AL + ((mt * 16 + kq) * 16 + lo) * 8);
                pa[mt] = mfma16(a, bf, pa[mt]);
            }
        }
        float pbv = pb[n0 + lo];
#pragma unroll
        for (int mt = 0; mt < 4; ++mt)
#pragma unroll
            for (int r = 0; r < 4; ++r)
                Xl[(mt * 16 + qd * 4 + r) * 132 + n0 + lo] += pa[mt][r] + pbv;
    }
    __syncthreads();
    ln_to_frags(Xl, l2s, l2b, aF, tid, 1e-5f);
    __syncthreads();
    // ---- ffn1 + gelu -> U (wave owns 64 cols) ----
    {
        int n0 = wv * 64;
        f32x4 fa[4][4] = {};
#pragma unroll
        for (int ki = 0; ki < 4; ++ki) {
            int kq = ki * 4 + qd;
            short8 bf[4];
#pragma unroll
            for (int t = 0; t < 4; ++t)
                bf[t] = *(const short8*)(w1 + ((size_t)kq * 512 + n0 + t * 16 + lo) * 8);
#pragma unroll
            for (int mt = 0; mt < 4; ++mt) {
                short8 a = *(const short8*)(aF + ((mt * 16 + kq) * 16 + lo) * 8);
#pragma unroll
                for (int t = 0; t < 4; ++t) fa[mt][t] = mfma16(a, bf[t], fa[mt][t]);
            }
        }
#pragma unroll
        for (int t = 0; t < 4; ++t) {
            int n = n0 + t * 16 + lo;
            float bvv = b1[n];
#pragma unroll
            for (int mt = 0; mt < 4; ++mt)
#pragma unroll
                for (int r = 0; r < 4; ++r) {
                    float x = fa[mt][t][r] + bvv;
                    float u = x * (0.7978845608f + 0.0356774081f * x * x);
                    x = x / (1.f + __expf(-2.f * u));
                    U[((size_t)(mt * 64 + (n >> 3)) * 16 + qd * 4 + r) * 8 + (n & 7)] = f2bs(x);
                }
        }
    }
    __syncthreads();
    // ---- ffn2 + residual (wave owns 16 cols) ----
    {
        int n0 = wv * 16;
        f32x4 fa[4] = {};
#pragma unroll
        for (int ki = 0; ki < 16; ++ki) {
            int kq = ki * 4 + qd;
            short8 bf = *(const short8*)(w2 + ((size_t)kq * 128 + n0 + lo) * 8);
#pragma unroll
            for (int mt = 0; mt < 4; ++mt) {
                short8 a = *(const short8*)(U + ((size_t)(mt * 64 + kq) * 16 + lo) * 8);
                fa[mt] = mfma16(a, bf, fa[mt]);
            }
        }
        float bvv = b2[n0 + lo];
#pragma unroll
        for (int mt = 0; mt < 4; ++mt)
#pragma unroll
            for (int r = 0; r < 4; ++r) {
                int row = mt * 16 + qd * 4 + r;
                float xv = Xl[row * 132 + n0 + lo] + fa[mt][r] + bvv;
                Xl[row * 132 + n0 + lo] = xv;
                X[(size_t)(mg * 64 + row) * 128 + n0 + lo] = xv;
            }
    }
    if (LAST) return;
    __syncthreads();
    ln_to_frags(Xl, l1s, l1b, aF, tid, 1e-5f);
    __syncthreads();
    // ---- next-layer qkv (wave owns 48 cols) ----
    {
        int n0 = wv * 48;
        f32x4 acc[4][3] = {};
#pragma unroll
        for (int ki = 0; ki < 4; ++ki) {
            int kq = ki * 4 + qd;
            short8 bf[3];
#pragma unroll
            for (int t = 0; t < 3; ++t)
                bf[t] = *(const short8*)(wq + ((size_t)kq * 384 + n0 + t * 16 + lo) * 8);
#pragma unroll
            for (int mt = 0; mt < 4; ++mt) {
                short8 a = *(const short8*)(aF + ((mt * 16 + kq) * 16 + lo) * 8);
#pragma unroll
                for (int t = 0; t < 3; ++t) acc[mt][t] = mfma16(a, bf[t], acc[mt][t]);
            }
        }
#pragma unroll
        for (int mt = 0; mt < 4; ++mt)
#pragma unroll
            for (int t = 0; t < 3; ++t) {
                int n = n0 + t * 16 + lo;
                float bvv = qb[n];
#pragma unroll
                for (int r = 0; r < 4; ++r) {
                    int row = mg * 64 + mt * 16 + qd * 4 + r;
                    qkv_scatter(row, n, acc[mt][t][r] + bvv, Qf, Kf, Vt);
                }
            }
    }
}

// Fused attention: block = (b,h,half); contiguous staging from Qf/Kf/Vt; Of in fragment layout.
__global__ __launch_bounds__(256) void attn(const short* __restrict__ Qf, const short* __restrict__ Kf,
                                            const short* __restrict__ Vt, short* __restrict__ Of) {
    __shared__ __align__(16) short Kl[4 * NP_ * 8];    // 17.4 KB
    __shared__ __align__(16) short Vl[32 * 288];       // 18.4 KB
    __shared__ __align__(16) short Pl[4 * 36 * 16 * 8];// 36.9 KB
    int b = blockIdx.x >> 3, h = (blockIdx.x >> 1) & 3, half = blockIdx.x & 1;
    int tid = threadIdx.x;
    const short* kf = Kf + (size_t)(b * 4 + h) * (4 * NP_ * 8);
    const short* vt = Vt + (size_t)(b * 4 + h) * (32 * NP_);
    const short* qf = Qf + (size_t)(b * 4 + h) * (4 * NP_ * 8);
    for (int idx = tid; idx < 1088; idx += 256)
        *(short8*)(Kl + idx * 8) = *(const short8*)(kf + idx * 8);
    for (int idx = tid; idx < 32 * 36; idx += 256) {
        int d = idx / 36, c = idx - d * 36;
        short8 v = {};
        if (c < 34) v = *(const short8*)(vt + d * NP_ + c * 8);
        *(short8*)(Vl + d * 288 + c * 8) = v;
    }
    for (int idx = tid; idx < 128; idx += 256) {       // zero P pad chunks (kq 34,35)
        int w = idx >> 5, t = idx & 31;
        short8 z = {};
        *(short8*)(Pl + w * 4608 + 34 * 128 + t * 8) = z;
    }
    __syncthreads();
    int wv = tid >> 6, lane = tid & 63, lo = lane & 15, qd = lane >> 4;
    short* Pw = Pl + wv * 4608;
    const float scale = 0.17677669529663687f;
    for (int it = 0; it < 3; ++it) {
        int qt = it * 8 + half * 4 + wv;
        if (qt > 16) break;                            // wave-uniform
        short8 qfr = *(const short8*)(qf + ((size_t)qd * NP_ + qt * 16 + lo) * 8);
        f32x4 sc[17];
#pragma unroll
        for (int kt = 0; kt < 17; ++kt) {
            short8 kfr = *(const short8*)(Kl + ((size_t)qd * NP_ + kt * 16 + lo) * 8);
            f32x4 z = {};
            sc[kt] = mfma16(qfr, kfr, z);
        }
        float mx[4] = {-1e30f, -1e30f, -1e30f, -1e30f};
#pragma unroll
        for (int kt = 0; kt < 17; ++kt) {
            bool valid = (kt * 16 + lo) < 257;
#pragma unroll
            for (int r = 0; r < 4; ++r) {
                float v2 = valid ? sc[kt][r] * scale : -1e30f;
                sc[kt][r] = v2;
                mx[r] = fmaxf(mx[r], v2);
            }
        }
#pragma unroll
        for (int r = 0; r < 4; ++r) {
            mx[r] = fmaxf(mx[r], __shfl_xor(mx[r], 1));
            mx[r] = fmaxf(mx[r], __shfl_xor(mx[r], 2));
            mx[r] = fmaxf(mx[r], __shfl_xor(mx[r], 4));
            mx[r] = fmaxf(mx[r], __shfl_xor(mx[r], 8));
        }
        float l[4] = {0.f, 0.f, 0.f, 0.f};
#pragma unroll
        for (int kt = 0; kt < 17; ++kt)
#pragma unroll
            for (int r = 0; r < 4; ++r) {
                float p = __expf(sc[kt][r] - mx[r]);
                sc[kt][r] = p;
                l[r] += p;
            }
#pragma unroll
        for (int r = 0; r < 4; ++r) {
            l[r] += __shfl_xor(l[r], 1);
            l[r] += __shfl_xor(l[r], 2);
            l[r] += __shfl_xor(l[r], 4);
            l[r] += __shfl_xor(l[r], 8);
        }
        float rl[4];
#pragma unroll
        for (int r = 0; r < 4; ++r) rl[r] = 1.f / l[r];
#pragma unroll
        for (int kt = 0; kt < 17; ++kt)
#pragma unroll
            for (int r = 0; r < 4; ++r) {
                int key = kt * 16 + lo;
                Pw[((key >> 3) * 16 + qd * 4 + r) * 8 + (key & 7)] = f2bs(sc[kt][r] * rl[r]);
            }
        f32x4 oa[2] = {};
#pragma unroll
        for (int ks = 0; ks < 9; ++ks) {
            short8 pf = *(const short8*)(Pw + ((ks * 4 + qd) * 16 + lo) * 8);
#pragma unroll
            for (int nt = 0; nt < 2; ++nt) {
                short8 vf = *(const short8*)(Vl + (nt * 16 + lo) * 288 + ks * 32 + qd * 8);
                oa[nt] = mfma16(pf, vf, oa[nt]);
            }
        }
        int tile = b * TPB_ + qt;
#pragma unroll
        for (int nt = 0; nt < 2; ++nt)
#pragma unroll
            for (int r = 0; r < 4; ++r) {
                int qq = qt * 16 + qd * 4 + r;
                if (qq <= 256) {
                    int col = h * 32 + nt * 16 + lo;
                    Of[(size_t)tile * 2048 + (col >> 3) * 128 + (qd * 4 + r) * 8 + (col & 7)] = f2bs(oa[nt][r]);
                }
            }
    }
}

// final LN (token 0 only, eps 1e-6) + fc head
__global__ __launch_bounds__(64) void final_head(const float* __restrict__ X, const float* __restrict__ fs,
                                                 const float* __restrict__ fb, const float* __restrict__ fcw,
                                                 const float* __restrict__ fcb, float* __restrict__ out) {
    int b = blockIdx.x, lane = threadIdx.x;
    float2 v = *(const float2*)(X + (size_t)b * NP_ * 128 + lane * 2);
    float sum = v.x + v.y;
#pragma unroll
    for (int m = 1; m < 64; m <<= 1) sum += __shfl_xor(sum, m);
    float mean = sum * (1.f / 128.f);
    float d0 = v.x - mean, d1 = v.y - mean;
    float vs = d0 * d0 + d1 * d1;
#pragma unroll
    for (int m = 1; m < 64; m <<= 1) vs += __shfl_xor(vs, m);
    float rs = rsqrtf(vs * (1.f / 128.f) + 1e-6f);
    int e = lane * 2;
    float f0 = d0 * rs * fs[e] + fb[e];
    float f1 = d1 * rs * fs[e + 1] + fb[e + 1];
    out[128 + b * 128 + e] = f0;
    out[128 + b * 128 + e + 1] = f1;
    float p0 = f0 * fcw[e] + f1 * fcw[e + 1];
    float p1 = f0 * fcw[128 + e] + f1 * fcw[128 + e + 1];
#pragma unroll
    for (int m = 1; m < 64; m <<= 1) {
        p0 += __shfl_xor(p0, m);
        p1 += __shfl_xor(p1, m);
    }
    if (lane == 0) {
        out[b * 2 + 0] = p0 + fcb[0];
        out[b * 2 + 1] = p1 + fcb[1];
    }
}

extern "C" void kernel_launch(void* const* d_in, const int* in_sizes, int n_in,
                              void* d_out, int out_size, void* d_ws, size_t ws_size,
                              hipStream_t stream) {
    const float* feat    = (const float*)d_in[0];
    const float* conv_w  = (const float*)d_in[1];
    const float* conv_b  = (const float*)d_in[2];
    const float* pos_emb = (const float*)d_in[3];
    const float* cls_tok = (const float*)d_in[4];
    const float* ln1_s   = (const float*)d_in[5];
    const float* ln1_b   = (const float*)d_in[6];
    const float* qkv_w   = (const float*)d_in[7];
    const float* qkv_b   = (const float*)d_in[8];
    const float* proj_w  = (const float*)d_in[9];
    const float* proj_b  = (const float*)d_in[10];
    const float* ln2_s   = (const float*)d_in[11];
    const float* ln2_b   = (const float*)d_in[12];
    const float* ffn1_w  = (const float*)d_in[13];
    const float* ffn1_b  = (const float*)d_in[14];
    const float* ffn2_w  = (const float*)d_in[15];
    const float* ffn2_b  = (const float*)d_in[16];
    const float* fn_s    = (const float*)d_in[17];
    const float* fn_b    = (const float*)d_in[18];
    const float* fc_w    = (const float*)d_in[19];
    const float* fc_b    = (const float*)d_in[20];

    char* p = (char*)d_ws;
    auto alloc = [&](size_t bytes) { char* r = p; p += (bytes + 255) & ~(size_t)255; return r; };
    short* wq  = (short*)alloc((size_t)589824 * 2);
    short* wp  = (short*)alloc((size_t)196608 * 2);
    short* w1  = (short*)alloc((size_t)786432 * 2);
    short* w2  = (short*)alloc((size_t)786432 * 2);
    short* wc  = (short*)alloc((size_t)294912 * 2);
    short* fpd = (short*)alloc((size_t)64 * 34 * 34 * 256 * 2);
    float* X   = (float*)alloc((size_t)MP_ * 128 * 4);
    short* Qf  = (short*)alloc((size_t)64 * 4 * 4 * NP_ * 8 * 2);
    short* Kf  = (short*)alloc((size_t)64 * 4 * 4 * NP_ * 8 * 2);
    short* Vt  = (short*)alloc((size_t)64 * 4 * 32 * NP_ * 2);
    short* Of  = (short*)alloc((size_t)(MP_ / 16) * 2048 * 2);

    hipMemsetAsync(fpd, 0, (size_t)64 * 34 * 34 * 256 * 2, stream);
    repack_w<<<2304, 256, 0, stream>>>(qkv_w, wq, 384, 128, 589824);
    repack_w<<<768, 256, 0, stream>>>(proj_w, wp, 128, 128, 196608);
    repack_w<<<3072, 256, 0, stream>>>(ffn1_w, w1, 512, 128, 786432);
    repack_w<<<3072, 256, 0, stream>>>(ffn2_w, w2, 128, 512, 786432);
    conv_w_perm<<<1152, 256, 0, stream>>>(conv_w, wc);
    feat_nhwc<<<64 * 32, 256, 0, stream>>>(feat, fpd);
    conv_gemm<<<1024, 256, 0, stream>>>(fpd, wc, conv_b, pos_emb, X);
    cls_init<<<64, 256, 0, stream>>>(cls_tok, pos_emb, X);

    qkv0<<<272, 512, 0, stream>>>(X, wq, qkv_b, ln1_s, ln1_b, Qf, Kf, Vt);
    for (int l = 0; l < 12; ++l) {
        attn<<<512, 256, 0, stream>>>(Qf, Kf, Vt, Of);
        if (l < 11)
            layer_tail<0><<<272, 512, 0, stream>>>(Of, wp + (size_t)l * 16384, proj_b + l * 128,
                                                   ln2_s + l * 128, ln2_b + l * 128,
                                                   w1 + (size_t)l * 65536, ffn1_b + l * 512,
                                                   w2 + (size_t)l * 65536, ffn2_b + l * 128, X,
                                                   ln1_s + (l + 1) * 128, ln1_b + (l + 1) * 128,
                                                   wq + (size_t)(l + 1) * 49152, qkv_b + (l + 1) * 384,
                                                   Qf, Kf, Vt);
        else
            layer_tail<1><<<272, 512, 0, stream>>>(Of, wp + (size_t)l * 16384, proj_b + l * 128,
                                                   ln2_s + l * 128, ln2_b + l * 128,
                                                   w1 + (size_t)l * 65536, ffn1_b + l * 512,
                                                   w2 + (size_t)l * 65536, ffn2_b + l * 128, X,
                                                   ln1_s, ln1_b, wq, qkv_b, Qf, Kf, Vt);
    }
    final_head<<<64, 64, 0, stream>>>(X, fn_s, fn_b, fc_w, fc_b, (float*)d_out);
}

// Round 6
// 870.377 us; speedup vs baseline: 2.2194x; 1.2006x over previous
//
#include <hip/hip_runtime.h>
#include <math.h>

// ---------------- dims ----------------
constexpr int NP_ = 272;               // padded tokens per batch (17 tiles of 16)
constexpr int MP_ = 64 * NP_;          // 17408 padded rows
constexpr int TPB_ = 17;               // tiles per batch

typedef short short8 __attribute__((ext_vector_type(8)));
typedef float f32x4 __attribute__((ext_vector_type(4)));

__device__ inline short f2bs(float f) {  // float -> bf16 bits, RNE
    unsigned u = __builtin_bit_cast(unsigned, f);
    unsigned r = (u + 0x7fffu + ((u >> 16) & 1u)) >> 16;
    return (short)r;
}

__device__ inline f32x4 mfma16(short8 a, short8 b, f32x4 c) {
    return __builtin_amdgcn_mfma_f32_16x16x32_bf16(a, b, c, 0, 0, 0);
}

// ---------------- weight repack: W[l][n][k] fp32 -> packed [l][(k/8)][n][8] bf16 ----------------
__global__ void repack_w(const float* __restrict__ in, short* __restrict__ out, int Nn, int K, int total) {
    int o = blockIdx.x * 256 + threadIdx.x;
    if (o >= total) return;
    int per = Nn * K;
    int l = o / per, r = o % per;
    int chunk = r / (Nn * 8);
    int w = r % (Nn * 8);
    int n = w >> 3, j = w & 7;
    int k = chunk * 8 + j;
    out[o] = f2bs(in[(size_t)l * per + (size_t)n * K + k]);
}

// conv_w (E,CIN,3,3) -> packed [(kykx*8+cs)*4+qd][col 0..127][j 0..7]
__global__ void conv_w_perm(const float* __restrict__ w, short* __restrict__ wr) {
    int o = blockIdx.x * 256 + threadIdx.x;            // 294912
    if (o >= 128 * 2304) return;
    int j = o & 7;
    int col = (o >> 3) & 127;
    int c = o >> 10;                                   // 0..287
    int qd = c & 3, cscb = c >> 2;
    int cs = cscb & 7, kykx = cscb >> 3;
    int cin = cs * 32 + qd * 8 + j;
    int ky = kykx / 3, kx = kykx % 3;
    wr[o] = f2bs(w[((col * 256 + cin) * 3 + ky) * 3 + kx]);
}

// feat (B,CIN,32,32) fp32 -> fp[b][y+1][x+1][cin] bf16 (34x34 zero-padded border via memset)
__global__ __launch_bounds__(256) void feat_nhwc(const float* __restrict__ feat, short* __restrict__ fp) {
    __shared__ float tile[32][33];
    int b = blockIdx.x >> 5, y = blockIdx.x & 31;
    int t = threadIdx.x;
    for (int c0 = 0; c0 < 256; c0 += 32) {
        int ci = t >> 5, x = t & 31;
        for (int cc = ci; cc < 32; cc += 8)
            tile[cc][x] = feat[((size_t)(b * 256 + c0 + cc) * 32 + y) * 32 + x];
        __syncthreads();
        for (int i = t; i < 1024; i += 256) {
            int c = i & 31, x2 = i >> 5;
            fp[((size_t)(b * 34 + y + 1) * 34 + x2 + 1) * 256 + c0 + c] = f2bs(tile[c][x2]);
        }
        __syncthreads();
    }
}

// conv as GEMM: block = (b, oy); 3 input rows staged in LDS (XOR-phase swizzle)
__global__ __launch_bounds__(256) void conv_gemm(const short* __restrict__ fp, const short* __restrict__ wr,
                                                 const float* __restrict__ cb, const float* __restrict__ pos,
                                                 float* __restrict__ X) {
    __shared__ __align__(16) short Ain[3 * 34 * 256];  // 51 KB
    int b = blockIdx.x >> 4, oy = blockIdx.x & 15;
    int tid = threadIdx.x;
    for (int idx = tid; idx < 3 * 34 * 32; idx += 256) {
        int r = idx / 1088, rem = idx - r * 1088;
        int x = rem >> 5, c = rem & 31;
        short8 v = *(const short8*)(fp + ((size_t)(b * 34 + 2 * oy + r) * 34 + x) * 256 + c * 8);
        *(short8*)(Ain + (r * 34 + x) * 256 + ((c ^ ((x >> 1) & 7)) * 8)) = v;
    }
    __syncthreads();
    int wave = tid >> 6, lane = tid & 63;
    int ng = wave, lo = lane & 15, qd = lane >> 4;
    f32x4 acc[2] = {};
#pragma unroll
    for (int ky = 0; ky < 3; ++ky)
#pragma unroll
        for (int kx = 0; kx < 3; ++kx) {
            int sx = 2 * lo + kx;
            int arow = (ky * 34 + sx) * 256;
            int sw = (sx >> 1) & 7;
            const short* wb = wr + (((size_t)((ky * 3 + kx) * 8) * 4 + qd) * 128 + ng * 32 + lo) * 8;
#pragma unroll
            for (int cs = 0; cs < 8; ++cs) {
                short8 af = *(const short8*)(Ain + arow + (((cs * 4 + qd) ^ sw) * 8));
                short8 b0 = *(const short8*)(wb + (size_t)cs * 4096);
                short8 b1 = *(const short8*)(wb + (size_t)cs * 4096 + 128);
                acc[0] = mfma16(af, b0, acc[0]);
                acc[1] = mfma16(af, b1, acc[1]);
            }
        }
#pragma unroll
    for (int t = 0; t < 2; ++t) {
        int e = ng * 32 + t * 16 + lo;
        float bias = cb[e];
#pragma unroll
        for (int r = 0; r < 4; ++r) {
            int tok = 1 + oy * 16 + qd * 4 + r;
            X[((size_t)b * NP_ + tok) * 128 + e] = acc[t][r] + bias + pos[tok * 128 + e];
        }
    }
}

// cls token + zero the pad rows (257..271) per batch
__global__ __launch_bounds__(256) void cls_init(const float* __restrict__ cls, const float* __restrict__ pos,
                                                float* __restrict__ X) {
    int b = blockIdx.x, tid = threadIdx.x;
    if (tid < 128) X[(size_t)b * NP_ * 128 + tid] = cls[tid] + pos[tid];
    for (int idx = tid; idx < 15 * 128; idx += 256)
        X[((size_t)b * NP_ + 257) * 128 + idx] = 0.f;
}

// LN of a 32-row LDS tile (stride 132) -> A-frag LDS tile [2 tiles][kq][m][8]. 512 threads.
__device__ inline void ln_frags32(const float* Xl, const float* __restrict__ s, const float* __restrict__ bb,
                                  short* aF, int tid, float eps) {
    int wv = tid >> 6, lane = tid & 63;
    int r4 = lane & 3, c32 = lane >> 2;                // c32: 16 groups of 8 cols
    int row = wv * 4 + r4;
    const float* xr = Xl + row * 132 + c32 * 8;
    float4 a = *(const float4*)(xr);
    float4 b = *(const float4*)(xr + 4);
    float v[8] = {a.x, a.y, a.z, a.w, b.x, b.y, b.z, b.w};
    float sum = v[0] + v[1] + v[2] + v[3] + v[4] + v[5] + v[6] + v[7];
    sum += __shfl_xor(sum, 4); sum += __shfl_xor(sum, 8);
    sum += __shfl_xor(sum, 16); sum += __shfl_xor(sum, 32);
    float mean = sum * (1.f / 128.f);
    float vs = 0.f;
#pragma unroll
    for (int j = 0; j < 8; ++j) { float d = v[j] - mean; vs += d * d; }
    vs += __shfl_xor(vs, 4); vs += __shfl_xor(vs, 8);
    vs += __shfl_xor(vs, 16); vs += __shfl_xor(vs, 32);
    float rs = rsqrtf(vs * (1.f / 128.f) + eps);
    float4 s0 = *(const float4*)(s + c32 * 8), s1 = *(const float4*)(s + c32 * 8 + 4);
    float4 b0 = *(const float4*)(bb + c32 * 8), b1 = *(const float4*)(bb + c32 * 8 + 4);
    float sv[8] = {s0.x, s0.y, s0.z, s0.w, s1.x, s1.y, s1.z, s1.w};
    float bv[8] = {b0.x, b0.y, b0.z, b0.w, b1.x, b1.y, b1.z, b1.w};
    short8 o;
#pragma unroll
    for (int j = 0; j < 8; ++j) o[j] = f2bs((v[j] - mean) * rs * sv[j] + bv[j]);
    *(short8*)(aF + (((row >> 4) * 16 + c32) * 16 + (row & 15)) * 8) = o;
}

// qkv GEMM stage from aF frags + scatter into Qf/Kf/Vf (all A-frag layout per (b,h))
__device__ inline void qkv_stage(const short* aF, const short* __restrict__ wq, const float* __restrict__ qb,
                                 int mg, int wv, int lo, int qd,
                                 short* __restrict__ Qf, short* __restrict__ Kf, short* __restrict__ Vf) {
    int n0 = wv * 48;
    f32x4 acc[2][3] = {};
#pragma unroll
    for (int ki = 0; ki < 4; ++ki) {
        int kq = ki * 4 + qd;
        short8 bf[3];
#pragma unroll
        for (int t = 0; t < 3; ++t)
            bf[t] = *(const short8*)(wq + ((size_t)kq * 384 + n0 + t * 16 + lo) * 8);
#pragma unroll
        for (int mt = 0; mt < 2; ++mt) {
            short8 a = *(const short8*)(aF + ((mt * 16 + kq) * 16 + lo) * 8);
#pragma unroll
            for (int t = 0; t < 3; ++t) acc[mt][t] = mfma16(a, bf[t], acc[mt][t]);
        }
    }
#pragma unroll
    for (int mt = 0; mt < 2; ++mt)
#pragma unroll
        for (int t = 0; t < 3; ++t) {
            int n = n0 + t * 16 + lo;
            float bvv = qb[n];
            int seg = n >> 7, m = n & 127, h = m >> 5, d = m & 31;
            short* dst = (seg == 0) ? Qf : ((seg == 1) ? Kf : Vf);
#pragma unroll
            for (int r = 0; r < 4; ++r) {
                int row = mg * 32 + mt * 16 + qd * 4 + r;
                int bb2 = row / NP_, q = row - bb2 * NP_;
                dst[((size_t)(bb2 * 4 + h) * 4 + (d >> 3)) * (NP_ * 8) + q * 8 + (d & 7)] =
                    f2bs(acc[mt][t][r] + bvv);
            }
        }
}

// layer-0 qkv: LN1(X) -> frags -> qkv
__global__ __launch_bounds__(512, 4) void qkv0(const float* __restrict__ X, const short* __restrict__ wq,
                                               const float* __restrict__ qb, const float* __restrict__ ls,
                                               const float* __restrict__ lb,
                                               short* __restrict__ Qf, short* __restrict__ Kf,
                                               short* __restrict__ Vf) {
    __shared__ __align__(16) float Xl[32 * 132];
    __shared__ __align__(16) short aF[2 * 16 * 16 * 8];
    int mg = blockIdx.x, tid = threadIdx.x;
    for (int idx = tid; idx < 1024; idx += 512) {
        int tok = idx >> 5, c = idx & 31;
        *(float4*)(Xl + tok * 132 + c * 4) = *(const float4*)(X + (size_t)(mg * 32 + tok) * 128 + c * 4);
    }
    __syncthreads();
    ln_frags32(Xl, ls, lb, aF, tid, 1e-5f);
    __syncthreads();
    int wv = tid >> 6, lane = tid & 63;
    qkv_stage(aF, wq, qb, mg, wv, lane & 15, lane >> 4, Qf, Kf, Vf);
}

// tail_a: proj(Of frags) + residual -> X ; LN2 -> Hf (A-frag tiles, global)
__global__ __launch_bounds__(256, 4) void tail_a(const short* __restrict__ Of, const short* __restrict__ wp,
                                                 const float* __restrict__ pb, const float* __restrict__ l2s,
                                                 const float* __restrict__ l2b, float* __restrict__ X,
                                                 short* __restrict__ Hf) {
    __shared__ __align__(16) short AL[2 * 2048];       // 8 KB
    __shared__ __align__(16) float Xl[32 * 132];       // 16.9 KB
    int mg = blockIdx.x, tid = threadIdx.x;
    const short* osrc = Of + (size_t)mg * 4096;
    for (int idx = tid; idx < 512; idx += 256)
        *(short8*)(AL + idx * 8) = *(const short8*)(osrc + idx * 8);
    for (int idx = tid; idx < 1024; idx += 256) {
        int tok = idx >> 5, c = idx & 31;
        *(float4*)(Xl + tok * 132 + c * 4) = *(const float4*)(X + (size_t)(mg * 32 + tok) * 128 + c * 4);
    }
    __syncthreads();
    int wv = tid >> 6, lane = tid & 63, lo = lane & 15, qd = lane >> 4;
    int n0 = wv * 32;
    f32x4 acc[2][2] = {};
#pragma unroll
    for (int ki = 0; ki < 4; ++ki) {
        int kq = ki * 4 + qd;
        short8 b0 = *(const short8*)(wp + ((size_t)kq * 128 + n0 + lo) * 8);
        short8 b1 = *(const short8*)(wp + ((size_t)kq * 128 + n0 + 16 + lo) * 8);
#pragma unroll
        for (int mt = 0; mt < 2; ++mt) {
            short8 a = *(const short8*)(AL + mt * 2048 + (kq * 16 + lo) * 8);
            acc[mt][0] = mfma16(a, b0, acc[mt][0]);
            acc[mt][1] = mfma16(a, b1, acc[mt][1]);
        }
    }
    float pb0 = pb[n0 + lo], pb1 = pb[n0 + 16 + lo];
#pragma unroll
    for (int mt = 0; mt < 2; ++mt)
#pragma unroll
        for (int r = 0; r < 4; ++r) {
            int row = mt * 16 + qd * 4 + r;
            Xl[row * 132 + n0 + lo] += acc[mt][0][r] + pb0;
            Xl[row * 132 + n0 + 16 + lo] += acc[mt][1][r] + pb1;
        }
    __syncthreads();
    for (int idx = tid; idx < 1024; idx += 256) {
        int tok = idx >> 5, c = idx & 31;
        *(float4*)(X + (size_t)(mg * 32 + tok) * 128 + c * 4) = *(const float4*)(Xl + tok * 132 + c * 4);
    }
    // LN2 -> Hf frags (4 waves x 8 rows; lane: r8 rows, c16: 8 groups of 16 cols)
    {
        int r8 = lane & 7, c16 = lane >> 3;
        int row = wv * 8 + r8;
        const float* xr = Xl + row * 132 + c16 * 16;
        float v[16]; float sum = 0.f;
#pragma unroll
        for (int p2 = 0; p2 < 4; ++p2) {
            float4 a = *(const float4*)(xr + p2 * 4);
            v[p2 * 4 + 0] = a.x; v[p2 * 4 + 1] = a.y; v[p2 * 4 + 2] = a.z; v[p2 * 4 + 3] = a.w;
            sum += a.x + a.y + a.z + a.w;
        }
        sum += __shfl_xor(sum, 8); sum += __shfl_xor(sum, 16); sum += __shfl_xor(sum, 32);
        float mean = sum * (1.f / 128.f);
        float vs = 0.f;
#pragma unroll
        for (int j = 0; j < 16; ++j) { float d = v[j] - mean; vs += d * d; }
        vs += __shfl_xor(vs, 8); vs += __shfl_xor(vs, 16); vs += __shfl_xor(vs, 32);
        float rs = rsqrtf(vs * (1.f / 128.f) + 1e-5f);
        float sv[16], bv[16];
#pragma unroll
        for (int p2 = 0; p2 < 4; ++p2) {
            float4 a = *(const float4*)(l2s + c16 * 16 + p2 * 4);
            float4 c = *(const float4*)(l2b + c16 * 16 + p2 * 4);
            sv[p2 * 4 + 0] = a.x; sv[p2 * 4 + 1] = a.y; sv[p2 * 4 + 2] = a.z; sv[p2 * 4 + 3] = a.w;
            bv[p2 * 4 + 0] = c.x; bv[p2 * 4 + 1] = c.y; bv[p2 * 4 + 2] = c.z; bv[p2 * 4 + 3] = c.w;
        }
        short8 o0, o1;
#pragma unroll
        for (int j = 0; j < 8; ++j) {
            o0[j] = f2bs((v[j] - mean) * rs * sv[j] + bv[j]);
            o1[j] = f2bs((v[j + 8] - mean) * rs * sv[j + 8] + bv[j + 8]);
        }
        int t2 = row >> 4, mr = row & 15;
        *(short8*)(Hf + (size_t)(2 * mg + t2) * 2048 + (c16 * 2) * 128 + mr * 8) = o0;
        *(short8*)(Hf + (size_t)(2 * mg + t2) * 2048 + (c16 * 2 + 1) * 128 + mr * 8) = o1;
    }
}

// tail_b: ffn1(Hf)+gelu -> U(LDS) ; ffn2+residual -> X ; LN1' -> next qkv
template <int LAST>
__global__ __launch_bounds__(512, 4) void tail_b(const short* __restrict__ Hf, const short* __restrict__ w1,
                                                 const float* __restrict__ b1, const short* __restrict__ w2,
                                                 const float* __restrict__ b2, float* __restrict__ X,
                                                 const float* __restrict__ l1s, const float* __restrict__ l1b,
                                                 const short* __restrict__ wq, const float* __restrict__ qb,
                                                 short* __restrict__ Qf, short* __restrict__ Kf,
                                                 short* __restrict__ Vf) {
    __shared__ __align__(16) short HfL[2 * 2048];      // 8 KB
    __shared__ __align__(16) short U[128 * 136];       // 34.8 KB, chunk stride 136 (pad)
    __shared__ __align__(16) float Xl[32 * 132];       // 16.9 KB
    __shared__ __align__(16) short aF[2 * 16 * 16 * 8];// 8 KB
    int mg = blockIdx.x, tid = threadIdx.x;
    const short* hsrc = Hf + (size_t)mg * 4096;
    for (int idx = tid; idx < 512; idx += 512)
        *(short8*)(HfL + idx * 8) = *(const short8*)(hsrc + idx * 8);
    for (int idx = tid; idx < 1024; idx += 512) {
        int tok = idx >> 5, c = idx & 31;
        *(float4*)(Xl + tok * 132 + c * 4) = *(const float4*)(X + (size_t)(mg * 32 + tok) * 128 + c * 4);
    }
    __syncthreads();
    int wv = tid >> 6, lane = tid & 63, lo = lane & 15, qd = lane >> 4;
    // ---- ffn1 + gelu -> U (wave owns 64 cols) ----
    {
        int n0 = wv * 64;
        f32x4 fa[2][4] = {};
#pragma unroll
        for (int ki = 0; ki < 4; ++ki) {
            int kq = ki * 4 + qd;
            short8 bf[4];
#pragma unroll
            for (int t = 0; t < 4; ++t)
                bf[t] = *(const short8*)(w1 + ((size_t)kq * 512 + n0 + t * 16 + lo) * 8);
#pragma unroll
            for (int mt = 0; mt < 2; ++mt) {
                short8 a = *(const short8*)(HfL + mt * 2048 + (kq * 16 + lo) * 8);
#pragma unroll
                for (int t = 0; t < 4; ++t) fa[mt][t] = mfma16(a, bf[t], fa[mt][t]);
            }
        }
#pragma unroll
        for (int t = 0; t < 4; ++t) {
            int n = n0 + t * 16 + lo;
            float bvv = b1[n];
#pragma unroll
            for (int mt = 0; mt < 2; ++mt)
#pragma unroll
                for (int r = 0; r < 4; ++r) {
                    float x = fa[mt][t][r] + bvv;
                    float u = x * (0.7978845608f + 0.0356774081f * x * x);
                    x = x / (1.f + __expf(-2.f * u));
                    U[(mt * 64 + (n >> 3)) * 136 + (qd * 4 + r) * 8 + (n & 7)] = f2bs(x);
                }
        }
    }
    __syncthreads();
    // ---- ffn2 + residual (wave owns 16 cols, K=512) ----
    {
        int n0 = wv * 16;
        f32x4 fa[2] = {};
#pragma unroll 4
        for (int ki = 0; ki < 16; ++ki) {
            int kq = ki * 4 + qd;
            short8 bf = *(const short8*)(w2 + ((size_t)kq * 128 + n0 + lo) * 8);
#pragma unroll
            for (int mt = 0; mt < 2; ++mt) {
                short8 a = *(const short8*)(U + (mt * 64 + kq) * 136 + lo * 8);
                fa[mt] = mfma16(a, bf, fa[mt]);
            }
        }
        float bvv = b2[n0 + lo];
#pragma unroll
        for (int mt = 0; mt < 2; ++mt)
#pragma unroll
            for (int r = 0; r < 4; ++r)
                Xl[(mt * 16 + qd * 4 + r) * 132 + n0 + lo] += fa[mt][r] + bvv;
    }
    __syncthreads();
    for (int idx = tid; idx < 1024; idx += 512) {
        int tok = idx >> 5, c = idx & 31;
        *(float4*)(X + (size_t)(mg * 32 + tok) * 128 + c * 4) = *(const float4*)(Xl + tok * 132 + c * 4);
    }
    if (LAST) return;
    ln_frags32(Xl, l1s, l1b, aF, tid, 1e-5f);
    __syncthreads();
    qkv_stage(aF, wq, qb, mg, wv, lo, qd, Qf, Kf, Vf);
}

// Fused attention: block = (b,h,half); K contiguous, V transposed in LDS from A-frag layout.
__global__ __launch_bounds__(256) void attn(const short* __restrict__ Qf, const short* __restrict__ Kf,
                                            const short* __restrict__ Vf, short* __restrict__ Of) {
    __shared__ __align__(16) short Kl[4 * NP_ * 8];    // 17.4 KB
    __shared__ __align__(16) short Vl[32 * 288];       // 18.4 KB
    __shared__ __align__(16) short Pl[4 * 36 * 16 * 8];// 36.9 KB
    int b = blockIdx.x >> 3, h = (blockIdx.x >> 1) & 3, half = blockIdx.x & 1;
    int tid = threadIdx.x;
    const short* kf = Kf + (size_t)(b * 4 + h) * (4 * NP_ * 8);
    const short* vf = Vf + (size_t)(b * 4 + h) * (4 * NP_ * 8);
    const short* qf = Qf + (size_t)(b * 4 + h) * (4 * NP_ * 8);
    for (int idx = tid; idx < 1088; idx += 256)
        *(short8*)(Kl + idx * 8) = *(const short8*)(kf + idx * 8);
#pragma unroll
    for (int kq = 0; kq < 4; ++kq)
        for (int q = tid; q < NP_; q += 256) {
            short8 v = *(const short8*)(vf + ((size_t)kq * NP_ + q) * 8);
#pragma unroll
            for (int j = 0; j < 8; ++j) Vl[(kq * 8 + j) * 288 + q] = v[j];
        }
    for (int idx = tid; idx < 512; idx += 256) {       // zero V cols 272..287
        int d = idx >> 4, c = idx & 15;
        Vl[d * 288 + 272 + c] = 0;
    }
    for (int idx = tid; idx < 128; idx += 256) {       // zero P pad chunks (kq 34,35)
        int w = idx >> 5, t = idx & 31;
        short8 z = {};
        *(short8*)(Pl + w * 4608 + 34 * 128 + t * 8) = z;
    }
    __syncthreads();
    int wv = tid >> 6, lane = tid & 63, lo = lane & 15, qd = lane >> 4;
    short* Pw = Pl + wv * 4608;
    const float scale = 0.17677669529663687f;
    for (int it = 0; it < 3; ++it) {
        int qt = it * 8 + half * 4 + wv;
        if (qt > 16) break;                            // wave-uniform
        short8 qfr = *(const short8*)(qf + ((size_t)qd * NP_ + qt * 16 + lo) * 8);
        f32x4 sc[17];
#pragma unroll
        for (int kt = 0; kt < 17; ++kt) {
            short8 kfr = *(const short8*)(Kl + ((size_t)qd * NP_ + kt * 16 + lo) * 8);
            f32x4 z = {};
            sc[kt] = mfma16(qfr, kfr, z);
        }
        float mx[4] = {-1e30f, -1e30f, -1e30f, -1e30f};
#pragma unroll
        for (int kt = 0; kt < 17; ++kt) {
            bool valid = (kt * 16 + lo) < 257;
#pragma unroll
            for (int r = 0; r < 4; ++r) {
                float v2 = valid ? sc[kt][r] * scale : -1e30f;
                sc[kt][r] = v2;
                mx[r] = fmaxf(mx[r], v2);
            }
        }
#pragma unroll
        for (int r = 0; r < 4; ++r) {
            mx[r] = fmaxf(mx[r], __shfl_xor(mx[r], 1));
            mx[r] = fmaxf(mx[r], __shfl_xor(mx[r], 2));
            mx[r] = fmaxf(mx[r], __shfl_xor(mx[r], 4));
            mx[r] = fmaxf(mx[r], __shfl_xor(mx[r], 8));
        }
        float l[4] = {0.f, 0.f, 0.f, 0.f};
#pragma unroll
        for (int kt = 0; kt < 17; ++kt)
#pragma unroll
            for (int r = 0; r < 4; ++r) {
                float p = __expf(sc[kt][r] - mx[r]);
                sc[kt][r] = p;
                l[r] += p;
            }
#pragma unroll
        for (int r = 0; r < 4; ++r) {
            l[r] += __shfl_xor(l[r], 1);
            l[r] += __shfl_xor(l[r], 2);
            l[r] += __shfl_xor(l[r], 4);
            l[r] += __shfl_xor(l[r], 8);
        }
        float rl[4];
#pragma unroll
        for (int r = 0; r < 4; ++r) rl[r] = 1.f / l[r];
#pragma unroll
        for (int kt = 0; kt < 17; ++kt)
#pragma unroll
            for (int r = 0; r < 4; ++r) {
                int key = kt * 16 + lo;
                Pw[((key >> 3) * 16 + qd * 4 + r) * 8 + (key & 7)] = f2bs(sc[kt][r] * rl[r]);
            }
        f32x4 oa[2] = {};
#pragma unroll
        for (int ks = 0; ks < 9; ++ks) {
            short8 pf = *(const short8*)(Pw + ((ks * 4 + qd) * 16 + lo) * 8);
#pragma unroll
            for (int nt = 0; nt < 2; ++nt) {
                short8 vfr = *(const short8*)(Vl + (nt * 16 + lo) * 288 + ks * 32 + qd * 8);
                oa[nt] = mfma16(pf, vfr, oa[nt]);
            }
        }
        int tile = b * TPB_ + qt;
#pragma unroll
        for (int nt = 0; nt < 2; ++nt)
#pragma unroll
            for (int r = 0; r < 4; ++r) {
                int qq = qt * 16 + qd * 4 + r;
                if (qq <= 256) {
                    int col = h * 32 + nt * 16 + lo;
                    Of[(size_t)tile * 2048 + (col >> 3) * 128 + (qd * 4 + r) * 8 + (col & 7)] = f2bs(oa[nt][r]);
                }
            }
    }
}

// final LN (token 0 only, eps 1e-6) + fc head
__global__ __launch_bounds__(64) void final_head(const float* __restrict__ X, const float* __restrict__ fs,
                                                 const float* __restrict__ fb, const float* __restrict__ fcw,
                                                 const float* __restrict__ fcb, float* __restrict__ out) {
    int b = blockIdx.x, lane = threadIdx.x;
    float2 v = *(const float2*)(X + (size_t)b * NP_ * 128 + lane * 2);
    float sum = v.x + v.y;
#pragma unroll
    for (int m = 1; m < 64; m <<= 1) sum += __shfl_xor(sum, m);
    float mean = sum * (1.f / 128.f);
    float d0 = v.x - mean, d1 = v.y - mean;
    float vs = d0 * d0 + d1 * d1;
#pragma unroll
    for (int m = 1; m < 64; m <<= 1) vs += __shfl_xor(vs, m);
    float rs = rsqrtf(vs * (1.f / 128.f) + 1e-6f);
    int e = lane * 2;
    float f0 = d0 * rs * fs[e] + fb[e];
    float f1 = d1 * rs * fs[e + 1] + fb[e + 1];
    out[128 + b * 128 + e] = f0;
    out[128 + b * 128 + e + 1] = f1;
    float p0 = f0 * fcw[e] + f1 * fcw[e + 1];
    float p1 = f0 * fcw[128 + e] + f1 * fcw[128 + e + 1];
#pragma unroll
    for (int m = 1; m < 64; m <<= 1) {
        p0 += __shfl_xor(p0, m);
        p1 += __shfl_xor(p1, m);
    }
    if (lane == 0) {
        out[b * 2 + 0] = p0 + fcb[0];
        out[b * 2 + 1] = p1 + fcb[1];
    }
}

extern "C" void kernel_launch(void* const* d_in, const int* in_sizes, int n_in,
                              void* d_out, int out_size, void* d_ws, size_t ws_size,
                              hipStream_t stream) {
    const float* feat    = (const float*)d_in[0];
    const float* conv_w  = (const float*)d_in[1];
    const float* conv_b  = (const float*)d_in[2];
    const float* pos_emb = (const float*)d_in[3];
    const float* cls_tok = (const float*)d_in[4];
    const float* ln1_s   = (const float*)d_in[5];
    const float* ln1_b   = (const float*)d_in[6];
    const float* qkv_w   = (const float*)d_in[7];
    const float* qkv_b   = (const float*)d_in[8];
    const float* proj_w  = (const float*)d_in[9];
    const float* proj_b  = (const float*)d_in[10];
    const float* ln2_s   = (const float*)d_in[11];
    const float* ln2_b   = (const float*)d_in[12];
    const float* ffn1_w  = (const float*)d_in[13];
    const float* ffn1_b  = (const float*)d_in[14];
    const float* ffn2_w  = (const float*)d_in[15];
    const float* ffn2_b  = (const float*)d_in[16];
    const float* fn_s    = (const float*)d_in[17];
    const float* fn_b    = (const float*)d_in[18];
    const float* fc_w    = (const float*)d_in[19];
    const float* fc_b    = (const float*)d_in[20];

    char* p = (char*)d_ws;
    auto alloc = [&](size_t bytes) { char* r = p; p += (bytes + 255) & ~(size_t)255; return r; };
    short* wq  = (short*)alloc((size_t)589824 * 2);
    short* wp  = (short*)alloc((size_t)196608 * 2);
    short* w1  = (short*)alloc((size_t)786432 * 2);
    short* w2  = (short*)alloc((size_t)786432 * 2);
    short* wc  = (short*)alloc((size_t)294912 * 2);
    short* fpd = (short*)alloc((size_t)64 * 34 * 34 * 256 * 2);
    float* X   = (float*)alloc((size_t)MP_ * 128 * 4);
    short* Qf  = (short*)alloc((size_t)64 * 16 * NP_ * 8 * 2);
    short* Kf  = (short*)alloc((size_t)64 * 16 * NP_ * 8 * 2);
    short* Vf  = (short*)alloc((size_t)64 * 16 * NP_ * 8 * 2);
    short* Of  = (short*)alloc((size_t)(MP_ / 16) * 2048 * 2);
    short* Hf  = (short*)alloc((size_t)(MP_ / 16) * 2048 * 2);

    hipMemsetAsync(fpd, 0, (size_t)64 * 34 * 34 * 256 * 2, stream);
    repack_w<<<2304, 256, 0, stream>>>(qkv_w, wq, 384, 128, 589824);
    repack_w<<<768, 256, 0, stream>>>(proj_w, wp, 128, 128, 196608);
    repack_w<<<3072, 256, 0, stream>>>(ffn1_w, w1, 512, 128, 786432);
    repack_w<<<3072, 256, 0, stream>>>(ffn2_w, w2, 128, 512, 786432);
    conv_w_perm<<<1152, 256, 0, stream>>>(conv_w, wc);
    feat_nhwc<<<64 * 32, 256, 0, stream>>>(feat, fpd);
    conv_gemm<<<1024, 256, 0, stream>>>(fpd, wc, conv_b, pos_emb, X);
    cls_init<<<64, 256, 0, stream>>>(cls_tok, pos_emb, X);

    qkv0<<<544, 512, 0, stream>>>(X, wq, qkv_b, ln1_s, ln1_b, Qf, Kf, Vf);
    for (int l = 0; l < 12; ++l) {
        attn<<<512, 256, 0, stream>>>(Qf, Kf, Vf, Of);
        tail_a<<<544, 256, 0, stream>>>(Of, wp + (size_t)l * 16384, proj_b + l * 128,
                                        ln2_s + l * 128, ln2_b + l * 128, X, Hf);
        if (l < 11)
            tail_b<0><<<544, 512, 0, stream>>>(Hf, w1 + (size_t)l * 65536, ffn1_b + l * 512,
                                               w2 + (size_t)l * 65536, ffn2_b + l * 128, X,
                                               ln1_s + (l + 1) * 128, ln1_b + (l + 1) * 128,
                                               wq + (size_t)(l + 1) * 49152, qkv_b + (l + 1) * 384,
                                               Qf, Kf, Vf);
        else
            tail_b<1><<<544, 512, 0, stream>>>(Hf, w1 + (size_t)l * 65536, ffn1_b + l * 512,
                                               w2 + (size_t)l * 65536, ffn2_b + l * 128, X,
                                               ln1_s, ln1_b, wq, qkv_b, Qf, Kf, Vf);
    }
    final_head<<<64, 64, 0, stream>>>(X, fn_s, fn_b, fc_w, fc_b, (float*)d_out);
}

// Round 7
// 864.244 us; speedup vs baseline: 2.2352x; 1.0071x over previous
//
#include <hip/hip_runtime.h>
#include <math.h>

// ---------------- dims ----------------
constexpr int NP_ = 272;               // padded tokens per batch (17 tiles of 16)
constexpr int MP_ = 64 * NP_;          // 17408 padded rows
constexpr int TPB_ = 17;               // tiles per batch

typedef short short8 __attribute__((ext_vector_type(8)));
typedef float f32x4 __attribute__((ext_vector_type(4)));

__device__ inline short f2bs(float f) {  // float -> bf16 bits, RNE
    unsigned u = __builtin_bit_cast(unsigned, f);
    unsigned r = (u + 0x7fffu + ((u >> 16) & 1u)) >> 16;
    return (short)r;
}

__device__ inline f32x4 mfma16(short8 a, short8 b, f32x4 c) {
    return __builtin_amdgcn_mfma_f32_16x16x32_bf16(a, b, c, 0, 0, 0);
}

// ---------------- one-shot weight repack (all weights, one kernel) ----------------
// packed layout: [l][(k/8)][n][8] bf16;  conv: [(kykx*8+cs)*4+qd][col][8]
__global__ void repack_all(const float* __restrict__ qkvw, const float* __restrict__ projw,
                           const float* __restrict__ f1w, const float* __restrict__ f2w,
                           const float* __restrict__ convw,
                           short* __restrict__ wq, short* __restrict__ wp,
                           short* __restrict__ w1, short* __restrict__ w2,
                           short* __restrict__ wc) {
    int o = blockIdx.x * 256 + threadIdx.x;
    if (o < 589824) {                                  // qkv: Nn=384 K=128
        int l = o / 49152, r = o % 49152;
        int chunk = r / 3072, w = r % 3072;
        int n = w >> 3, k = chunk * 8 + (w & 7);
        wq[o] = f2bs(qkvw[(size_t)l * 49152 + n * 128 + k]);
        return;
    }
    o -= 589824;
    if (o < 196608) {                                  // proj: 128x128
        int l = o / 16384, r = o % 16384;
        int chunk = r / 1024, w = r % 1024;
        int n = w >> 3, k = chunk * 8 + (w & 7);
        wp[o] = f2bs(projw[(size_t)l * 16384 + n * 128 + k]);
        return;
    }
    o -= 196608;
    if (o < 786432) {                                  // ffn1: Nn=512 K=128
        int l = o / 65536, r = o % 65536;
        int chunk = r / 4096, w = r % 4096;
        int n = w >> 3, k = chunk * 8 + (w & 7);
        w1[o] = f2bs(f1w[(size_t)l * 65536 + n * 128 + k]);
        return;
    }
    o -= 786432;
    if (o < 786432) {                                  // ffn2: Nn=128 K=512
        int l = o / 65536, r = o % 65536;
        int chunk = r / 1024, w = r % 1024;
        int n = w >> 3, k = chunk * 8 + (w & 7);
        w2[o] = f2bs(f2w[(size_t)l * 65536 + n * 512 + k]);
        return;
    }
    o -= 786432;
    if (o < 294912) {                                  // conv
        int j = o & 7;
        int col = (o >> 3) & 127;
        int c = o >> 10;
        int qd = c & 3, cscb = c >> 2;
        int cs = cscb & 7, kykx = cscb >> 3;
        int cin = cs * 32 + qd * 8 + j;
        int ky = kykx / 3, kx = kykx % 3;
        wc[o] = f2bs(convw[((col * 256 + cin) * 3 + ky) * 3 + kx]);
    }
}

// feat (B,CIN,32,32) fp32 -> fp[b][y+1][x+1][cin] bf16, border zeroed here (no memset)
__global__ __launch_bounds__(256) void feat_nhwc(const float* __restrict__ feat, short* __restrict__ fp) {
    __shared__ float tile[32][33];
    int b = blockIdx.x >> 5, y = blockIdx.x & 31;
    int t = threadIdx.x;
    for (int c0 = 0; c0 < 256; c0 += 32) {
        int ci = t >> 5, x = t & 31;
        for (int cc = ci; cc < 32; cc += 8)
            tile[cc][x] = feat[((size_t)(b * 256 + c0 + cc) * 32 + y) * 32 + x];
        __syncthreads();
        for (int i = t; i < 1024; i += 256) {
            int c = i & 31, x2 = i >> 5;
            fp[((size_t)(b * 34 + y + 1) * 34 + x2 + 1) * 256 + c0 + c] = f2bs(tile[c][x2]);
        }
        __syncthreads();
    }
    // border zeros: x=0 and x=33 of own row; rows 0 and 33 by y==0 / y==31 blocks
    short* rowp = fp + (size_t)(b * 34 + y + 1) * 34 * 256;
    for (int c = t; c < 256; c += 256) { rowp[c] = 0; rowp[33 * 256 + c] = 0; }
    if (y == 0) {
        short* r0 = fp + (size_t)(b * 34) * 34 * 256;
        for (int i = t; i < 34 * 256; i += 256) r0[i] = 0;
    }
    if (y == 31) {
        short* r33 = fp + (size_t)(b * 34 + 33) * 34 * 256;
        for (int i = t; i < 34 * 256; i += 256) r33[i] = 0;
    }
}

// conv as GEMM: block = (b, oy); 3 input rows staged in LDS (XOR-phase swizzle)
__global__ __launch_bounds__(256) void conv_gemm(const short* __restrict__ fp, const short* __restrict__ wr,
                                                 const float* __restrict__ cb, const float* __restrict__ pos,
                                                 float* __restrict__ X) {
    __shared__ __align__(16) short Ain[3 * 34 * 256];  // 51 KB
    int b = blockIdx.x >> 4, oy = blockIdx.x & 15;
    int tid = threadIdx.x;
    for (int idx = tid; idx < 3 * 34 * 32; idx += 256) {
        int r = idx / 1088, rem = idx - r * 1088;
        int x = rem >> 5, c = rem & 31;
        short8 v = *(const short8*)(fp + ((size_t)(b * 34 + 2 * oy + r) * 34 + x) * 256 + c * 8);
        *(short8*)(Ain + (r * 34 + x) * 256 + ((c ^ ((x >> 1) & 7)) * 8)) = v;
    }
    __syncthreads();
    int wave = tid >> 6, lane = tid & 63;
    int ng = wave, lo = lane & 15, qd = lane >> 4;
    f32x4 acc[2] = {};
#pragma unroll
    for (int ky = 0; ky < 3; ++ky)
#pragma unroll
        for (int kx = 0; kx < 3; ++kx) {
            int sx = 2 * lo + kx;
            int arow = (ky * 34 + sx) * 256;
            int sw = (sx >> 1) & 7;
            const short* wb = wr + (((size_t)((ky * 3 + kx) * 8) * 4 + qd) * 128 + ng * 32 + lo) * 8;
#pragma unroll
            for (int cs = 0; cs < 8; ++cs) {
                short8 af = *(const short8*)(Ain + arow + (((cs * 4 + qd) ^ sw) * 8));
                short8 b0 = *(const short8*)(wb + (size_t)cs * 4096);
                short8 b1 = *(const short8*)(wb + (size_t)cs * 4096 + 128);
                acc[0] = mfma16(af, b0, acc[0]);
                acc[1] = mfma16(af, b1, acc[1]);
            }
        }
#pragma unroll
    for (int t = 0; t < 2; ++t) {
        int e = ng * 32 + t * 16 + lo;
        float bias = cb[e];
#pragma unroll
        for (int r = 0; r < 4; ++r) {
            int tok = 1 + oy * 16 + qd * 4 + r;
            X[((size_t)b * NP_ + tok) * 128 + e] = acc[t][r] + bias + pos[tok * 128 + e];
        }
    }
}

// cls token + zero the pad rows (257..271) per batch
__global__ __launch_bounds__(256) void cls_init(const float* __restrict__ cls, const float* __restrict__ pos,
                                                float* __restrict__ X) {
    int b = blockIdx.x, tid = threadIdx.x;
    if (tid < 128) X[(size_t)b * NP_ * 128 + tid] = cls[tid] + pos[tid];
    for (int idx = tid; idx < 15 * 128; idx += 256)
        X[((size_t)b * NP_ + 257) * 128 + idx] = 0.f;
}

// LN of a 16-row LDS tile (stride 132) -> A-frag tile SB[kq(16)][m(16)][8]. 256 threads.
__device__ inline void ln_tile16(const float* Xl, const float* __restrict__ s, const float* __restrict__ bb,
                                 short* SB, int tid, float eps) {
    int wv = tid >> 6, lane = tid & 63;
    int r4 = lane & 3, c32 = lane >> 2;                // c32: 16 groups of 8 cols
    int row = wv * 4 + r4;                             // 0..15
    const float* xr = Xl + row * 132 + c32 * 8;
    float4 a = *(const float4*)(xr);
    float4 b = *(const float4*)(xr + 4);
    float v[8] = {a.x, a.y, a.z, a.w, b.x, b.y, b.z, b.w};
    float sum = v[0] + v[1] + v[2] + v[3] + v[4] + v[5] + v[6] + v[7];
    sum += __shfl_xor(sum, 4); sum += __shfl_xor(sum, 8);
    sum += __shfl_xor(sum, 16); sum += __shfl_xor(sum, 32);
    float mean = sum * (1.f / 128.f);
    float vs = 0.f;
#pragma unroll
    for (int j = 0; j < 8; ++j) { float d = v[j] - mean; vs += d * d; }
    vs += __shfl_xor(vs, 4); vs += __shfl_xor(vs, 8);
    vs += __shfl_xor(vs, 16); vs += __shfl_xor(vs, 32);
    float rs = rsqrtf(vs * (1.f / 128.f) + eps);
    float4 s0 = *(const float4*)(s + c32 * 8), s1 = *(const float4*)(s + c32 * 8 + 4);
    float4 b0 = *(const float4*)(bb + c32 * 8), b1 = *(const float4*)(bb + c32 * 8 + 4);
    float sv[8] = {s0.x, s0.y, s0.z, s0.w, s1.x, s1.y, s1.z, s1.w};
    float bv[8] = {b0.x, b0.y, b0.z, b0.w, b1.x, b1.y, b1.z, b1.w};
    short8 o;
#pragma unroll
    for (int j = 0; j < 8; ++j) o[j] = f2bs((v[j] - mean) * rs * sv[j] + bv[j]);
    *(short8*)(SB + (c32 * 16 + row) * 8) = o;
}

// qkv GEMM from SB frags (16 tokens) -> Qf/Kf (A-frag per (b,h)) and Vt ([d][q] per (b,h))
__device__ inline void qkv_stage16(const short* SB, const short* __restrict__ wq, const float* __restrict__ qb,
                                   int mg, int wv, int lo, int qd,
                                   short* __restrict__ Qf, short* __restrict__ Kf, short* __restrict__ Vt) {
    int n0 = wv * 96;
    f32x4 acc[6] = {};
#pragma unroll
    for (int ki = 0; ki < 4; ++ki) {
        int kq = ki * 4 + qd;
        short8 a = *(const short8*)(SB + (kq * 16 + lo) * 8);
#pragma unroll
        for (int t = 0; t < 6; ++t) {
            short8 bf = *(const short8*)(wq + ((size_t)kq * 384 + n0 + t * 16 + lo) * 8);
            acc[t] = mfma16(a, bf, acc[t]);
        }
    }
#pragma unroll
    for (int t = 0; t < 6; ++t) {
        int n = n0 + t * 16 + lo;
        float bvv = qb[n];
        int seg = n >> 7, m = n & 127, h = m >> 5, d = m & 31;
#pragma unroll
        for (int r = 0; r < 4; ++r) {
            int row = mg * 16 + qd * 4 + r;
            int bb2 = row / NP_, q = row - bb2 * NP_;
            short val = f2bs(acc[t][r] + bvv);
            if (seg == 2)
                Vt[((size_t)(bb2 * 4 + h) * 32 + d) * NP_ + q] = val;
            else
                (seg ? Kf : Qf)[((size_t)(bb2 * 4 + h) * 4 + (d >> 3)) * (NP_ * 8) + q * 8 + (d & 7)] = val;
        }
    }
}

// layer-0 qkv: LN1(X) -> frags -> qkv
__global__ __launch_bounds__(256, 4) void qkv0(const float* __restrict__ X, const short* __restrict__ wq,
                                               const float* __restrict__ qb, const float* __restrict__ ls,
                                               const float* __restrict__ lb,
                                               short* __restrict__ Qf, short* __restrict__ Kf,
                                               short* __restrict__ Vt) {
    __shared__ __align__(16) float Xl[16 * 132];
    __shared__ __align__(16) short SB[2048];
    int mg = blockIdx.x, tid = threadIdx.x;
    for (int idx = tid; idx < 512; idx += 256) {
        int tok = idx >> 5, c = idx & 31;
        *(float4*)(Xl + tok * 132 + c * 4) = *(const float4*)(X + (size_t)(mg * 16 + tok) * 128 + c * 4);
    }
    __syncthreads();
    ln_tile16(Xl, ls, lb, SB, tid, 1e-5f);
    __syncthreads();
    int wv = tid >> 6, lane = tid & 63;
    qkv_stage16(SB, wq, qb, mg, wv, lane & 15, lane >> 4, Qf, Kf, Vt);
}

// Fused layer tail, 16 tokens/block:
// proj(Of) + X -> LN2 -> ffn1+gelu (two 256-col halves through Uh) -> ffn2 + X -> LN1' -> qkv'
template <int LAST>
__global__ __launch_bounds__(256, 4) void layer_tail(
    const short* __restrict__ Of, const short* __restrict__ wp, const float* __restrict__ pb,
    const float* __restrict__ l2s, const float* __restrict__ l2b,
    const short* __restrict__ w1, const float* __restrict__ b1,
    const short* __restrict__ w2, const float* __restrict__ b2,
    float* __restrict__ X,
    const float* __restrict__ l1s, const float* __restrict__ l1b,
    const short* __restrict__ wq, const float* __restrict__ qb,
    short* __restrict__ Qf, short* __restrict__ Kf, short* __restrict__ Vt) {
    __shared__ __align__(16) short SB[2048];           // 4 KB: Of tile, then LN frag tile
    __shared__ __align__(16) float Xl[16 * 132];       // 8.4 KB
    __shared__ __align__(16) short Uh[32 * 136];       // 8.7 KB (half of U, padded chunks)
    int mg = blockIdx.x, tid = threadIdx.x;
    const short* osrc = Of + (size_t)mg * 2048;
    for (int idx = tid; idx < 256; idx += 256)
        *(short8*)(SB + idx * 8) = *(const short8*)(osrc + idx * 8);
    for (int idx = tid; idx < 512; idx += 256) {
        int tok = idx >> 5, c = idx & 31;
        *(float4*)(Xl + tok * 132 + c * 4) = *(const float4*)(X + (size_t)(mg * 16 + tok) * 128 + c * 4);
    }
    __syncthreads();
    int wv = tid >> 6, lane = tid & 63, lo = lane & 15, qd = lane >> 4;
    // ---- proj: wave owns 32 cols ----
    {
        int n0 = wv * 32;
        f32x4 pa[2] = {};
#pragma unroll
        for (int ki = 0; ki < 4; ++ki) {
            int kq = ki * 4 + qd;
            short8 a = *(const short8*)(SB + (kq * 16 + lo) * 8);
            short8 b0 = *(const short8*)(wp + ((size_t)kq * 128 + n0 + lo) * 8);
            short8 b1 = *(const short8*)(wp + ((size_t)kq * 128 + n0 + 16 + lo) * 8);
            pa[0] = mfma16(a, b0, pa[0]);
            pa[1] = mfma16(a, b1, pa[1]);
        }
        float pb0 = pb[n0 + lo], pb1 = pb[n0 + 16 + lo];
#pragma unroll
        for (int r = 0; r < 4; ++r) {
            Xl[(qd * 4 + r) * 132 + n0 + lo] += pa[0][r] + pb0;
            Xl[(qd * 4 + r) * 132 + n0 + 16 + lo] += pa[1][r] + pb1;
        }
    }
    __syncthreads();
    ln_tile16(Xl, l2s, l2b, SB, tid, 1e-5f);
    __syncthreads();
    // ---- ffn1/ffn2 in two 256-col halves ----
    f32x4 facc[2] = {};
#pragma unroll
    for (int hh = 0; hh < 2; ++hh) {
        {   // ffn1 half: wave owns 64 local cols
            int n0h = wv * 64;
            f32x4 fa[4] = {};
#pragma unroll
            for (int ki = 0; ki < 4; ++ki) {
                int kq = ki * 4 + qd;
                short8 a = *(const short8*)(SB + (kq * 16 + lo) * 8);
#pragma unroll
                for (int t = 0; t < 4; ++t) {
                    short8 bf = *(const short8*)(w1 + ((size_t)kq * 512 + hh * 256 + n0h + t * 16 + lo) * 8);
                    fa[t] = mfma16(a, bf, fa[t]);
                }
            }
#pragma unroll
            for (int t = 0; t < 4; ++t) {
                int nl = n0h + t * 16 + lo;            // 0..255 local
                float bvv = b1[hh * 256 + nl];
#pragma unroll
                for (int r = 0; r < 4; ++r) {
                    float x = fa[t][r] + bvv;
                    float u = x * (0.7978845608f + 0.0356774081f * x * x);
                    x = x / (1.f + __expf(-2.f * u));
                    Uh[(nl >> 3) * 136 + (qd * 4 + r) * 8 + (nl & 7)] = f2bs(x);
                }
            }
        }
        __syncthreads();
        {   // ffn2 half: wave owns 32 cols, local K=256
            int n0 = wv * 32;
#pragma unroll
            for (int ki = 0; ki < 8; ++ki) {
                int kq2 = ki * 4 + qd;
                short8 a = *(const short8*)(Uh + kq2 * 136 + lo * 8);
                short8 b0 = *(const short8*)(w2 + (((size_t)(hh * 32 + kq2)) * 128 + n0 + lo) * 8);
                short8 b1 = *(const short8*)(w2 + (((size_t)(hh * 32 + kq2)) * 128 + n0 + 16 + lo) * 8);
                facc[0] = mfma16(a, b0, facc[0]);
                facc[1] = mfma16(a, b1, facc[1]);
            }
        }
        if (hh == 0) __syncthreads();                  // before ffn1 h1 overwrites Uh
    }
    // ---- residual add (same lane ownership as proj epilogue) ----
    {
        int n0 = wv * 32;
        float b20 = b2[n0 + lo], b21 = b2[n0 + 16 + lo];
#pragma unroll
        for (int r = 0; r < 4; ++r) {
            Xl[(qd * 4 + r) * 132 + n0 + lo] += facc[0][r] + b20;
            Xl[(qd * 4 + r) * 132 + n0 + 16 + lo] += facc[1][r] + b21;
        }
    }
    __syncthreads();
    for (int idx = tid; idx < 512; idx += 256) {
        int tok = idx >> 5, c = idx & 31;
        *(float4*)(X + (size_t)(mg * 16 + tok) * 128 + c * 4) = *(const float4*)(Xl + tok * 132 + c * 4);
    }
    if (LAST) return;
    ln_tile16(Xl, l1s, l1b, SB, tid, 1e-5f);
    __syncthreads();
    qkv_stage16(SB, wq, qb, mg, wv, lo, qd, Qf, Kf, Vt);
}

// Fused attention: block = (b,h,half). K/Q frags direct from global (L1/L2);
// V staged to LDS (stride 296); P round-trips through a 1KB per-wave chunk buffer.
__global__ __launch_bounds__(256, 4) void attn(const short* __restrict__ Qf, const short* __restrict__ Kf,
                                               const short* __restrict__ Vt, short* __restrict__ Of) {
    __shared__ __align__(16) short Vl[32 * 296];       // 18.9 KB
    __shared__ __align__(16) short Pl[4][544];         // per-wave 32-key chunk (A-frag), padded
    int b = blockIdx.x >> 3, h = (blockIdx.x >> 1) & 3, half = blockIdx.x & 1;
    int tid = threadIdx.x;
    const short* kf = Kf + (size_t)(b * 4 + h) * (4 * NP_ * 8);
    const short* qf = Qf + (size_t)(b * 4 + h) * (4 * NP_ * 8);
    const short* vt = Vt + (size_t)(b * 4 + h) * (32 * NP_);
    for (int idx = tid; idx < 32 * 37; idx += 256) {
        int d = idx / 37, c8 = idx - d * 37;
        short8 v = {};
        if (c8 < 34) v = *(const short8*)(vt + d * NP_ + c8 * 8);
        *(short8*)(Vl + d * 296 + c8 * 8) = v;
    }
    __syncthreads();
    int wv = tid >> 6, lane = tid & 63, lo = lane & 15, qd = lane >> 4;
    short* Pw = Pl[wv];
    const float scale = 0.17677669529663687f;
    for (int it = 0; it < 3; ++it) {
        int qt = it * 8 + half * 4 + wv;
        if (qt > 16) break;                            // wave-uniform
        short8 qfr = *(const short8*)(qf + ((size_t)qd * NP_ + qt * 16 + lo) * 8);
        f32x4 sc[17];
#pragma unroll
        for (int kt = 0; kt < 17; ++kt) {
            short8 kfr = *(const short8*)(kf + ((size_t)qd * NP_ + kt * 16 + lo) * 8);
            f32x4 z = {};
            sc[kt] = mfma16(qfr, kfr, z);
        }
        float mx[4] = {-1e30f, -1e30f, -1e30f, -1e30f};
#pragma unroll
        for (int kt = 0; kt < 17; ++kt) {
            bool valid = (kt * 16 + lo) < 257;
#pragma unroll
            for (int r = 0; r < 4; ++r) {
                float v2 = valid ? sc[kt][r] * scale : -1e30f;
                sc[kt][r] = v2;
                mx[r] = fmaxf(mx[r], v2);
            }
        }
#pragma unroll
        for (int r = 0; r < 4; ++r) {
            mx[r] = fmaxf(mx[r], __shfl_xor(mx[r], 1));
            mx[r] = fmaxf(mx[r], __shfl_xor(mx[r], 2));
            mx[r] = fmaxf(mx[r], __shfl_xor(mx[r], 4));
            mx[r] = fmaxf(mx[r], __shfl_xor(mx[r], 8));
        }
        float l[4] = {0.f, 0.f, 0.f, 0.f};
#pragma unroll
        for (int kt = 0; kt < 17; ++kt)
#pragma unroll
            for (int r = 0; r < 4; ++r) {
                float p = __expf(sc[kt][r] - mx[r]);
                sc[kt][r] = p;
                l[r] += p;
            }
#pragma unroll
        for (int r = 0; r < 4; ++r) {
            l[r] += __shfl_xor(l[r], 1);
            l[r] += __shfl_xor(l[r], 2);
            l[r] += __shfl_xor(l[r], 4);
            l[r] += __shfl_xor(l[r], 8);
        }
        float rl[4];
#pragma unroll
        for (int r = 0; r < 4; ++r) rl[r] = 1.f / l[r];
        f32x4 oa[2] = {};
#pragma unroll
        for (int ks = 0; ks < 9; ++ks) {
            // write this 32-key P chunk in A-frag layout (same-wave, no barrier)
#pragma unroll
            for (int kt2 = 0; kt2 < 2; ++kt2) {
                int kt = ks * 2 + kt2;
                int lkey = kt2 * 16 + lo;
#pragma unroll
                for (int r = 0; r < 4; ++r) {
                    short pv = (kt < 17) ? f2bs(sc[kt][r] * rl[r]) : (short)0;
                    Pw[(lkey >> 3) * 128 + (qd * 4 + r) * 8 + (lkey & 7)] = pv;
                }
            }
            short8 pf = *(const short8*)(Pw + (qd * 16 + lo) * 8);
#pragma unroll
            for (int nt = 0; nt < 2; ++nt) {
                short8 vfr = *(const short8*)(Vl + (nt * 16 + lo) * 296 + ks * 32 + qd * 8);
                oa[nt] = mfma16(pf, vfr, oa[nt]);
            }
        }
        int tile = b * TPB_ + qt;
#pragma unroll
        for (int nt = 0; nt < 2; ++nt)
#pragma unroll
            for (int r = 0; r < 4; ++r) {
                int qq = qt * 16 + qd * 4 + r;
                if (qq <= 256) {
                    int col = h * 32 + nt * 16 + lo;
                    Of[(size_t)tile * 2048 + (col >> 3) * 128 + (qd * 4 + r) * 8 + (col & 7)] = f2bs(oa[nt][r]);
                }
            }
    }
}

// final LN (token 0 only, eps 1e-6) + fc head
__global__ __launch_bounds__(64) void final_head(const float* __restrict__ X, const float* __restrict__ fs,
                                                 const float* __restrict__ fb, const float* __restrict__ fcw,
                                                 const float* __restrict__ fcb, float* __restrict__ out) {
    int b = blockIdx.x, lane = threadIdx.x;
    float2 v = *(const float2*)(X + (size_t)b * NP_ * 128 + lane * 2);
    float sum = v.x + v.y;
#pragma unroll
    for (int m = 1; m < 64; m <<= 1) sum += __shfl_xor(sum, m);
    float mean = sum * (1.f / 128.f);
    float d0 = v.x - mean, d1 = v.y - mean;
    float vs = d0 * d0 + d1 * d1;
#pragma unroll
    for (int m = 1; m < 64; m <<= 1) vs += __shfl_xor(vs, m);
    float rs = rsqrtf(vs * (1.f / 128.f) + 1e-6f);
    int e = lane * 2;
    float f0 = d0 * rs * fs[e] + fb[e];
    float f1 = d1 * rs * fs[e + 1] + fb[e + 1];
    out[128 + b * 128 + e] = f0;
    out[128 + b * 128 + e + 1] = f1;
    float p0 = f0 * fcw[e] + f1 * fcw[e + 1];
    float p1 = f0 * fcw[128 + e] + f1 * fcw[128 + e + 1];
#pragma unroll
    for (int m = 1; m < 64; m <<= 1) {
        p0 += __shfl_xor(p0, m);
        p1 += __shfl_xor(p1, m);
    }
    if (lane == 0) {
        out[b * 2 + 0] = p0 + fcb[0];
        out[b * 2 + 1] = p1 + fcb[1];
    }
}

extern "C" void kernel_launch(void* const* d_in, const int* in_sizes, int n_in,
                              void* d_out, int out_size, void* d_ws, size_t ws_size,
                              hipStream_t stream) {
    const float* feat    = (const float*)d_in[0];
    const float* conv_w  = (const float*)d_in[1];
    const float* conv_b  = (const float*)d_in[2];
    const float* pos_emb = (const float*)d_in[3];
    const float* cls_tok = (const float*)d_in[4];
    const float* ln1_s   = (const float*)d_in[5];
    const float* ln1_b   = (const float*)d_in[6];
    const float* qkv_w   = (const float*)d_in[7];
    const float* qkv_b   = (const float*)d_in[8];
    const float* proj_w  = (const float*)d_in[9];
    const float* proj_b  = (const float*)d_in[10];
    const float* ln2_s   = (const float*)d_in[11];
    const float* ln2_b   = (const float*)d_in[12];
    const float* ffn1_w  = (const float*)d_in[13];
    const float* ffn1_b  = (const float*)d_in[14];
    const float* ffn2_w  = (const float*)d_in[15];
    const float* ffn2_b  = (const float*)d_in[16];
    const float* fn_s    = (const float*)d_in[17];
    const float* fn_b    = (const float*)d_in[18];
    const float* fc_w    = (const float*)d_in[19];
    const float* fc_b    = (const float*)d_in[20];

    char* p = (char*)d_ws;
    auto alloc = [&](size_t bytes) { char* r = p; p += (bytes + 255) & ~(size_t)255; return r; };
    short* wq  = (short*)alloc((size_t)589824 * 2);
    short* wp  = (short*)alloc((size_t)196608 * 2);
    short* w1  = (short*)alloc((size_t)786432 * 2);
    short* w2  = (short*)alloc((size_t)786432 * 2);
    short* wc  = (short*)alloc((size_t)294912 * 2);
    short* fpd = (short*)alloc((size_t)64 * 34 * 34 * 256 * 2);
    float* X   = (float*)alloc((size_t)MP_ * 128 * 4);
    short* Qf  = (short*)alloc((size_t)64 * 16 * NP_ * 8 * 2);
    short* Kf  = (short*)alloc((size_t)64 * 16 * NP_ * 8 * 2);
    short* Vt  = (short*)alloc((size_t)64 * 4 * 32 * NP_ * 2);
    short* Of  = (short*)alloc((size_t)(MP_ / 16) * 2048 * 2);

    repack_all<<<10368, 256, 0, stream>>>(qkv_w, proj_w, ffn1_w, ffn2_w, conv_w, wq, wp, w1, w2, wc);
    feat_nhwc<<<64 * 32, 256, 0, stream>>>(feat, fpd);
    conv_gemm<<<1024, 256, 0, stream>>>(fpd, wc, conv_b, pos_emb, X);
    cls_init<<<64, 256, 0, stream>>>(cls_tok, pos_emb, X);

    qkv0<<<1088, 256, 0, stream>>>(X, wq, qkv_b, ln1_s, ln1_b, Qf, Kf, Vt);
    for (int l = 0; l < 12; ++l) {
        attn<<<512, 256, 0, stream>>>(Qf, Kf, Vt, Of);
        if (l < 11)
            layer_tail<0><<<1088, 256, 0, stream>>>(Of, wp + (size_t)l * 16384, proj_b + l * 128,
                                                    ln2_s + l * 128, ln2_b + l * 128,
                                                    w1 + (size_t)l * 65536, ffn1_b + l * 512,
                                                    w2 + (size_t)l * 65536, ffn2_b + l * 128, X,
                                                    ln1_s + (l + 1) * 128, ln1_b + (l + 1) * 128,
                                                    wq + (size_t)(l + 1) * 49152, qkv_b + (l + 1) * 384,
                                                    Qf, Kf, Vt);
        else
            layer_tail<1><<<1088, 256, 0, stream>>>(Of, wp + (size_t)l * 16384, proj_b + l * 128,
                                                    ln2_s + l * 128, ln2_b + l * 128,
                                                    w1 + (size_t)l * 65536, ffn1_b + l * 512,
                                                    w2 + (size_t)l * 65536, ffn2_b + l * 128, X,
                                                    ln1_s, ln1_b, wq, qkv_b, Qf, Kf, Vt);
    }
    final_head<<<64, 64, 0, stream>>>(X, fn_s, fn_b, fc_w, fc_b, (float*)d_out);
}

// Round 8
// 807.821 us; speedup vs baseline: 2.3913x; 1.0698x over previous
//
#include <hip/hip_runtime.h>
#include <math.h>

// ---------------- dims ----------------
constexpr int NP_ = 272;               // padded tokens per batch (17 tiles of 16)
constexpr int MP_ = 64 * NP_;          // 17408 padded rows
constexpr int TPB_ = 17;               // tiles per batch

typedef short short8 __attribute__((ext_vector_type(8)));
typedef float f32x4 __attribute__((ext_vector_type(4)));

__device__ inline short f2bs(float f) {  // float -> bf16 bits, RNE
    unsigned u = __builtin_bit_cast(unsigned, f);
    unsigned r = (u + 0x7fffu + ((u >> 16) & 1u)) >> 16;
    return (short)r;
}

__device__ inline f32x4 mfma16(short8 a, short8 b, f32x4 c) {
    return __builtin_amdgcn_mfma_f32_16x16x32_bf16(a, b, c, 0, 0, 0);
}

// ---------------- one-shot weight repack ----------------
__global__ void repack_all(const float* __restrict__ qkvw, const float* __restrict__ projw,
                           const float* __restrict__ f1w, const float* __restrict__ f2w,
                           const float* __restrict__ convw,
                           short* __restrict__ wq, short* __restrict__ wp,
                           short* __restrict__ w1, short* __restrict__ w2,
                           short* __restrict__ wc) {
    int o = blockIdx.x * 256 + threadIdx.x;
    if (o < 589824) {                                  // qkv: Nn=384 K=128
        int l = o / 49152, r = o % 49152;
        int chunk = r / 3072, w = r % 3072;
        int n = w >> 3, k = chunk * 8 + (w & 7);
        wq[o] = f2bs(qkvw[(size_t)l * 49152 + n * 128 + k]);
        return;
    }
    o -= 589824;
    if (o < 196608) {                                  // proj: 128x128
        int l = o / 16384, r = o % 16384;
        int chunk = r / 1024, w = r % 1024;
        int n = w >> 3, k = chunk * 8 + (w & 7);
        wp[o] = f2bs(projw[(size_t)l * 16384 + n * 128 + k]);
        return;
    }
    o -= 196608;
    if (o < 786432) {                                  // ffn1: Nn=512 K=128
        int l = o / 65536, r = o % 65536;
        int chunk = r / 4096, w = r % 4096;
        int n = w >> 3, k = chunk * 8 + (w & 7);
        w1[o] = f2bs(f1w[(size_t)l * 65536 + n * 128 + k]);
        return;
    }
    o -= 786432;
    if (o < 786432) {                                  // ffn2: Nn=128 K=512
        int l = o / 65536, r = o % 65536;
        int chunk = r / 1024, w = r % 1024;
        int n = w >> 3, k = chunk * 8 + (w & 7);
        w2[o] = f2bs(f2w[(size_t)l * 65536 + n * 512 + k]);
        return;
    }
    o -= 786432;
    if (o < 294912) {                                  // conv
        int j = o & 7;
        int col = (o >> 3) & 127;
        int c = o >> 10;
        int qd = c & 3, cscb = c >> 2;
        int cs = cscb & 7, kykx = cscb >> 3;
        int cin = cs * 32 + qd * 8 + j;
        int ky = kykx / 3, kx = kykx % 3;
        wc[o] = f2bs(convw[((col * 256 + cin) * 3 + ky) * 3 + kx]);
    }
}

// feat (B,CIN,32,32) fp32 -> fp[b][y+1][x+1][cin] bf16, border zeroed here
__global__ __launch_bounds__(256) void feat_nhwc(const float* __restrict__ feat, short* __restrict__ fp) {
    __shared__ float tile[32][33];
    int b = blockIdx.x >> 5, y = blockIdx.x & 31;
    int t = threadIdx.x;
    for (int c0 = 0; c0 < 256; c0 += 32) {
        int ci = t >> 5, x = t & 31;
        for (int cc = ci; cc < 32; cc += 8)
            tile[cc][x] = feat[((size_t)(b * 256 + c0 + cc) * 32 + y) * 32 + x];
        __syncthreads();
        for (int i = t; i < 1024; i += 256) {
            int c = i & 31, x2 = i >> 5;
            fp[((size_t)(b * 34 + y + 1) * 34 + x2 + 1) * 256 + c0 + c] = f2bs(tile[c][x2]);
        }
        __syncthreads();
    }
    short* rowp = fp + (size_t)(b * 34 + y + 1) * 34 * 256;
    for (int c = t; c < 256; c += 256) { rowp[c] = 0; rowp[33 * 256 + c] = 0; }
    if (y == 0) {
        short* r0 = fp + (size_t)(b * 34) * 34 * 256;
        for (int i = t; i < 34 * 256; i += 256) r0[i] = 0;
    }
    if (y == 31) {
        short* r33 = fp + (size_t)(b * 34 + 33) * 34 * 256;
        for (int i = t; i < 34 * 256; i += 256) r33[i] = 0;
    }
}

// conv as GEMM: block = (b, oy); 3 input rows staged in LDS (XOR-phase swizzle); cls/pad init folded in
__global__ __launch_bounds__(256) void conv_gemm(const short* __restrict__ fp, const short* __restrict__ wr,
                                                 const float* __restrict__ cb, const float* __restrict__ pos,
                                                 const float* __restrict__ cls, float* __restrict__ X) {
    __shared__ __align__(16) short Ain[3 * 34 * 256];  // 51 KB
    int b = blockIdx.x >> 4, oy = blockIdx.x & 15;
    int tid = threadIdx.x;
    for (int idx = tid; idx < 3 * 34 * 32; idx += 256) {
        int r = idx / 1088, rem = idx - r * 1088;
        int x = rem >> 5, c = rem & 31;
        short8 v = *(const short8*)(fp + ((size_t)(b * 34 + 2 * oy + r) * 34 + x) * 256 + c * 8);
        *(short8*)(Ain + (r * 34 + x) * 256 + ((c ^ ((x >> 1) & 7)) * 8)) = v;
    }
    __syncthreads();
    int wave = tid >> 6, lane = tid & 63;
    int ng = wave, lo = lane & 15, qd = lane >> 4;
    f32x4 acc[2] = {};
#pragma unroll
    for (int ky = 0; ky < 3; ++ky)
#pragma unroll
        for (int kx = 0; kx < 3; ++kx) {
            int sx = 2 * lo + kx;
            int arow = (ky * 34 + sx) * 256;
            int sw = (sx >> 1) & 7;
            const short* wb = wr + (((size_t)((ky * 3 + kx) * 8) * 4 + qd) * 128 + ng * 32 + lo) * 8;
#pragma unroll
            for (int cs = 0; cs < 8; ++cs) {
                short8 af = *(const short8*)(Ain + arow + (((cs * 4 + qd) ^ sw) * 8));
                short8 b0 = *(const short8*)(wb + (size_t)cs * 4096);
                short8 b1 = *(const short8*)(wb + (size_t)cs * 4096 + 128);
                acc[0] = mfma16(af, b0, acc[0]);
                acc[1] = mfma16(af, b1, acc[1]);
            }
        }
#pragma unroll
    for (int t = 0; t < 2; ++t) {
        int e = ng * 32 + t * 16 + lo;
        float bias = cb[e];
#pragma unroll
        for (int r = 0; r < 4; ++r) {
            int tok = 1 + oy * 16 + qd * 4 + r;
            X[((size_t)b * NP_ + tok) * 128 + e] = acc[t][r] + bias + pos[tok * 128 + e];
        }
    }
    if (oy == 0) {                                     // cls token + pad rows
        if (tid < 128) X[(size_t)b * NP_ * 128 + tid] = cls[tid] + pos[tid];
        for (int idx = tid; idx < 15 * 128; idx += 256)
            X[((size_t)b * NP_ + 257) * 128 + idx] = 0.f;
    }
}

// LN of a 16-row LDS tile (stride 132) -> A-frag tile SB[kq(16)][m(16)][8]. 256 threads.
__device__ inline void ln_tile16(const float* Xl, const float* __restrict__ s, const float* __restrict__ bb,
                                 short* SB, int tid, float eps) {
    int wv = tid >> 6, lane = tid & 63;
    int r4 = lane & 3, c32 = lane >> 2;
    int row = wv * 4 + r4;
    const float* xr = Xl + row * 132 + c32 * 8;
    float4 a = *(const float4*)(xr);
    float4 b = *(const float4*)(xr + 4);
    float v[8] = {a.x, a.y, a.z, a.w, b.x, b.y, b.z, b.w};
    float sum = v[0] + v[1] + v[2] + v[3] + v[4] + v[5] + v[6] + v[7];
    sum += __shfl_xor(sum, 4); sum += __shfl_xor(sum, 8);
    sum += __shfl_xor(sum, 16); sum += __shfl_xor(sum, 32);
    float mean = sum * (1.f / 128.f);
    float vs = 0.f;
#pragma unroll
    for (int j = 0; j < 8; ++j) { float d = v[j] - mean; vs += d * d; }
    vs += __shfl_xor(vs, 4); vs += __shfl_xor(vs, 8);
    vs += __shfl_xor(vs, 16); vs += __shfl_xor(vs, 32);
    float rs = rsqrtf(vs * (1.f / 128.f) + eps);
    float4 s0 = *(const float4*)(s + c32 * 8), s1 = *(const float4*)(s + c32 * 8 + 4);
    float4 b0 = *(const float4*)(bb + c32 * 8), b1 = *(const float4*)(bb + c32 * 8 + 4);
    float sv[8] = {s0.x, s0.y, s0.z, s0.w, s1.x, s1.y, s1.z, s1.w};
    float bv[8] = {b0.x, b0.y, b0.z, b0.w, b1.x, b1.y, b1.z, b1.w};
    short8 o;
#pragma unroll
    for (int j = 0; j < 8; ++j) o[j] = f2bs((v[j] - mean) * rs * sv[j] + bv[j]);
    *(short8*)(SB + (c32 * 16 + row) * 8) = o;
}

// qkv GEMM from SB frags; ki=0 B-frags come prefetched in pre[6]
__device__ inline void qkv_stage16(const short* SB, const short* __restrict__ wq, const float* __restrict__ qb,
                                   const short8* pre, int mg, int wv, int lo, int qd,
                                   short* __restrict__ Qf, short* __restrict__ Kf, short* __restrict__ Vt) {
    int n0 = wv * 96;
    f32x4 acc[6] = {};
#pragma unroll
    for (int ki = 0; ki < 4; ++ki) {
        int kq = ki * 4 + qd;
        short8 a = *(const short8*)(SB + (kq * 16 + lo) * 8);
#pragma unroll
        for (int t = 0; t < 6; ++t) {
            short8 bf = (ki == 0) ? pre[t]
                                  : *(const short8*)(wq + ((size_t)kq * 384 + n0 + t * 16 + lo) * 8);
            acc[t] = mfma16(a, bf, acc[t]);
        }
    }
#pragma unroll
    for (int t = 0; t < 6; ++t) {
        int n = n0 + t * 16 + lo;
        float bvv = qb[n];
        int seg = n >> 7, m = n & 127, h = m >> 5, d = m & 31;
#pragma unroll
        for (int r = 0; r < 4; ++r) {
            int row = mg * 16 + qd * 4 + r;
            int bb2 = row / NP_, q = row - bb2 * NP_;
            short val = f2bs(acc[t][r] + bvv);
            if (seg == 2)
                Vt[((size_t)(bb2 * 4 + h) * 32 + d) * NP_ + q] = val;
            else
                (seg ? Kf : Qf)[((size_t)(bb2 * 4 + h) * 4 + (d >> 3)) * (NP_ * 8) + q * 8 + (d & 7)] = val;
        }
    }
}

// layer-0 qkv: LN1(X) -> frags -> qkv
__global__ __launch_bounds__(256, 4) void qkv0(const float* __restrict__ X, const short* __restrict__ wq,
                                               const float* __restrict__ qb, const float* __restrict__ ls,
                                               const float* __restrict__ lb,
                                               short* __restrict__ Qf, short* __restrict__ Kf,
                                               short* __restrict__ Vt) {
    __shared__ __align__(16) float Xl[16 * 132];
    __shared__ __align__(16) short SB[2048];
    int mg = blockIdx.x, tid = threadIdx.x;
    int wv = tid >> 6, lane = tid & 63, lo = lane & 15, qd = lane >> 4;
    for (int idx = tid; idx < 512; idx += 256) {
        int tok = idx >> 5, c = idx & 31;
        *(float4*)(Xl + tok * 132 + c * 4) = *(const float4*)(X + (size_t)(mg * 16 + tok) * 128 + c * 4);
    }
    short8 preq[6];
#pragma unroll
    for (int t = 0; t < 6; ++t)
        preq[t] = *(const short8*)(wq + ((size_t)qd * 384 + wv * 96 + t * 16 + lo) * 8);
    __syncthreads();
    ln_tile16(Xl, ls, lb, SB, tid, 1e-5f);
    __syncthreads();
    qkv_stage16(SB, wq, qb, preq, mg, wv, lo, qd, Qf, Kf, Vt);
}

// Fused layer tail, 16 tokens/block, stage-entry weights prefetched across barriers.
template <int LAST>
__global__ __launch_bounds__(256, 4) void layer_tail(
    const short* __restrict__ Of, const short* __restrict__ wp, const float* __restrict__ pb,
    const float* __restrict__ l2s, const float* __restrict__ l2b,
    const short* __restrict__ w1, const float* __restrict__ b1,
    const short* __restrict__ w2, const float* __restrict__ b2,
    float* __restrict__ X,
    const float* __restrict__ l1s, const float* __restrict__ l1b,
    const short* __restrict__ wq, const float* __restrict__ qb,
    short* __restrict__ Qf, short* __restrict__ Kf, short* __restrict__ Vt) {
    __shared__ __align__(16) short SB[2048];           // 4 KB
    __shared__ __align__(16) float Xl[16 * 132];       // 8.4 KB
    __shared__ __align__(16) short Uh[32 * 136];       // 8.7 KB
    int mg = blockIdx.x, tid = threadIdx.x;
    int wv = tid >> 6, lane = tid & 63, lo = lane & 15, qd = lane >> 4;
    const short* osrc = Of + (size_t)mg * 2048;
    for (int idx = tid; idx < 256; idx += 256)
        *(short8*)(SB + idx * 8) = *(const short8*)(osrc + idx * 8);
    for (int idx = tid; idx < 512; idx += 256) {
        int tok = idx >> 5, c = idx & 31;
        *(float4*)(Xl + tok * 132 + c * 4) = *(const float4*)(X + (size_t)(mg * 16 + tok) * 128 + c * 4);
    }
    // prefetch all proj b-frags during staging
    int n0 = wv * 32;
    short8 prep[8];
#pragma unroll
    for (int ki = 0; ki < 4; ++ki) {
        int kq = ki * 4 + qd;
        prep[ki * 2] = *(const short8*)(wp + ((size_t)kq * 128 + n0 + lo) * 8);
        prep[ki * 2 + 1] = *(const short8*)(wp + ((size_t)kq * 128 + n0 + 16 + lo) * 8);
    }
    __syncthreads();
    // ---- proj: wave owns 32 cols ----
    {
        f32x4 pa[2] = {};
#pragma unroll
        for (int ki = 0; ki < 4; ++ki) {
            int kq = ki * 4 + qd;
            short8 a = *(const short8*)(SB + (kq * 16 + lo) * 8);
            pa[0] = mfma16(a, prep[ki * 2], pa[0]);
            pa[1] = mfma16(a, prep[ki * 2 + 1], pa[1]);
        }
        float pb0 = pb[n0 + lo], pb1 = pb[n0 + 16 + lo];
#pragma unroll
        for (int r = 0; r < 4; ++r) {
            Xl[(qd * 4 + r) * 132 + n0 + lo] += pa[0][r] + pb0;
            Xl[(qd * 4 + r) * 132 + n0 + 16 + lo] += pa[1][r] + pb1;
        }
    }
    int n0h = wv * 64;
    short8 pre1[4];                                    // ffn1 h0 ki=0
#pragma unroll
    for (int t = 0; t < 4; ++t)
        pre1[t] = *(const short8*)(w1 + ((size_t)qd * 512 + n0h + t * 16 + lo) * 8);
    __syncthreads();
    ln_tile16(Xl, l2s, l2b, SB, tid, 1e-5f);
    __syncthreads();
    f32x4 facc[2] = {};
    // ---- ffn1 h0 ----
    {
        f32x4 fa[4] = {};
#pragma unroll
        for (int ki = 0; ki < 4; ++ki) {
            int kq = ki * 4 + qd;
            short8 a = *(const short8*)(SB + (kq * 16 + lo) * 8);
#pragma unroll
            for (int t = 0; t < 4; ++t) {
                short8 bf = (ki == 0) ? pre1[t]
                                      : *(const short8*)(w1 + ((size_t)kq * 512 + n0h + t * 16 + lo) * 8);
                fa[t] = mfma16(a, bf, fa[t]);
            }
        }
#pragma unroll
        for (int t = 0; t < 4; ++t) {
            int nl = n0h + t * 16 + lo;
            float bvv = b1[nl];
#pragma unroll
            for (int r = 0; r < 4; ++r) {
                float x = fa[t][r] + bvv;
                float u = x * (0.7978845608f + 0.0356774081f * x * x);
                x = x / (1.f + __expf(-2.f * u));
                Uh[(nl >> 3) * 136 + (qd * 4 + r) * 8 + (nl & 7)] = f2bs(x);
            }
        }
    }
    short8 pre2a = *(const short8*)(w2 + ((size_t)qd * 128 + n0 + lo) * 8);       // ffn2 h0 ki=0
    short8 pre2b = *(const short8*)(w2 + ((size_t)qd * 128 + n0 + 16 + lo) * 8);
    short8 pre1b[4];                                   // ffn1 h1 ki=0
#pragma unroll
    for (int t = 0; t < 4; ++t)
        pre1b[t] = *(const short8*)(w1 + ((size_t)qd * 512 + 256 + n0h + t * 16 + lo) * 8);
    __syncthreads();
    // ---- ffn2 h0 ----
#pragma unroll
    for (int ki = 0; ki < 8; ++ki) {
        int kq2 = ki * 4 + qd;
        short8 a = *(const short8*)(Uh + kq2 * 136 + lo * 8);
        short8 b0 = (ki == 0) ? pre2a : *(const short8*)(w2 + ((size_t)kq2 * 128 + n0 + lo) * 8);
        short8 b1 = (ki == 0) ? pre2b : *(const short8*)(w2 + ((size_t)kq2 * 128 + n0 + 16 + lo) * 8);
        facc[0] = mfma16(a, b0, facc[0]);
        facc[1] = mfma16(a, b1, facc[1]);
    }
    short8 pre3a = *(const short8*)(w2 + ((size_t)(32 + qd) * 128 + n0 + lo) * 8); // ffn2 h1 ki=0
    short8 pre3b = *(const short8*)(w2 + ((size_t)(32 + qd) * 128 + n0 + 16 + lo) * 8);
    __syncthreads();
    // ---- ffn1 h1 ----
    {
        f32x4 fa[4] = {};
#pragma unroll
        for (int ki = 0; ki < 4; ++ki) {
            int kq = ki * 4 + qd;
            short8 a = *(const short8*)(SB + (kq * 16 + lo) * 8);
#pragma unroll
            for (int t = 0; t < 4; ++t) {
                short8 bf = (ki == 0) ? pre1b[t]
                                      : *(const short8*)(w1 + ((size_t)kq * 512 + 256 + n0h + t * 16 + lo) * 8);
                fa[t] = mfma16(a, bf, fa[t]);
            }
        }
#pragma unroll
        for (int t = 0; t < 4; ++t) {
            int nl = n0h + t * 16 + lo;
            float bvv = b1[256 + nl];
#pragma unroll
            for (int r = 0; r < 4; ++r) {
                float x = fa[t][r] + bvv;
                float u = x * (0.7978845608f + 0.0356774081f * x * x);
                x = x / (1.f + __expf(-2.f * u));
                Uh[(nl >> 3) * 136 + (qd * 4 + r) * 8 + (nl & 7)] = f2bs(x);
            }
        }
    }
    __syncthreads();
    // ---- ffn2 h1 ----
#pragma unroll
    for (int ki = 0; ki < 8; ++ki) {
        int kq2 = ki * 4 + qd;
        short8 a = *(const short8*)(Uh + kq2 * 136 + lo * 8);
        short8 b0 = (ki == 0) ? pre3a : *(const short8*)(w2 + ((size_t)(32 + kq2) * 128 + n0 + lo) * 8);
        short8 b1 = (ki == 0) ? pre3b : *(const short8*)(w2 + ((size_t)(32 + kq2) * 128 + n0 + 16 + lo) * 8);
        facc[0] = mfma16(a, b0, facc[0]);
        facc[1] = mfma16(a, b1, facc[1]);
    }
    // ---- residual ----
    {
        float b20 = b2[n0 + lo], b21 = b2[n0 + 16 + lo];
#pragma unroll
        for (int r = 0; r < 4; ++r) {
            Xl[(qd * 4 + r) * 132 + n0 + lo] += facc[0][r] + b20;
            Xl[(qd * 4 + r) * 132 + n0 + 16 + lo] += facc[1][r] + b21;
        }
    }
    short8 preq[6];
    if (!LAST) {
#pragma unroll
        for (int t = 0; t < 6; ++t)
            preq[t] = *(const short8*)(wq + ((size_t)qd * 384 + wv * 96 + t * 16 + lo) * 8);
    }
    __syncthreads();
    for (int idx = tid; idx < 512; idx += 256) {
        int tok = idx >> 5, c = idx & 31;
        *(float4*)(X + (size_t)(mg * 16 + tok) * 128 + c * 4) = *(const float4*)(Xl + tok * 132 + c * 4);
    }
    if (LAST) return;
    ln_tile16(Xl, l1s, l1b, SB, tid, 1e-5f);
    __syncthreads();
    qkv_stage16(SB, wq, qb, preq, mg, wv, lo, qd, Qf, Kf, Vt);
}

// Fused attention: block = (b,h,quarter); 1 q-tile per wave (+qt16 on one wave).
__global__ __launch_bounds__(256, 4) void attn(const short* __restrict__ Qf, const short* __restrict__ Kf,
                                               const short* __restrict__ Vt, short* __restrict__ Of) {
    __shared__ __align__(16) short Vl[32 * 296];       // 18.9 KB
    __shared__ __align__(16) short Pl[4][544];         // per-wave 32-key P chunk
    int b = blockIdx.x >> 4, h = (blockIdx.x >> 2) & 3, qc = blockIdx.x & 3;
    int tid = threadIdx.x;
    const short* kf = Kf + (size_t)(b * 4 + h) * (4 * NP_ * 8);
    const short* qf = Qf + (size_t)(b * 4 + h) * (4 * NP_ * 8);
    const short* vt = Vt + (size_t)(b * 4 + h) * (32 * NP_);
    for (int idx = tid; idx < 32 * 37; idx += 256) {
        int d = idx / 37, c8 = idx - d * 37;
        short8 v = {};
        if (c8 < 34) v = *(const short8*)(vt + d * NP_ + c8 * 8);
        *(short8*)(Vl + d * 296 + c8 * 8) = v;
    }
    __syncthreads();
    int wv = tid >> 6, lane = tid & 63, lo = lane & 15, qd = lane >> 4;
    short* Pw = Pl[wv];
    const float scale = 0.17677669529663687f;
    for (int it = 0; it < 2; ++it) {
        int qt;
        if (it == 0) qt = qc * 4 + wv;
        else { if ((qc | wv) != 0) break; qt = 16; }   // wave-uniform
        short8 qfr = *(const short8*)(qf + ((size_t)qd * NP_ + qt * 16 + lo) * 8);
        f32x4 sc[17];
#pragma unroll
        for (int kt = 0; kt < 17; ++kt) {
            short8 kfr = *(const short8*)(kf + ((size_t)qd * NP_ + kt * 16 + lo) * 8);
            f32x4 z = {};
            sc[kt] = mfma16(qfr, kfr, z);
        }
        float mx[4] = {-1e30f, -1e30f, -1e30f, -1e30f};
#pragma unroll
        for (int kt = 0; kt < 17; ++kt) {
            bool valid = (kt * 16 + lo) < 257;
#pragma unroll
            for (int r = 0; r < 4; ++r) {
                float v2 = valid ? sc[kt][r] * scale : -1e30f;
                sc[kt][r] = v2;
                mx[r] = fmaxf(mx[r], v2);
            }
        }
#pragma unroll
        for (int r = 0; r < 4; ++r) {
            mx[r] = fmaxf(mx[r], __shfl_xor(mx[r], 1));
            mx[r] = fmaxf(mx[r], __shfl_xor(mx[r], 2));
            mx[r] = fmaxf(mx[r], __shfl_xor(mx[r], 4));
            mx[r] = fmaxf(mx[r], __shfl_xor(mx[r], 8));
        }
        float l[4] = {0.f, 0.f, 0.f, 0.f};
#pragma unroll
        for (int kt = 0; kt < 17; ++kt)
#pragma unroll
            for (int r = 0; r < 4; ++r) {
                float p = __expf(sc[kt][r] - mx[r]);
                sc[kt][r] = p;
                l[r] += p;
            }
#pragma unroll
        for (int r = 0; r < 4; ++r) {
            l[r] += __shfl_xor(l[r], 1);
            l[r] += __shfl_xor(l[r], 2);
            l[r] += __shfl_xor(l[r], 4);
            l[r] += __shfl_xor(l[r], 8);
        }
        float rl[4];
#pragma unroll
        for (int r = 0; r < 4; ++r) rl[r] = 1.f / l[r];
        f32x4 oa[2] = {};
#pragma unroll
        for (int ks = 0; ks < 9; ++ks) {
#pragma unroll
            for (int kt2 = 0; kt2 < 2; ++kt2) {
                int kt = ks * 2 + kt2;
                int lkey = kt2 * 16 + lo;
#pragma unroll
                for (int r = 0; r < 4; ++r) {
                    short pv = (kt < 17) ? f2bs(sc[kt][r] * rl[r]) : (short)0;
                    Pw[(lkey >> 3) * 128 + (qd * 4 + r) * 8 + (lkey & 7)] = pv;
                }
            }
            short8 pf = *(const short8*)(Pw + (qd * 16 + lo) * 8);
#pragma unroll
            for (int nt = 0; nt < 2; ++nt) {
                short8 vfr = *(const short8*)(Vl + (nt * 16 + lo) * 296 + ks * 32 + qd * 8);
                oa[nt] = mfma16(pf, vfr, oa[nt]);
            }
        }
        int tile = b * TPB_ + qt;
#pragma unroll
        for (int nt = 0; nt < 2; ++nt)
#pragma unroll
            for (int r = 0; r < 4; ++r) {
                int qq = qt * 16 + qd * 4 + r;
                if (qq <= 256) {
                    int col = h * 32 + nt * 16 + lo;
                    Of[(size_t)tile * 2048 + (col >> 3) * 128 + (qd * 4 + r) * 8 + (col & 7)] = f2bs(oa[nt][r]);
                }
            }
    }
}

// final LN (token 0 only, eps 1e-6) + fc head
__global__ __launch_bounds__(64) void final_head(const float* __restrict__ X, const float* __restrict__ fs,
                                                 const float* __restrict__ fb, const float* __restrict__ fcw,
                                                 const float* __restrict__ fcb, float* __restrict__ out) {
    int b = blockIdx.x, lane = threadIdx.x;
    float2 v = *(const float2*)(X + (size_t)b * NP_ * 128 + lane * 2);
    float sum = v.x + v.y;
#pragma unroll
    for (int m = 1; m < 64; m <<= 1) sum += __shfl_xor(sum, m);
    float mean = sum * (1.f / 128.f);
    float d0 = v.x - mean, d1 = v.y - mean;
    float vs = d0 * d0 + d1 * d1;
#pragma unroll
    for (int m = 1; m < 64; m <<= 1) vs += __shfl_xor(vs, m);
    float rs = rsqrtf(vs * (1.f / 128.f) + 1e-6f);
    int e = lane * 2;
    float f0 = d0 * rs * fs[e] + fb[e];
    float f1 = d1 * rs * fs[e + 1] + fb[e + 1];
    out[128 + b * 128 + e] = f0;
    out[128 + b * 128 + e + 1] = f1;
    float p0 = f0 * fcw[e] + f1 * fcw[e + 1];
    float p1 = f0 * fcw[128 + e] + f1 * fcw[128 + e + 1];
#pragma unroll
    for (int m = 1; m < 64; m <<= 1) {
        p0 += __shfl_xor(p0, m);
        p1 += __shfl_xor(p1, m);
    }
    if (lane == 0) {
        out[b * 2 + 0] = p0 + fcb[0];
        out[b * 2 + 1] = p1 + fcb[1];
    }
}

extern "C" void kernel_launch(void* const* d_in, const int* in_sizes, int n_in,
                              void* d_out, int out_size, void* d_ws, size_t ws_size,
                              hipStream_t stream) {
    const float* feat    = (const float*)d_in[0];
    const float* conv_w  = (const float*)d_in[1];
    const float* conv_b  = (const float*)d_in[2];
    const float* pos_emb = (const float*)d_in[3];
    const float* cls_tok = (const float*)d_in[4];
    const float* ln1_s   = (const float*)d_in[5];
    const float* ln1_b   = (const float*)d_in[6];
    const float* qkv_w   = (const float*)d_in[7];
    const float* qkv_b   = (const float*)d_in[8];
    const float* proj_w  = (const float*)d_in[9];
    const float* proj_b  = (const float*)d_in[10];
    const float* ln2_s   = (const float*)d_in[11];
    const float* ln2_b   = (const float*)d_in[12];
    const float* ffn1_w  = (const float*)d_in[13];
    const float* ffn1_b  = (const float*)d_in[14];
    const float* ffn2_w  = (const float*)d_in[15];
    const float* ffn2_b  = (const float*)d_in[16];
    const float* fn_s    = (const float*)d_in[17];
    const float* fn_b    = (const float*)d_in[18];
    const float* fc_w    = (const float*)d_in[19];
    const float* fc_b    = (const float*)d_in[20];

    char* p = (char*)d_ws;
    auto alloc = [&](size_t bytes) { char* r = p; p += (bytes + 255) & ~(size_t)255; return r; };
    short* wq  = (short*)alloc((size_t)589824 * 2);
    short* wp  = (short*)alloc((size_t)196608 * 2);
    short* w1  = (short*)alloc((size_t)786432 * 2);
    short* w2  = (short*)alloc((size_t)786432 * 2);
    short* wc  = (short*)alloc((size_t)294912 * 2);
    short* fpd = (short*)alloc((size_t)64 * 34 * 34 * 256 * 2);
    float* X   = (float*)alloc((size_t)MP_ * 128 * 4);
    short* Qf  = (short*)alloc((size_t)64 * 16 * NP_ * 8 * 2);
    short* Kf  = (short*)alloc((size_t)64 * 16 * NP_ * 8 * 2);
    short* Vt  = (short*)alloc((size_t)64 * 4 * 32 * NP_ * 2);
    short* Of  = (short*)alloc((size_t)(MP_ / 16) * 2048 * 2);

    repack_all<<<10368, 256, 0, stream>>>(qkv_w, proj_w, ffn1_w, ffn2_w, conv_w, wq, wp, w1, w2, wc);
    feat_nhwc<<<64 * 32, 256, 0, stream>>>(feat, fpd);
    conv_gemm<<<1024, 256, 0, stream>>>(fpd, wc, conv_b, pos_emb, cls_tok, X);

    qkv0<<<1088, 256, 0, stream>>>(X, wq, qkv_b, ln1_s, ln1_b, Qf, Kf, Vt);
    for (int l = 0; l < 12; ++l) {
        attn<<<1024, 256, 0, stream>>>(Qf, Kf, Vt, Of);
        if (l < 11)
            layer_tail<0><<<1088, 256, 0, stream>>>(Of, wp + (size_t)l * 16384, proj_b + l * 128,
                                                    ln2_s + l * 128, ln2_b + l * 128,
                                                    w1 + (size_t)l * 65536, ffn1_b + l * 512,
                                                    w2 + (size_t)l * 65536, ffn2_b + l * 128, X,
                                                    ln1_s + (l + 1) * 128, ln1_b + (l + 1) * 128,
                                                    wq + (size_t)(l + 1) * 49152, qkv_b + (l + 1) * 384,
                                                    Qf, Kf, Vt);
        else
            layer_tail<1><<<1088, 256, 0, stream>>>(Of, wp + (size_t)l * 16384, proj_b + l * 128,
                                                    ln2_s + l * 128, ln2_b + l * 128,
                                                    w1 + (size_t)l * 65536, ffn1_b + l * 512,
                                                    w2 + (size_t)l * 65536, ffn2_b + l * 128, X,
                                                    ln1_s, ln1_b, wq, qkv_b, Qf, Kf, Vt);
    }
    final_head<<<64, 64, 0, stream>>>(X, fn_s, fn_b, fc_w, fc_b, (float*)d_out);
}

// Round 9
// 782.170 us; speedup vs baseline: 2.4697x; 1.0328x over previous
//
#include <hip/hip_runtime.h>
#include <math.h>

// ---------------- dims ----------------
constexpr int NP_ = 272;               // padded tokens per batch (17 tiles of 16)
constexpr int MP_ = 64 * NP_;          // 17408 padded rows
constexpr int TPB_ = 17;               // tiles per batch

typedef short short8 __attribute__((ext_vector_type(8)));
typedef float f32x4 __attribute__((ext_vector_type(4)));

__device__ inline short f2bs(float f) {  // float -> bf16 bits, RNE
    unsigned u = __builtin_bit_cast(unsigned, f);
    unsigned r = (u + 0x7fffu + ((u >> 16) & 1u)) >> 16;
    return (short)r;
}

__device__ inline f32x4 mfma16(short8 a, short8 b, f32x4 c) {
    return __builtin_amdgcn_mfma_f32_16x16x32_bf16(a, b, c, 0, 0, 0);
}

// ---------------- one-shot weight repack ----------------
__global__ void repack_all(const float* __restrict__ qkvw, const float* __restrict__ projw,
                           const float* __restrict__ f1w, const float* __restrict__ f2w,
                           const float* __restrict__ convw,
                           short* __restrict__ wq, short* __restrict__ wp,
                           short* __restrict__ w1, short* __restrict__ w2,
                           short* __restrict__ wc) {
    int o = blockIdx.x * 256 + threadIdx.x;
    if (o < 589824) {                                  // qkv: Nn=384 K=128
        int l = o / 49152, r = o % 49152;
        int chunk = r / 3072, w = r % 3072;
        int n = w >> 3, k = chunk * 8 + (w & 7);
        wq[o] = f2bs(qkvw[(size_t)l * 49152 + n * 128 + k]);
        return;
    }
    o -= 589824;
    if (o < 196608) {                                  // proj: 128x128
        int l = o / 16384, r = o % 16384;
        int chunk = r / 1024, w = r % 1024;
        int n = w >> 3, k = chunk * 8 + (w & 7);
        wp[o] = f2bs(projw[(size_t)l * 16384 + n * 128 + k]);
        return;
    }
    o -= 196608;
    if (o < 786432) {                                  // ffn1: Nn=512 K=128
        int l = o / 65536, r = o % 65536;
        int chunk = r / 4096, w = r % 4096;
        int n = w >> 3, k = chunk * 8 + (w & 7);
        w1[o] = f2bs(f1w[(size_t)l * 65536 + n * 128 + k]);
        return;
    }
    o -= 786432;
    if (o < 786432) {                                  // ffn2: Nn=128 K=512
        int l = o / 65536, r = o % 65536;
        int chunk = r / 1024, w = r % 1024;
        int n = w >> 3, k = chunk * 8 + (w & 7);
        w2[o] = f2bs(f2w[(size_t)l * 65536 + n * 512 + k]);
        return;
    }
    o -= 786432;
    if (o < 294912) {                                  // conv
        int j = o & 7;
        int col = (o >> 3) & 127;
        int c = o >> 10;
        int qd = c & 3, cscb = c >> 2;
        int cs = cscb & 7, kykx = cscb >> 3;
        int cin = cs * 32 + qd * 8 + j;
        int ky = kykx / 3, kx = kykx % 3;
        wc[o] = f2bs(convw[((col * 256 + cin) * 3 + ky) * 3 + kx]);
    }
}

// conv as GEMM: block = (b, oy). Stages 3 padded input rows straight from NCHW fp32 feat
// into swizzled bf16 LDS (transpose folded in); cls/pad init folded in.
__global__ __launch_bounds__(256) void conv_gemm(const float* __restrict__ feat, const short* __restrict__ wr,
                                                 const float* __restrict__ cb, const float* __restrict__ pos,
                                                 const float* __restrict__ cls, float* __restrict__ X) {
    __shared__ __align__(16) short Ain[3 * 34 * 256];  // 51 KB
    int b = blockIdx.x >> 4, oy = blockIdx.x & 15;
    int tid = threadIdx.x;
    for (int idx = tid; idx < 6144; idx += 256) {      // (r, cin, x4): coalesced 128B runs per cin
        int x4 = idx & 7;
        int cin = (idx >> 3) & 255;
        int r = idx >> 11;                             // 0..2, uniform per iteration
        int y = 2 * oy + r - 1;
        float4 f = make_float4(0.f, 0.f, 0.f, 0.f);
        if (y >= 0 && y < 32)
            f = *(const float4*)(feat + (((size_t)(b * 256 + cin) * 32 + y) * 32 + x4 * 4));
        int cg = cin >> 3, c7 = cin & 7;
        float vv[4] = {f.x, f.y, f.z, f.w};
#pragma unroll
        for (int dx = 0; dx < 4; ++dx) {
            int px = x4 * 4 + 1 + dx;
            int sw = (px >> 1) & 7;
            Ain[(r * 34 + px) * 256 + ((cg ^ sw) * 8) + c7] = f2bs(vv[dx]);
        }
    }
    for (int idx = tid; idx < 1536; idx += 256) {      // zero px=0 and px=33 columns
        int c = idx & 255;
        int j = idx >> 8;                              // 0..5
        int r = j >> 1;
        int px = (j & 1) ? 33 : 0;
        Ain[(r * 34 + px) * 256 + c] = 0;
    }
    __syncthreads();
    int wave = tid >> 6, lane = tid & 63;
    int ng = wave, lo = lane & 15, qd = lane >> 4;
    f32x4 acc[2] = {};
#pragma unroll
    for (int ky = 0; ky < 3; ++ky)
#pragma unroll
        for (int kx = 0; kx < 3; ++kx) {
            int sx = 2 * lo + kx;
            int arow = (ky * 34 + sx) * 256;
            int sw = (sx >> 1) & 7;
            const short* wb = wr + (((size_t)((ky * 3 + kx) * 8) * 4 + qd) * 128 + ng * 32 + lo) * 8;
#pragma unroll
            for (int cs = 0; cs < 8; ++cs) {
                short8 af = *(const short8*)(Ain + arow + (((cs * 4 + qd) ^ sw) * 8));
                short8 b0 = *(const short8*)(wb + (size_t)cs * 4096);
                short8 b1 = *(const short8*)(wb + (size_t)cs * 4096 + 128);
                acc[0] = mfma16(af, b0, acc[0]);
                acc[1] = mfma16(af, b1, acc[1]);
            }
        }
#pragma unroll
    for (int t = 0; t < 2; ++t) {
        int e = ng * 32 + t * 16 + lo;
        float bias = cb[e];
#pragma unroll
        for (int r = 0; r < 4; ++r) {
            int tok = 1 + oy * 16 + qd * 4 + r;
            X[((size_t)b * NP_ + tok) * 128 + e] = acc[t][r] + bias + pos[tok * 128 + e];
        }
    }
    if (oy == 0) {                                     // cls token + pad rows
        if (tid < 128) X[(size_t)b * NP_ * 128 + tid] = cls[tid] + pos[tid];
        for (int idx = tid; idx < 15 * 128; idx += 256)
            X[((size_t)b * NP_ + 257) * 128 + idx] = 0.f;
    }
}

// LN of a 16-row slab of Xl (stride 132) -> A-frag tile SB[kq(16)][m(16)][8]. 256 threads.
__device__ inline void ln_tile16(const float* Xl, const float* __restrict__ s, const float* __restrict__ bb,
                                 short* SB, int tid, float eps) {
    int wv = tid >> 6, lane = tid & 63;
    int r4 = lane & 3, c32 = lane >> 2;
    int row = wv * 4 + r4;
    const float* xr = Xl + row * 132 + c32 * 8;
    float4 a = *(const float4*)(xr);
    float4 b = *(const float4*)(xr + 4);
    float v[8] = {a.x, a.y, a.z, a.w, b.x, b.y, b.z, b.w};
    float sum = v[0] + v[1] + v[2] + v[3] + v[4] + v[5] + v[6] + v[7];
    sum += __shfl_xor(sum, 4); sum += __shfl_xor(sum, 8);
    sum += __shfl_xor(sum, 16); sum += __shfl_xor(sum, 32);
    float mean = sum * (1.f / 128.f);
    float vs = 0.f;
#pragma unroll
    for (int j = 0; j < 8; ++j) { float d = v[j] - mean; vs += d * d; }
    vs += __shfl_xor(vs, 4); vs += __shfl_xor(vs, 8);
    vs += __shfl_xor(vs, 16); vs += __shfl_xor(vs, 32);
    float rs = rsqrtf(vs * (1.f / 128.f) + eps);
    float4 s0 = *(const float4*)(s + c32 * 8), s1 = *(const float4*)(s + c32 * 8 + 4);
    float4 b0 = *(const float4*)(bb + c32 * 8), b1 = *(const float4*)(bb + c32 * 8 + 4);
    float sv[8] = {s0.x, s0.y, s0.z, s0.w, s1.x, s1.y, s1.z, s1.w};
    float bv[8] = {b0.x, b0.y, b0.z, b0.w, b1.x, b1.y, b1.z, b1.w};
    short8 o;
#pragma unroll
    for (int j = 0; j < 8; ++j) o[j] = f2bs((v[j] - mean) * rs * sv[j] + bv[j]);
    *(short8*)(SB + (c32 * 16 + row) * 8) = o;
}

// qkv GEMM from SB frags (2 m-tiles); ki=0 B-frags prefetched in pre[6]
__device__ inline void qkv_stage32(const short* SB, const short* __restrict__ wq, const float* __restrict__ qb,
                                   const short8* pre, int mg, int wv, int lo, int qd,
                                   short* __restrict__ Qf, short* __restrict__ Kf, short* __restrict__ Vt) {
    int n0 = wv * 96;
    f32x4 acc[2][6] = {};
#pragma unroll
    for (int ki = 0; ki < 4; ++ki) {
        int kq = ki * 4 + qd;
        short8 a0 = *(const short8*)(SB + (kq * 16 + lo) * 8);
        short8 a1 = *(const short8*)(SB + 2048 + (kq * 16 + lo) * 8);
#pragma unroll
        for (int t = 0; t < 6; ++t) {
            short8 bf = (ki == 0) ? pre[t]
                                  : *(const short8*)(wq + ((size_t)kq * 384 + n0 + t * 16 + lo) * 8);
            acc[0][t] = mfma16(a0, bf, acc[0][t]);
            acc[1][t] = mfma16(a1, bf, acc[1][t]);
        }
    }
#pragma unroll
    for (int mt = 0; mt < 2; ++mt)
#pragma unroll
        for (int t = 0; t < 6; ++t) {
            int n = n0 + t * 16 + lo;
            float bvv = qb[n];
            int seg = n >> 7, m = n & 127, h = m >> 5, d = m & 31;
#pragma unroll
            for (int r = 0; r < 4; ++r) {
                int row = mg * 32 + mt * 16 + qd * 4 + r;
                int bb2 = row / NP_, q = row - bb2 * NP_;
                short val = f2bs(acc[mt][t][r] + bvv);
                if (seg == 2)
                    Vt[((size_t)(bb2 * 4 + h) * 32 + d) * NP_ + q] = val;
                else
                    (seg ? Kf : Qf)[((size_t)(bb2 * 4 + h) * 4 + (d >> 3)) * (NP_ * 8) + q * 8 + (d & 7)] = val;
            }
        }
}

// layer-0 qkv: LN1(X) -> frags -> qkv  (32 tokens/block)
__global__ __launch_bounds__(256, 3) void qkv0(const float* __restrict__ X, const short* __restrict__ wq,
                                               const float* __restrict__ qb, const float* __restrict__ ls,
                                               const float* __restrict__ lb,
                                               short* __restrict__ Qf, short* __restrict__ Kf,
                                               short* __restrict__ Vt) {
    __shared__ __align__(16) float Xl[32 * 132];
    __shared__ __align__(16) short SB[2 * 2048];
    int mg = blockIdx.x, tid = threadIdx.x;
    int wv = tid >> 6, lane = tid & 63, lo = lane & 15, qd = lane >> 4;
    for (int idx = tid; idx < 1024; idx += 256) {
        int tok = idx >> 5, c = idx & 31;
        *(float4*)(Xl + tok * 132 + c * 4) = *(const float4*)(X + (size_t)(mg * 32 + tok) * 128 + c * 4);
    }
    short8 preq[6];
#pragma unroll
    for (int t = 0; t < 6; ++t)
        preq[t] = *(const short8*)(wq + ((size_t)qd * 384 + wv * 96 + t * 16 + lo) * 8);
    __syncthreads();
    ln_tile16(Xl, ls, lb, SB, tid, 1e-5f);
    ln_tile16(Xl + 16 * 132, ls, lb, SB + 2048, tid, 1e-5f);
    __syncthreads();
    qkv_stage32(SB, wq, qb, preq, mg, wv, lo, qd, Qf, Kf, Vt);
}

// Fused layer tail, 32 tokens/block (2 m-tiles), stage-entry weights prefetched.
template <int LAST>
__global__ __launch_bounds__(256, 3) void layer_tail(
    const short* __restrict__ Of, const short* __restrict__ wp, const float* __restrict__ pb,
    const float* __restrict__ l2s, const float* __restrict__ l2b,
    const short* __restrict__ w1, const float* __restrict__ b1,
    const short* __restrict__ w2, const float* __restrict__ b2,
    float* __restrict__ X,
    const float* __restrict__ l1s, const float* __restrict__ l1b,
    const short* __restrict__ wq, const float* __restrict__ qb,
    short* __restrict__ Qf, short* __restrict__ Kf, short* __restrict__ Vt) {
    __shared__ __align__(16) short SB[2 * 2048];       // 8 KB
    __shared__ __align__(16) float Xl[32 * 132];       // 16.9 KB
    __shared__ __align__(16) short Uh[2 * 32 * 136];   // 17.4 KB
    int mg = blockIdx.x, tid = threadIdx.x;
    int wv = tid >> 6, lane = tid & 63, lo = lane & 15, qd = lane >> 4;
    const short* osrc = Of + (size_t)mg * 4096;
    for (int idx = tid; idx < 512; idx += 256)
        *(short8*)(SB + idx * 8) = *(const short8*)(osrc + idx * 8);
    for (int idx = tid; idx < 1024; idx += 256) {
        int tok = idx >> 5, c = idx & 31;
        *(float4*)(Xl + tok * 132 + c * 4) = *(const float4*)(X + (size_t)(mg * 32 + tok) * 128 + c * 4);
    }
    int n0 = wv * 32;
    short8 prep[8];
#pragma unroll
    for (int ki = 0; ki < 4; ++ki) {
        int kq = ki * 4 + qd;
        prep[ki * 2] = *(const short8*)(wp + ((size_t)kq * 128 + n0 + lo) * 8);
        prep[ki * 2 + 1] = *(const short8*)(wp + ((size_t)kq * 128 + n0 + 16 + lo) * 8);
    }
    __syncthreads();
    // ---- proj: wave owns 32 cols, 2 m-tiles ----
    {
        f32x4 pa[2][2] = {};
#pragma unroll
        for (int ki = 0; ki < 4; ++ki) {
            int kq = ki * 4 + qd;
            short8 a0 = *(const short8*)(SB + (kq * 16 + lo) * 8);
            short8 a1 = *(const short8*)(SB + 2048 + (kq * 16 + lo) * 8);
            pa[0][0] = mfma16(a0, prep[ki * 2], pa[0][0]);
            pa[0][1] = mfma16(a0, prep[ki * 2 + 1], pa[0][1]);
            pa[1][0] = mfma16(a1, prep[ki * 2], pa[1][0]);
            pa[1][1] = mfma16(a1, prep[ki * 2 + 1], pa[1][1]);
        }
        float pb0 = pb[n0 + lo], pb1 = pb[n0 + 16 + lo];
#pragma unroll
        for (int mt = 0; mt < 2; ++mt)
#pragma unroll
            for (int r = 0; r < 4; ++r) {
                Xl[(mt * 16 + qd * 4 + r) * 132 + n0 + lo] += pa[mt][0][r] + pb0;
                Xl[(mt * 16 + qd * 4 + r) * 132 + n0 + 16 + lo] += pa[mt][1][r] + pb1;
            }
    }
    int n0h = wv * 64;
    short8 pre1[4];                                    // ffn1 h0 ki=0
#pragma unroll
    for (int t = 0; t < 4; ++t)
        pre1[t] = *(const short8*)(w1 + ((size_t)qd * 512 + n0h + t * 16 + lo) * 8);
    __syncthreads();
    ln_tile16(Xl, l2s, l2b, SB, tid, 1e-5f);
    ln_tile16(Xl + 16 * 132, l2s, l2b, SB + 2048, tid, 1e-5f);
    __syncthreads();
    f32x4 facc[2][2] = {};
    // ---- ffn1 h0 ----
    {
        f32x4 fa[2][4] = {};
#pragma unroll
        for (int ki = 0; ki < 4; ++ki) {
            int kq = ki * 4 + qd;
            short8 a0 = *(const short8*)(SB + (kq * 16 + lo) * 8);
            short8 a1 = *(const short8*)(SB + 2048 + (kq * 16 + lo) * 8);
#pragma unroll
            for (int t = 0; t < 4; ++t) {
                short8 bf = (ki == 0) ? pre1[t]
                                      : *(const short8*)(w1 + ((size_t)kq * 512 + n0h + t * 16 + lo) * 8);
                fa[0][t] = mfma16(a0, bf, fa[0][t]);
                fa[1][t] = mfma16(a1, bf, fa[1][t]);
            }
        }
#pragma unroll
        for (int t = 0; t < 4; ++t) {
            int nl = n0h + t * 16 + lo;
            float bvv = b1[nl];
#pragma unroll
            for (int mt = 0; mt < 2; ++mt)
#pragma unroll
                for (int r = 0; r < 4; ++r) {
                    float x = fa[mt][t][r] + bvv;
                    float u = x * (0.7978845608f + 0.0356774081f * x * x);
                    x = x / (1.f + __expf(-2.f * u));
                    Uh[(mt * 32 + (nl >> 3)) * 136 + (qd * 4 + r) * 8 + (nl & 7)] = f2bs(x);
                }
        }
    }
    short8 pre2a = *(const short8*)(w2 + ((size_t)qd * 128 + n0 + lo) * 8);       // ffn2 h0 ki=0
    short8 pre2b = *(const short8*)(w2 + ((size_t)qd * 128 + n0 + 16 + lo) * 8);
    short8 pre1b[4];                                   // ffn1 h1 ki=0
#pragma unroll
    for (int t = 0; t < 4; ++t)
        pre1b[t] = *(const short8*)(w1 + ((size_t)qd * 512 + 256 + n0h + t * 16 + lo) * 8);
    __syncthreads();
    // ---- ffn2 h0 ----
#pragma unroll
    for (int ki = 0; ki < 8; ++ki) {
        int kq2 = ki * 4 + qd;
        short8 a0 = *(const short8*)(Uh + kq2 * 136 + lo * 8);
        short8 a1 = *(const short8*)(Uh + (32 + kq2) * 136 + lo * 8);
        short8 b0 = (ki == 0) ? pre2a : *(const short8*)(w2 + ((size_t)kq2 * 128 + n0 + lo) * 8);
        short8 b1 = (ki == 0) ? pre2b : *(const short8*)(w2 + ((size_t)kq2 * 128 + n0 + 16 + lo) * 8);
        facc[0][0] = mfma16(a0, b0, facc[0][0]);
        facc[0][1] = mfma16(a0, b1, facc[0][1]);
        facc[1][0] = mfma16(a1, b0, facc[1][0]);
        facc[1][1] = mfma16(a1, b1, facc[1][1]);
    }
    short8 pre3a = *(const short8*)(w2 + ((size_t)(32 + qd) * 128 + n0 + lo) * 8); // ffn2 h1 ki=0
    short8 pre3b = *(const short8*)(w2 + ((size_t)(32 + qd) * 128 + n0 + 16 + lo) * 8);
    __syncthreads();
    // ---- ffn1 h1 ----
    {
        f32x4 fa[2][4] = {};
#pragma unroll
        for (int ki = 0; ki < 4; ++ki) {
            int kq = ki * 4 + qd;
            short8 a0 = *(const short8*)(SB + (kq * 16 + lo) * 8);
            short8 a1 = *(const short8*)(SB + 2048 + (kq * 16 + lo) * 8);
#pragma unroll
            for (int t = 0; t < 4; ++t) {
                short8 bf = (ki == 0) ? pre1b[t]
                                      : *(const short8*)(w1 + ((size_t)kq * 512 + 256 + n0h + t * 16 + lo) * 8);
                fa[0][t] = mfma16(a0, bf, fa[0][t]);
                fa[1][t] = mfma16(a1, bf, fa[1][t]);
            }
        }
#pragma unroll
        for (int t = 0; t < 4; ++t) {
            int nl = n0h + t * 16 + lo;
            float bvv = b1[256 + nl];
#pragma unroll
            for (int mt = 0; mt < 2; ++mt)
#pragma unroll
                for (int r = 0; r < 4; ++r) {
                    float x = fa[mt][t][r] + bvv;
                    float u = x * (0.7978845608f + 0.0356774081f * x * x);
                    x = x / (1.f + __expf(-2.f * u));
                    Uh[(mt * 32 + (nl >> 3)) * 136 + (qd * 4 + r) * 8 + (nl & 7)] = f2bs(x);
                }
        }
    }
    __syncthreads();
    // ---- ffn2 h1 ----
#pragma unroll
    for (int ki = 0; ki < 8; ++ki) {
        int kq2 = ki * 4 + qd;
        short8 a0 = *(const short8*)(Uh + kq2 * 136 + lo * 8);
        short8 a1 = *(const short8*)(Uh + (32 + kq2) * 136 + lo * 8);
        short8 b0 = (ki == 0) ? pre3a : *(const short8*)(w2 + ((size_t)(32 + kq2) * 128 + n0 + lo) * 8);
        short8 b1 = (ki == 0) ? pre3b : *(const short8*)(w2 + ((size_t)(32 + kq2) * 128 + n0 + 16 + lo) * 8);
        facc[0][0] = mfma16(a0, b0, facc[0][0]);
        facc[0][1] = mfma16(a0, b1, facc[0][1]);
        facc[1][0] = mfma16(a1, b0, facc[1][0]);
        facc[1][1] = mfma16(a1, b1, facc[1][1]);
    }
    // ---- residual ----
    {
        float b20 = b2[n0 + lo], b21 = b2[n0 + 16 + lo];
#pragma unroll
        for (int mt = 0; mt < 2; ++mt)
#pragma unroll
            for (int r = 0; r < 4; ++r) {
                Xl[(mt * 16 + qd * 4 + r) * 132 + n0 + lo] += facc[mt][0][r] + b20;
                Xl[(mt * 16 + qd * 4 + r) * 132 + n0 + 16 + lo] += facc[mt][1][r] + b21;
            }
    }
    short8 preq[6];
    if (!LAST) {
#pragma unroll
        for (int t = 0; t < 6; ++t)
            preq[t] = *(const short8*)(wq + ((size_t)qd * 384 + wv * 96 + t * 16 + lo) * 8);
    }
    __syncthreads();
    for (int idx = tid; idx < 1024; idx += 256) {
        int tok = idx >> 5, c = idx & 31;
        *(float4*)(X + (size_t)(mg * 32 + tok) * 128 + c * 4) = *(const float4*)(Xl + tok * 132 + c * 4);
    }
    if (LAST) return;
    ln_tile16(Xl, l1s, l1b, SB, tid, 1e-5f);
    ln_tile16(Xl + 16 * 132, l1s, l1b, SB + 2048, tid, 1e-5f);
    __syncthreads();
    qkv_stage32(SB, wq, qb, preq, mg, wv, lo, qd, Qf, Kf, Vt);
}

// Fused attention: block = (b,h,quarter); 1 q-tile per wave (+qt16 on one wave).
__global__ __launch_bounds__(256, 4) void attn(const short* __restrict__ Qf, const short* __restrict__ Kf,
                                               const short* __restrict__ Vt, short* __restrict__ Of) {
    __shared__ __align__(16) short Vl[32 * 296];       // 18.9 KB
    __shared__ __align__(16) short Pl[4][544];         // per-wave 32-key P chunk
    int b = blockIdx.x >> 4, h = (blockIdx.x >> 2) & 3, qc = blockIdx.x & 3;
    int tid = threadIdx.x;
    const short* kf = Kf + (size_t)(b * 4 + h) * (4 * NP_ * 8);
    const short* qf = Qf + (size_t)(b * 4 + h) * (4 * NP_ * 8);
    const short* vt = Vt + (size_t)(b * 4 + h) * (32 * NP_);
    for (int idx = tid; idx < 32 * 37; idx += 256) {
        int d = idx / 37, c8 = idx - d * 37;
        short8 v = {};
        if (c8 < 34) v = *(const short8*)(vt + d * NP_ + c8 * 8);
        *(short8*)(Vl + d * 296 + c8 * 8) = v;
    }
    __syncthreads();
    int wv = tid >> 6, lane = tid & 63, lo = lane & 15, qd = lane >> 4;
    short* Pw = Pl[wv];
    const float scale = 0.17677669529663687f;
    for (int it = 0; it < 2; ++it) {
        int qt;
        if (it == 0) qt = qc * 4 + wv;
        else { if ((qc | wv) != 0) break; qt = 16; }   // wave-uniform
        short8 qfr = *(const short8*)(qf + ((size_t)qd * NP_ + qt * 16 + lo) * 8);
        f32x4 sc[17];
#pragma unroll
        for (int kt = 0; kt < 17; ++kt) {
            short8 kfr = *(const short8*)(kf + ((size_t)qd * NP_ + kt * 16 + lo) * 8);
            f32x4 z = {};
            sc[kt] = mfma16(qfr, kfr, z);
        }
        float mx[4] = {-1e30f, -1e30f, -1e30f, -1e30f};
#pragma unroll
        for (int kt = 0; kt < 17; ++kt) {
            bool valid = (kt * 16 + lo) < 257;
#pragma unroll
            for (int r = 0; r < 4; ++r) {
                float v2 = valid ? sc[kt][r] * scale : -1e30f;
                sc[kt][r] = v2;
                mx[r] = fmaxf(mx[r], v2);
            }
        }
#pragma unroll
        for (int r = 0; r < 4; ++r) {
            mx[r] = fmaxf(mx[r], __shfl_xor(mx[r], 1));
            mx[r] = fmaxf(mx[r], __shfl_xor(mx[r], 2));
            mx[r] = fmaxf(mx[r], __shfl_xor(mx[r], 4));
            mx[r] = fmaxf(mx[r], __shfl_xor(mx[r], 8));
        }
        float l[4] = {0.f, 0.f, 0.f, 0.f};
#pragma unroll
        for (int kt = 0; kt < 17; ++kt)
#pragma unroll
            for (int r = 0; r < 4; ++r) {
                float p = __expf(sc[kt][r] - mx[r]);
                sc[kt][r] = p;
                l[r] += p;
            }
#pragma unroll
        for (int r = 0; r < 4; ++r) {
            l[r] += __shfl_xor(l[r], 1);
            l[r] += __shfl_xor(l[r], 2);
            l[r] += __shfl_xor(l[r], 4);
            l[r] += __shfl_xor(l[r], 8);
        }
        float rl[4];
#pragma unroll
        for (int r = 0; r < 4; ++r) rl[r] = 1.f / l[r];
        f32x4 oa[2] = {};
#pragma unroll
        for (int ks = 0; ks < 9; ++ks) {
#pragma unroll
            for (int kt2 = 0; kt2 < 2; ++kt2) {
                int kt = ks * 2 + kt2;
                int lkey = kt2 * 16 + lo;
#pragma unroll
                for (int r = 0; r < 4; ++r) {
                    short pv = (kt < 17) ? f2bs(sc[kt][r] * rl[r]) : (short)0;
                    Pw[(lkey >> 3) * 128 + (qd * 4 + r) * 8 + (lkey & 7)] = pv;
                }
            }
            short8 pf = *(const short8*)(Pw + (qd * 16 + lo) * 8);
#pragma unroll
            for (int nt = 0; nt < 2; ++nt) {
                short8 vfr = *(const short8*)(Vl + (nt * 16 + lo) * 296 + ks * 32 + qd * 8);
                oa[nt] = mfma16(pf, vfr, oa[nt]);
            }
        }
        int tile = b * TPB_ + qt;
#pragma unroll
        for (int nt = 0; nt < 2; ++nt)
#pragma unroll
            for (int r = 0; r < 4; ++r) {
                int qq = qt * 16 + qd * 4 + r;
                if (qq <= 256) {
                    int col = h * 32 + nt * 16 + lo;
                    Of[(size_t)tile * 2048 + (col >> 3) * 128 + (qd * 4 + r) * 8 + (col & 7)] = f2bs(oa[nt][r]);
                }
            }
    }
}

// final LN (token 0 only, eps 1e-6) + fc head
__global__ __launch_bounds__(64) void final_head(const float* __restrict__ X, const float* __restrict__ fs,
                                                 const float* __restrict__ fb, const float* __restrict__ fcw,
                                                 const float* __restrict__ fcb, float* __restrict__ out) {
    int b = blockIdx.x, lane = threadIdx.x;
    float2 v = *(const float2*)(X + (size_t)b * NP_ * 128 + lane * 2);
    float sum = v.x + v.y;
#pragma unroll
    for (int m = 1; m < 64; m <<= 1) sum += __shfl_xor(sum, m);
    float mean = sum * (1.f / 128.f);
    float d0 = v.x - mean, d1 = v.y - mean;
    float vs = d0 * d0 + d1 * d1;
#pragma unroll
    for (int m = 1; m < 64; m <<= 1) vs += __shfl_xor(vs, m);
    float rs = rsqrtf(vs * (1.f / 128.f) + 1e-6f);
    int e = lane * 2;
    float f0 = d0 * rs * fs[e] + fb[e];
    float f1 = d1 * rs * fs[e + 1] + fb[e + 1];
    out[128 + b * 128 + e] = f0;
    out[128 + b * 128 + e + 1] = f1;
    float p0 = f0 * fcw[e] + f1 * fcw[e + 1];
    float p1 = f0 * fcw[128 + e] + f1 * fcw[128 + e + 1];
#pragma unroll
    for (int m = 1; m < 64; m <<= 1) {
        p0 += __shfl_xor(p0, m);
        p1 += __shfl_xor(p1, m);
    }
    if (lane == 0) {
        out[b * 2 + 0] = p0 + fcb[0];
        out[b * 2 + 1] = p1 + fcb[1];
    }
}

extern "C" void kernel_launch(void* const* d_in, const int* in_sizes, int n_in,
                              void* d_out, int out_size, void* d_ws, size_t ws_size,
                              hipStream_t stream) {
    const float* feat    = (const float*)d_in[0];
    const float* conv_w  = (const float*)d_in[1];
    const float* conv_b  = (const float*)d_in[2];
    const float* pos_emb = (const float*)d_in[3];
    const float* cls_tok = (const float*)d_in[4];
    const float* ln1_s   = (const float*)d_in[5];
    const float* ln1_b   = (const float*)d_in[6];
    const float* qkv_w   = (const float*)d_in[7];
    const float* qkv_b   = (const float*)d_in[8];
    const float* proj_w  = (const float*)d_in[9];
    const float* proj_b  = (const float*)d_in[10];
    const float* ln2_s   = (const float*)d_in[11];
    const float* ln2_b   = (const float*)d_in[12];
    const float* ffn1_w  = (const float*)d_in[13];
    const float* ffn1_b  = (const float*)d_in[14];
    const float* ffn2_w  = (const float*)d_in[15];
    const float* ffn2_b  = (const float*)d_in[16];
    const float* fn_s    = (const float*)d_in[17];
    const float* fn_b    = (const float*)d_in[18];
    const float* fc_w    = (const float*)d_in[19];
    const float* fc_b    = (const float*)d_in[20];

    char* p = (char*)d_ws;
    auto alloc = [&](size_t bytes) { char* r = p; p += (bytes + 255) & ~(size_t)255; return r; };
    short* wq  = (short*)alloc((size_t)589824 * 2);
    short* wp  = (short*)alloc((size_t)196608 * 2);
    short* w1  = (short*)alloc((size_t)786432 * 2);
    short* w2  = (short*)alloc((size_t)786432 * 2);
    short* wc  = (short*)alloc((size_t)294912 * 2);
    float* X   = (float*)alloc((size_t)MP_ * 128 * 4);
    short* Qf  = (short*)alloc((size_t)64 * 16 * NP_ * 8 * 2);
    short* Kf  = (short*)alloc((size_t)64 * 16 * NP_ * 8 * 2);
    short* Vt  = (short*)alloc((size_t)64 * 4 * 32 * NP_ * 2);
    short* Of  = (short*)alloc((size_t)(MP_ / 16) * 2048 * 2);

    repack_all<<<10368, 256, 0, stream>>>(qkv_w, proj_w, ffn1_w, ffn2_w, conv_w, wq, wp, w1, w2, wc);
    conv_gemm<<<1024, 256, 0, stream>>>(feat, wc, conv_b, pos_emb, cls_tok, X);

    qkv0<<<544, 256, 0, stream>>>(X, wq, qkv_b, ln1_s, ln1_b, Qf, Kf, Vt);
    for (int l = 0; l < 12; ++l) {
        attn<<<1024, 256, 0, stream>>>(Qf, Kf, Vt, Of);
        if (l < 11)
            layer_tail<0><<<544, 256, 0, stream>>>(Of, wp + (size_t)l * 16384, proj_b + l * 128,
                                                   ln2_s + l * 128, ln2_b + l * 128,
                                                   w1 + (size_t)l * 65536, ffn1_b + l * 512,
                                                   w2 + (size_t)l * 65536, ffn2_b + l * 128, X,
                                                   ln1_s + (l + 1) * 128, ln1_b + (l + 1) * 128,
                                                   wq + (size_t)(l + 1) * 49152, qkv_b + (l + 1) * 384,
                                                   Qf, Kf, Vt);
        else
            layer_tail<1><<<544, 256, 0, stream>>>(Of, wp + (size_t)l * 16384, proj_b + l * 128,
                                                   ln2_s + l * 128, ln2_b + l * 128,
                                                   w1 + (size_t)l * 65536, ffn1_b + l * 512,
                                                   w2 + (size_t)l * 65536, ffn2_b + l * 128, X,
                                                   ln1_s, ln1_b, wq, qkv_b, Qf, Kf, Vt);
    }
    final_head<<<64, 64, 0, stream>>>(X, fn_s, fn_b, fc_w, fc_b, (float*)d_out);
}

// Round 11
// 717.258 us; speedup vs baseline: 2.6932x; 1.0905x over previous
//
#include <hip/hip_runtime.h>
#include <math.h>

// ---------------- dims ----------------
constexpr int NP_ = 272;               // padded tokens per batch (17 tiles of 16)
constexpr int MP_ = 64 * NP_;          // 17408 padded rows
constexpr int TPB_ = 17;               // tiles per batch

typedef short short8 __attribute__((ext_vector_type(8)));
typedef float f32x4 __attribute__((ext_vector_type(4)));

__device__ inline short f2bs(float f) {  // float -> bf16 bits, RNE
    unsigned u = __builtin_bit_cast(unsigned, f);
    unsigned r = (u + 0x7fffu + ((u >> 16) & 1u)) >> 16;
    return (short)r;
}

__device__ inline unsigned f2bs2(float a, float b) {  // packed bf16 pair
    unsigned ua = __builtin_bit_cast(unsigned, a);
    unsigned ub = __builtin_bit_cast(unsigned, b);
    unsigned ra = (ua + 0x7fffu + ((ua >> 16) & 1u)) >> 16;
    unsigned rb = (ub + 0x7fffu + ((ub >> 16) & 1u)) & 0xffff0000u;
    return ra | rb;
}

__device__ inline f32x4 mfma16(short8 a, short8 b, f32x4 c) {
    return __builtin_amdgcn_mfma_f32_16x16x32_bf16(a, b, c, 0, 0, 0);
}

// ---------------- one-shot weight repack ----------------
__global__ void repack_all(const float* __restrict__ qkvw, const float* __restrict__ projw,
                           const float* __restrict__ f1w, const float* __restrict__ f2w,
                           const float* __restrict__ convw,
                           short* __restrict__ wq, short* __restrict__ wp,
                           short* __restrict__ w1, short* __restrict__ w2,
                           short* __restrict__ wc) {
    int o = blockIdx.x * 256 + threadIdx.x;
    if (o < 589824) {                                  // qkv: Nn=384 K=128
        int l = o / 49152, r = o % 49152;
        int chunk = r / 3072, w = r % 3072;
        int n = w >> 3, k = chunk * 8 + (w & 7);
        wq[o] = f2bs(qkvw[(size_t)l * 49152 + n * 128 + k]);
        return;
    }
    o -= 589824;
    if (o < 196608) {                                  // proj: 128x128
        int l = o / 16384, r = o % 16384;
        int chunk = r / 1024, w = r % 1024;
        int n = w >> 3, k = chunk * 8 + (w & 7);
        wp[o] = f2bs(projw[(size_t)l * 16384 + n * 128 + k]);
        return;
    }
    o -= 196608;
    if (o < 786432) {                                  // ffn1: Nn=512 K=128
        int l = o / 65536, r = o % 65536;
        int chunk = r / 4096, w = r % 4096;
        int n = w >> 3, k = chunk * 8 + (w & 7);
        w1[o] = f2bs(f1w[(size_t)l * 65536 + n * 128 + k]);
        return;
    }
    o -= 786432;
    if (o < 786432) {                                  // ffn2: Nn=128 K=512
        int l = o / 65536, r = o % 65536;
        int chunk = r / 1024, w = r % 1024;
        int n = w >> 3, k = chunk * 8 + (w & 7);
        w2[o] = f2bs(f2w[(size_t)l * 65536 + n * 512 + k]);
        return;
    }
    o -= 786432;
    if (o < 294912) {                                  // conv
        int j = o & 7;
        int col = (o >> 3) & 127;
        int c = o >> 10;
        int qd = c & 3, cscb = c >> 2;
        int cs = cscb & 7, kykx = cscb >> 3;
        int cin = cs * 32 + qd * 8 + j;
        int ky = kykx / 3, kx = kykx % 3;
        wc[o] = f2bs(convw[((col * 256 + cin) * 3 + ky) * 3 + kx]);
    }
}

// conv as GEMM: block = (b, oy). Two-step conflict-free staging:
// coalesced fp32 loads -> tmp[64][33] -> transposed vec8 bf16 writes into swizzled Ain.
__global__ __launch_bounds__(256) void conv_gemm(const float* __restrict__ feat, const short* __restrict__ wr,
                                                 const float* __restrict__ cb, const float* __restrict__ pos,
                                                 const float* __restrict__ cls, float* __restrict__ X) {
    __shared__ __align__(16) short Ain[3 * 34 * 256];  // 51 KB
    __shared__ float tmp[64 * 33];                     // 8.25 KB
    int b = blockIdx.x >> 4, oy = blockIdx.x & 15;
    int tid = threadIdx.x;
    for (int idx = tid; idx < 1536; idx += 256) {      // zero px=0 and px=33 columns
        int c = idx & 255;
        int j = idx >> 8;                              // 0..5
        int r = j >> 1;
        int px = (j & 1) ? 33 : 0;
        Ain[(r * 34 + px) * 256 + c] = 0;
    }
    auto load_slice = [&](int s, float4& A, float4& B) {
        int r = s >> 2, cbase = (s & 3) * 64;
        int y = 2 * oy + r - 1;
        A = make_float4(0.f, 0.f, 0.f, 0.f);
        B = A;
        if (y >= 0 && y < 32) {
            int cl = tid >> 3, x4 = tid & 7;
            A = *(const float4*)(feat + (((size_t)(b * 256 + cbase + cl) * 32 + y) * 32 + x4 * 4));
            int i2 = tid + 256;
            int cl2 = i2 >> 3, x42 = i2 & 7;
            B = *(const float4*)(feat + (((size_t)(b * 256 + cbase + cl2) * 32 + y) * 32 + x42 * 4));
        }
    };
    float4 ra, rb;
    load_slice(0, ra, rb);
    for (int s = 0; s < 12; ++s) {
        int rr = s >> 2, cbase = (s & 3) * 64;
        {   // regs -> tmp (banks ~(cl+x)%32, conflict-free)
            int cl = tid >> 3, x4 = tid & 7;
            tmp[cl * 33 + x4 * 4 + 0] = ra.x;
            tmp[cl * 33 + x4 * 4 + 1] = ra.y;
            tmp[cl * 33 + x4 * 4 + 2] = ra.z;
            tmp[cl * 33 + x4 * 4 + 3] = ra.w;
            int i2 = tid + 256;
            int cl2 = i2 >> 3, x42 = i2 & 7;
            tmp[cl2 * 33 + x42 * 4 + 0] = rb.x;
            tmp[cl2 * 33 + x42 * 4 + 1] = rb.y;
            tmp[cl2 * 33 + x42 * 4 + 2] = rb.z;
            tmp[cl2 * 33 + x42 * 4 + 3] = rb.w;
        }
        __syncthreads();
        float4 na, nb;
        if (s < 11) load_slice(s + 1, na, nb);
        {   // transposed read (bank-step 1) -> one vec8 bf16 write into swizzled Ain
            int px = 1 + (tid & 31), g = tid >> 5;
            int sw = (px >> 1) & 7;
            int cg = (cbase >> 3) + g;
            float f[8];
#pragma unroll
            for (int j = 0; j < 8; ++j) f[j] = tmp[(g * 8 + j) * 33 + (px - 1)];
            uint4 ov;
            ov.x = f2bs2(f[0], f[1]);
            ov.y = f2bs2(f[2], f[3]);
            ov.z = f2bs2(f[4], f[5]);
            ov.w = f2bs2(f[6], f[7]);
            *(uint4*)(Ain + (rr * 34 + px) * 256 + ((cg ^ sw) * 8)) = ov;
        }
        __syncthreads();
        ra = na;
        rb = nb;
    }
    int wave = tid >> 6, lane = tid & 63;
    int ng = wave, lo = lane & 15, qd = lane >> 4;
    f32x4 acc[2] = {};
#pragma unroll
    for (int ky = 0; ky < 3; ++ky)
#pragma unroll
        for (int kx = 0; kx < 3; ++kx) {
            int sx = 2 * lo + kx;
            int arow = (ky * 34 + sx) * 256;
            int sw = (sx >> 1) & 7;
            const short* wb = wr + (((size_t)((ky * 3 + kx) * 8) * 4 + qd) * 128 + ng * 32 + lo) * 8;
#pragma unroll
            for (int cs = 0; cs < 8; ++cs) {
                short8 af = *(const short8*)(Ain + arow + (((cs * 4 + qd) ^ sw) * 8));
                short8 b0 = *(const short8*)(wb + (size_t)cs * 4096);
                short8 b1 = *(const short8*)(wb + (size_t)cs * 4096 + 128);
                acc[0] = mfma16(af, b0, acc[0]);
                acc[1] = mfma16(af, b1, acc[1]);
            }
        }
#pragma unroll
    for (int t = 0; t < 2; ++t) {
        int e = ng * 32 + t * 16 + lo;
        float bias = cb[e];
#pragma unroll
        for (int r = 0; r < 4; ++r) {
            int tok = 1 + oy * 16 + qd * 4 + r;
            X[((size_t)b * NP_ + tok) * 128 + e] = acc[t][r] + bias + pos[tok * 128 + e];
        }
    }
    if (oy == 0) {                                     // cls token + pad rows
        if (tid < 128) X[(size_t)b * NP_ * 128 + tid] = cls[tid] + pos[tid];
        for (int idx = tid; idx < 15 * 128; idx += 256)
            X[((size_t)b * NP_ + 257) * 128 + idx] = 0.f;
    }
}

// LN of a 16-row slab of Xl (stride 132) -> A-frag tile SB[kq(16)][m(16)][8]. 256 threads.
__device__ inline void ln_tile16(const float* Xl, const float* __restrict__ s, const float* __restrict__ bb,
                                 short* SB, int tid, float eps) {
    int wv = tid >> 6, lane = tid & 63;
    int r4 = lane & 3, c32 = lane >> 2;
    int row = wv * 4 + r4;
    const float* xr = Xl + row * 132 + c32 * 8;
    float4 a = *(const float4*)(xr);
    float4 b = *(const float4*)(xr + 4);
    float v[8] = {a.x, a.y, a.z, a.w, b.x, b.y, b.z, b.w};
    float sum = v[0] + v[1] + v[2] + v[3] + v[4] + v[5] + v[6] + v[7];
    sum += __shfl_xor(sum, 4); sum += __shfl_xor(sum, 8);
    sum += __shfl_xor(sum, 16); sum += __shfl_xor(sum, 32);
    float mean = sum * (1.f / 128.f);
    float vs = 0.f;
#pragma unroll
    for (int j = 0; j < 8; ++j) { float d = v[j] - mean; vs += d * d; }
    vs += __shfl_xor(vs, 4); vs += __shfl_xor(vs, 8);
    vs += __shfl_xor(vs, 16); vs += __shfl_xor(vs, 32);
    float rs = rsqrtf(vs * (1.f / 128.f) + eps);
    float4 s0 = *(const float4*)(s + c32 * 8), s1 = *(const float4*)(s + c32 * 8 + 4);
    float4 b0 = *(const float4*)(bb + c32 * 8), b1 = *(const float4*)(bb + c32 * 8 + 4);
    float sv[8] = {s0.x, s0.y, s0.z, s0.w, s1.x, s1.y, s1.z, s1.w};
    float bv[8] = {b0.x, b0.y, b0.z, b0.w, b1.x, b1.y, b1.z, b1.w};
    float y[8];
#pragma unroll
    for (int j = 0; j < 8; ++j) y[j] = (v[j] - mean) * rs * sv[j] + bv[j];
    uint4 ov;
    ov.x = f2bs2(y[0], y[1]);
    ov.y = f2bs2(y[2], y[3]);
    ov.z = f2bs2(y[4], y[5]);
    ov.w = f2bs2(y[6], y[7]);
    *(uint4*)(SB + (c32 * 16 + row) * 8) = ov;
}

// qkv GEMM from SB frags (2 m-tiles); ki=0 B-frags prefetched; Q pre-scaled; V packed 8B stores.
__device__ inline void qkv_stage32(const short* SB, const short* __restrict__ wq, const float* __restrict__ qb,
                                   const short8* pre, int mg, int wv, int lo, int qd,
                                   short* __restrict__ Qf, short* __restrict__ Kf, short* __restrict__ Vt) {
    int n0 = wv * 96;
    f32x4 acc[2][6] = {};
#pragma unroll
    for (int ki = 0; ki < 4; ++ki) {
        int kq = ki * 4 + qd;
        short8 a0 = *(const short8*)(SB + (kq * 16 + lo) * 8);
        short8 a1 = *(const short8*)(SB + 2048 + (kq * 16 + lo) * 8);
#pragma unroll
        for (int t = 0; t < 6; ++t) {
            short8 bf = (ki == 0) ? pre[t]
                                  : *(const short8*)(wq + ((size_t)kq * 384 + n0 + t * 16 + lo) * 8);
            acc[0][t] = mfma16(a0, bf, acc[0][t]);
            acc[1][t] = mfma16(a1, bf, acc[1][t]);
        }
    }
#pragma unroll
    for (int mt = 0; mt < 2; ++mt)
#pragma unroll
        for (int t = 0; t < 6; ++t) {
            int n = n0 + t * 16 + lo;
            float bvv = qb[n];
            int seg = n >> 7, m = n & 127, h = m >> 5, d = m & 31;
            int row0 = mg * 32 + mt * 16 + qd * 4;
            int bb2 = row0 / NP_, q0 = row0 - bb2 * NP_;
            if (seg == 2) {
                uint2 u;
                u.x = f2bs2(acc[mt][t][0] + bvv, acc[mt][t][1] + bvv);
                u.y = f2bs2(acc[mt][t][2] + bvv, acc[mt][t][3] + bvv);
                *(uint2*)(Vt + ((size_t)(bb2 * 4 + h) * 32 + d) * NP_ + q0) = u;
            } else {
                float qs = (seg == 0) ? 0.17677669529663687f : 1.f;  // fold softmax scale into Q
#pragma unroll
                for (int r = 0; r < 4; ++r) {
                    short val = f2bs((acc[mt][t][r] + bvv) * qs);
                    (seg ? Kf : Qf)[((size_t)(bb2 * 4 + h) * 4 + (d >> 3)) * (NP_ * 8) + (q0 + r) * 8 + (d & 7)] = val;
                }
            }
        }
}

// layer-0 qkv: LN1(X) -> frags -> qkv  (32 tokens/block)
__global__ __launch_bounds__(256, 3) void qkv0(const float* __restrict__ X, const short* __restrict__ wq,
                                               const float* __restrict__ qb, const float* __restrict__ ls,
                                               const float* __restrict__ lb,
                                               short* __restrict__ Qf, short* __restrict__ Kf,
                                               short* __restrict__ Vt) {
    __shared__ __align__(16) float Xl[32 * 132];
    __shared__ __align__(16) short SB[2 * 2048];
    int mg = blockIdx.x, tid = threadIdx.x;
    int wv = tid >> 6, lane = tid & 63, lo = lane & 15, qd = lane >> 4;
    for (int idx = tid; idx < 1024; idx += 256) {
        int tok = idx >> 5, c = idx & 31;
        *(float4*)(Xl + tok * 132 + c * 4) = *(const float4*)(X + (size_t)(mg * 32 + tok) * 128 + c * 4);
    }
    short8 preq[6];
#pragma unroll
    for (int t = 0; t < 6; ++t)
        preq[t] = *(const short8*)(wq + ((size_t)qd * 384 + wv * 96 + t * 16 + lo) * 8);
    __syncthreads();
    ln_tile16(Xl, ls, lb, SB, tid, 1e-5f);
    ln_tile16(Xl + 16 * 132, ls, lb, SB + 2048, tid, 1e-5f);
    __syncthreads();
    qkv_stage32(SB, wq, qb, preq, mg, wv, lo, qd, Qf, Kf, Vt);
}

// Fused layer tail, 32 tokens/block (2 m-tiles), stage-entry weights prefetched.
template <int LAST>
__global__ __launch_bounds__(256, 3) void layer_tail(
    const short* __restrict__ Of, const short* __restrict__ wp, const float* __restrict__ pb,
    const float* __restrict__ l2s, const float* __restrict__ l2b,
    const short* __restrict__ w1, const float* __restrict__ b1,
    const short* __restrict__ w2, const float* __restrict__ b2,
    float* __restrict__ X,
    const float* __restrict__ l1s, const float* __restrict__ l1b,
    const short* __restrict__ wq, const float* __restrict__ qb,
    short* __restrict__ Qf, short* __restrict__ Kf, short* __restrict__ Vt) {
    __shared__ __align__(16) short SB[2 * 2048];       // 8 KB
    __shared__ __align__(16) float Xl[32 * 132];       // 16.9 KB
    __shared__ __align__(16) short Uh[2 * 32 * 136];   // 17.4 KB
    int mg = blockIdx.x, tid = threadIdx.x;
    int wv = tid >> 6, lane = tid & 63, lo = lane & 15, qd = lane >> 4;
    const short* osrc = Of + (size_t)mg * 4096;
    for (int idx = tid; idx < 512; idx += 256)
        *(short8*)(SB + idx * 8) = *(const short8*)(osrc + idx * 8);
    for (int idx = tid; idx < 1024; idx += 256) {
        int tok = idx >> 5, c = idx & 31;
        *(float4*)(Xl + tok * 132 + c * 4) = *(const float4*)(X + (size_t)(mg * 32 + tok) * 128 + c * 4);
    }
    int n0 = wv * 32;
    short8 prep[8];
#pragma unroll
    for (int ki = 0; ki < 4; ++ki) {
        int kq = ki * 4 + qd;
        prep[ki * 2] = *(const short8*)(wp + ((size_t)kq * 128 + n0 + lo) * 8);
        prep[ki * 2 + 1] = *(const short8*)(wp + ((size_t)kq * 128 + n0 + 16 + lo) * 8);
    }
    __syncthreads();
    // ---- proj: wave owns 32 cols, 2 m-tiles ----
    {
        f32x4 pa[2][2] = {};
#pragma unroll
        for (int ki = 0; ki < 4; ++ki) {
            int kq = ki * 4 + qd;
            short8 a0 = *(const short8*)(SB + (kq * 16 + lo) * 8);
            short8 a1 = *(const short8*)(SB + 2048 + (kq * 16 + lo) * 8);
            pa[0][0] = mfma16(a0, prep[ki * 2], pa[0][0]);
            pa[0][1] = mfma16(a0, prep[ki * 2 + 1], pa[0][1]);
            pa[1][0] = mfma16(a1, prep[ki * 2], pa[1][0]);
            pa[1][1] = mfma16(a1, prep[ki * 2 + 1], pa[1][1]);
        }
        float pb0 = pb[n0 + lo], pb1 = pb[n0 + 16 + lo];
#pragma unroll
        for (int mt = 0; mt < 2; ++mt)
#pragma unroll
            for (int r = 0; r < 4; ++r) {
                Xl[(mt * 16 + qd * 4 + r) * 132 + n0 + lo] += pa[mt][0][r] + pb0;
                Xl[(mt * 16 + qd * 4 + r) * 132 + n0 + 16 + lo] += pa[mt][1][r] + pb1;
            }
    }
    int n0h = wv * 64;
    short8 pre1[4];                                    // ffn1 h0 ki=0
#pragma unroll
    for (int t = 0; t < 4; ++t)
        pre1[t] = *(const short8*)(w1 + ((size_t)qd * 512 + n0h + t * 16 + lo) * 8);
    __syncthreads();
    ln_tile16(Xl, l2s, l2b, SB, tid, 1e-5f);
    ln_tile16(Xl + 16 * 132, l2s, l2b, SB + 2048, tid, 1e-5f);
    __syncthreads();
    f32x4 facc[2][2] = {};
    // ---- ffn1 h0 ----
    {
        f32x4 fa[2][4] = {};
#pragma unroll
        for (int ki = 0; ki < 4; ++ki) {
            int kq = ki * 4 + qd;
            short8 a0 = *(const short8*)(SB + (kq * 16 + lo) * 8);
            short8 a1 = *(const short8*)(SB + 2048 + (kq * 16 + lo) * 8);
#pragma unroll
            for (int t = 0; t < 4; ++t) {
                short8 bf = (ki == 0) ? pre1[t]
                                      : *(const short8*)(w1 + ((size_t)kq * 512 + n0h + t * 16 + lo) * 8);
                fa[0][t] = mfma16(a0, bf, fa[0][t]);
                fa[1][t] = mfma16(a1, bf, fa[1][t]);
            }
        }
#pragma unroll
        for (int t = 0; t < 4; ++t) {
            int nl = n0h + t * 16 + lo;
            float bvv = b1[nl];
#pragma unroll
            for (int mt = 0; mt < 2; ++mt)
#pragma unroll
                for (int r = 0; r < 4; ++r) {
                    float x = fa[mt][t][r] + bvv;
                    float u = x * (0.7978845608f + 0.0356774081f * x * x);
                    x = x / (1.f + __expf(-2.f * u));
                    Uh[(mt * 32 + (nl >> 3)) * 136 + (qd * 4 + r) * 8 + (nl & 7)] = f2bs(x);
                }
        }
    }
    short8 pre2a = *(const short8*)(w2 + ((size_t)qd * 128 + n0 + lo) * 8);       // ffn2 h0 ki=0
    short8 pre2b = *(const short8*)(w2 + ((size_t)qd * 128 + n0 + 16 + lo) * 8);
    short8 pre1b[4];                                   // ffn1 h1 ki=0
#pragma unroll
    for (int t = 0; t < 4; ++t)
        pre1b[t] = *(const short8*)(w1 + ((size_t)qd * 512 + 256 + n0h + t * 16 + lo) * 8);
    __syncthreads();
    // ---- ffn2 h0 ----
#pragma unroll
    for (int ki = 0; ki < 8; ++ki) {
        int kq2 = ki * 4 + qd;
        short8 a0 = *(const short8*)(Uh + kq2 * 136 + lo * 8);
        short8 a1 = *(const short8*)(Uh + (32 + kq2) * 136 + lo * 8);
        short8 b0 = (ki == 0) ? pre2a : *(const short8*)(w2 + ((size_t)kq2 * 128 + n0 + lo) * 8);
        short8 b1 = (ki == 0) ? pre2b : *(const short8*)(w2 + ((size_t)kq2 * 128 + n0 + 16 + lo) * 8);
        facc[0][0] = mfma16(a0, b0, facc[0][0]);
        facc[0][1] = mfma16(a0, b1, facc[0][1]);
        facc[1][0] = mfma16(a1, b0, facc[1][0]);
        facc[1][1] = mfma16(a1, b1, facc[1][1]);
    }
    short8 pre3a = *(const short8*)(w2 + ((size_t)(32 + qd) * 128 + n0 + lo) * 8); // ffn2 h1 ki=0
    short8 pre3b = *(const short8*)(w2 + ((size_t)(32 + qd) * 128 + n0 + 16 + lo) * 8);
    __syncthreads();
    // ---- ffn1 h1 ----
    {
        f32x4 fa[2][4] = {};
#pragma unroll
        for (int ki = 0; ki < 4; ++ki) {
            int kq = ki * 4 + qd;
            short8 a0 = *(const short8*)(SB + (kq * 16 + lo) * 8);
            short8 a1 = *(const short8*)(SB + 2048 + (kq * 16 + lo) * 8);
#pragma unroll
            for (int t = 0; t < 4; ++t) {
                short8 bf = (ki == 0) ? pre1b[t]
                                      : *(const short8*)(w1 + ((size_t)kq * 512 + 256 + n0h + t * 16 + lo) * 8);
                fa[0][t] = mfma16(a0, bf, fa[0][t]);
                fa[1][t] = mfma16(a1, bf, fa[1][t]);
            }
        }
#pragma unroll
        for (int t = 0; t < 4; ++t) {
            int nl = n0h + t * 16 + lo;
            float bvv = b1[256 + nl];
#pragma unroll
            for (int mt = 0; mt < 2; ++mt)
#pragma unroll
                for (int r = 0; r < 4; ++r) {
                    float x = fa[mt][t][r] + bvv;
                    float u = x * (0.7978845608f + 0.0356774081f * x * x);
                    x = x / (1.f + __expf(-2.f * u));
                    Uh[(mt * 32 + (nl >> 3)) * 136 + (qd * 4 + r) * 8 + (nl & 7)] = f2bs(x);
                }
        }
    }
    __syncthreads();
    // ---- ffn2 h1 ----
#pragma unroll
    for (int ki = 0; ki < 8; ++ki) {
        int kq2 = ki * 4 + qd;
        short8 a0 = *(const short8*)(Uh + kq2 * 136 + lo * 8);
        short8 a1 = *(const short8*)(Uh + (32 + kq2) * 136 + lo * 8);
        short8 b0 = (ki == 0) ? pre3a : *(const short8*)(w2 + ((size_t)(32 + kq2) * 128 + n0 + lo) * 8);
        short8 b1 = (ki == 0) ? pre3b : *(const short8*)(w2 + ((size_t)(32 + kq2) * 128 + n0 + 16 + lo) * 8);
        facc[0][0] = mfma16(a0, b0, facc[0][0]);
        facc[0][1] = mfma16(a0, b1, facc[0][1]);
        facc[1][0] = mfma16(a1, b0, facc[1][0]);
        facc[1][1] = mfma16(a1, b1, facc[1][1]);
    }
    // ---- residual ----
    {
        float b20 = b2[n0 + lo], b21 = b2[n0 + 16 + lo];
#pragma unroll
        for (int mt = 0; mt < 2; ++mt)
#pragma unroll
            for (int r = 0; r < 4; ++r) {
                Xl[(mt * 16 + qd * 4 + r) * 132 + n0 + lo] += facc[mt][0][r] + b20;
                Xl[(mt * 16 + qd * 4 + r) * 132 + n0 + 16 + lo] += facc[mt][1][r] + b21;
            }
    }
    short8 preq[6];
    if (!LAST) {
#pragma unroll
        for (int t = 0; t < 6; ++t)
            preq[t] = *(const short8*)(wq + ((size_t)qd * 384 + wv * 96 + t * 16 + lo) * 8);
    }
    __syncthreads();
    for (int idx = tid; idx < 1024; idx += 256) {
        int tok = idx >> 5, c = idx & 31;
        *(float4*)(X + (size_t)(mg * 32 + tok) * 128 + c * 4) = *(const float4*)(Xl + tok * 132 + c * 4);
    }
    if (LAST) return;
    ln_tile16(Xl, l1s, l1b, SB, tid, 1e-5f);
    ln_tile16(Xl + 16 * 132, l1s, l1b, SB + 2048, tid, 1e-5f);
    __syncthreads();
    qkv_stage32(SB, wq, qb, preq, mg, wv, lo, qd, Qf, Kf, Vt);
}

// Fused attention: block = (b,h,quarter); Q pre-scaled; P stores raw exp, 1/l folded into O.
__global__ __launch_bounds__(256, 4) void attn(const short* __restrict__ Qf, const short* __restrict__ Kf,
                                               const short* __restrict__ Vt, short* __restrict__ Of) {
    __shared__ __align__(16) short Vl[32 * 296];       // 18.9 KB
    __shared__ __align__(16) short Pl[4][544];         // per-wave 32-key P chunk
    int b = blockIdx.x >> 4, h = (blockIdx.x >> 2) & 3, qc = blockIdx.x & 3;
    int tid = threadIdx.x;
    const short* kf = Kf + (size_t)(b * 4 + h) * (4 * NP_ * 8);
    const short* qf = Qf + (size_t)(b * 4 + h) * (4 * NP_ * 8);
    const short* vt = Vt + (size_t)(b * 4 + h) * (32 * NP_);
    for (int idx = tid; idx < 32 * 37; idx += 256) {
        int d = idx / 37, c8 = idx - d * 37;
        short8 v = {};
        if (c8 < 34) v = *(const short8*)(vt + d * NP_ + c8 * 8);
        *(short8*)(Vl + d * 296 + c8 * 8) = v;
    }
    __syncthreads();
    int wv = tid >> 6, lane = tid & 63, lo = lane & 15, qd = lane >> 4;
    short* Pw = Pl[wv];
    for (int it = 0; it < 2; ++it) {
        int qt;
        if (it == 0) qt = qc * 4 + wv;
        else { if ((qc | wv) != 0) break; qt = 16; }   // wave-uniform
        short8 qfr = *(const short8*)(qf + ((size_t)qd * NP_ + qt * 16 + lo) * 8);
        f32x4 sc[17];
#pragma unroll
        for (int kt = 0; kt < 17; ++kt) {
            short8 kfr = *(const short8*)(kf + ((size_t)qd * NP_ + kt * 16 + lo) * 8);
            f32x4 z = {};
            sc[kt] = mfma16(qfr, kfr, z);
        }
        float mx[4] = {-1e30f, -1e30f, -1e30f, -1e30f};
#pragma unroll
        for (int kt = 0; kt < 17; ++kt) {
            bool valid = (kt * 16 + lo) < 257;
#pragma unroll
            for (int r = 0; r < 4; ++r) {
                float v2 = valid ? sc[kt][r] : -1e30f;
                sc[kt][r] = v2;
                mx[r] = fmaxf(mx[r], v2);
            }
        }
#pragma unroll
        for (int r = 0; r < 4; ++r) {
            mx[r] = fmaxf(mx[r], __shfl_xor(mx[r], 1));
            mx[r] = fmaxf(mx[r], __shfl_xor(mx[r], 2));
            mx[r] = fmaxf(mx[r], __shfl_xor(mx[r], 4));
            mx[r] = fmaxf(mx[r], __shfl_xor(mx[r], 8));
        }
        float l[4] = {0.f, 0.f, 0.f, 0.f};
#pragma unroll
        for (int kt = 0; kt < 17; ++kt)
#pragma unroll
            for (int r = 0; r < 4; ++r) {
                float p = __expf(sc[kt][r] - mx[r]);
                sc[kt][r] = p;
                l[r] += p;
            }
#pragma unroll
        for (int r = 0; r < 4; ++r) {
            l[r] += __shfl_xor(l[r], 1);
            l[r] += __shfl_xor(l[r], 2);
            l[r] += __shfl_xor(l[r], 4);
            l[r] += __shfl_xor(l[r], 8);
        }
        float rl[4];
#pragma unroll
        for (int r = 0; r < 4; ++r) rl[r] = 1.f / l[r];
        f32x4 oa[2] = {};
#pragma unroll
        for (int ks = 0; ks < 9; ++ks) {
#pragma unroll
            for (int kt2 = 0; kt2 < 2; ++kt2) {
                int kt = ks * 2 + kt2;
                int lkey = kt2 * 16 + lo;
#pragma unroll
                for (int r = 0; r < 4; ++r) {
                    short pv = (kt < 17) ? f2bs(sc[kt][r]) : (short)0;
                    Pw[(lkey >> 3) * 128 + (qd * 4 + r) * 8 + (lkey & 7)] = pv;
                }
            }
            short8 pf = *(const short8*)(Pw + (qd * 16 + lo) * 8);
#pragma unroll
            for (int nt = 0; nt < 2; ++nt) {
                short8 vfr = *(const short8*)(Vl + (nt * 16 + lo) * 296 + ks * 32 + qd * 8);
                oa[nt] = mfma16(pf, vfr, oa[nt]);
            }
        }
        int tile = b * TPB_ + qt;
#pragma unroll
        for (int nt = 0; nt < 2; ++nt)
#pragma unroll
            for (int r = 0; r < 4; ++r) {
                int qq = qt * 16 + qd * 4 + r;
                if (qq <= 256) {
                    int col = h * 32 + nt * 16 + lo;
                    Of[(size_t)tile * 2048 + (col >> 3) * 128 + (qd * 4 + r) * 8 + (col & 7)] = f2bs(oa[nt][r] * rl[r]);
                }
            }
    }
}

// final LN (token 0 only, eps 1e-6) + fc head
__global__ __launch_bounds__(64) void final_head(const float* __restrict__ X, const float* __restrict__ fs,
                                                 const float* __restrict__ fb, const float* __restrict__ fcw,
                                                 const float* __restrict__ fcb, float* __restrict__ out) {
    int b = blockIdx.x, lane = threadIdx.x;
    float2 v = *(const float2*)(X + (size_t)b * NP_ * 128 + lane * 2);
    float sum = v.x + v.y;
#pragma unroll
    for (int m = 1; m < 64; m <<= 1) sum += __shfl_xor(sum, m);
    float mean = sum * (1.f / 128.f);
    float d0 = v.x - mean, d1 = v.y - mean;
    float vs = d0 * d0 + d1 * d1;
#pragma unroll
    for (int m = 1; m < 64; m <<= 1) vs += __shfl_xor(vs, m);
    float rs = rsqrtf(vs * (1.f / 128.f) + 1e-6f);
    int e = lane * 2;
    float f0 = d0 * rs * fs[e] + fb[e];
    float f1 = d1 * rs * fs[e + 1] + fb[e + 1];
    out[128 + b * 128 + e] = f0;
    out[128 + b * 128 + e + 1] = f1;
    float p0 = f0 * fcw[e] + f1 * fcw[e + 1];
    float p1 = f0 * fcw[128 + e] + f1 * fcw[128 + e + 1];
#pragma unroll
    for (int m = 1; m < 64; m <<= 1) {
        p0 += __shfl_xor(p0, m);
        p1 += __shfl_xor(p1, m);
    }
    if (lane == 0) {
        out[b * 2 + 0] = p0 + fcb[0];
        out[b * 2 + 1] = p1 + fcb[1];
    }
}

extern "C" void kernel_launch(void* const* d_in, const int* in_sizes, int n_in,
                              void* d_out, int out_size, void* d_ws, size_t ws_size,
                              hipStream_t stream) {
    const float* feat    = (const float*)d_in[0];
    const float* conv_w  = (const float*)d_in[1];
    const float* conv_b  = (const float*)d_in[2];
    const float* pos_emb = (const float*)d_in[3];
    const float* cls_tok = (const float*)d_in[4];
    const float* ln1_s   = (const float*)d_in[5];
    const float* ln1_b   = (const float*)d_in[6];
    const float* qkv_w   = (const float*)d_in[7];
    const float* qkv_b   = (const float*)d_in[8];
    const float* proj_w  = (const float*)d_in[9];
    const float* proj_b  = (const float*)d_in[10];
    const float* ln2_s   = (const float*)d_in[11];
    const float* ln2_b   = (const float*)d_in[12];
    const float* ffn1_w  = (const float*)d_in[13];
    const float* ffn1_b  = (const float*)d_in[14];
    const float* ffn2_w  = (const float*)d_in[15];
    const float* ffn2_b  = (const float*)d_in[16];
    const float* fn_s    = (const float*)d_in[17];
    const float* fn_b    = (const float*)d_in[18];
    const float* fc_w    = (const float*)d_in[19];
    const float* fc_b    = (const float*)d_in[20];

    char* p = (char*)d_ws;
    auto alloc = [&](size_t bytes) { char* r = p; p += (bytes + 255) & ~(size_t)255; return r; };
    short* wq  = (short*)alloc((size_t)589824 * 2);
    short* wp  = (short*)alloc((size_t)196608 * 2);
    short* w1  = (short*)alloc((size_t)786432 * 2);
    short* w2  = (short*)alloc((size_t)786432 * 2);
    short* wc  = (short*)alloc((size_t)294912 * 2);
    float* X   = (float*)alloc((size_t)MP_ * 128 * 4);
    short* Qf  = (short*)alloc((size_t)64 * 16 * NP_ * 8 * 2);
    short* Kf  = (short*)alloc((size_t)64 * 16 * NP_ * 8 * 2);
    short* Vt  = (short*)alloc((size_t)64 * 4 * 32 * NP_ * 2);
    short* Of  = (short*)alloc((size_t)(MP_ / 16) * 2048 * 2);

    repack_all<<<10368, 256, 0, stream>>>(qkv_w, proj_w, ffn1_w, ffn2_w, conv_w, wq, wp, w1, w2, wc);
    conv_gemm<<<1024, 256, 0, stream>>>(feat, wc, conv_b, pos_emb, cls_tok, X);

    qkv0<<<544, 256, 0, stream>>>(X, wq, qkv_b, ln1_s, ln1_b, Qf, Kf, Vt);
    for (int l = 0; l < 12; ++l) {
        attn<<<1024, 256, 0, stream>>>(Qf, Kf, Vt, Of);
        if (l < 11)
            layer_tail<0><<<544, 256, 0, stream>>>(Of, wp + (size_t)l * 16384, proj_b + l * 128,
                                                   ln2_s + l * 128, ln2_b + l * 128,
                                                   w1 + (size_t)l * 65536, ffn1_b + l * 512,
                                                   w2 + (size_t)l * 65536, ffn2_b + l * 128, X,
                                                   ln1_s + (l + 1) * 128, ln1_b + (l + 1) * 128,
                                                   wq + (size_t)(l + 1) * 49152, qkv_b + (l + 1) * 384,
                                                   Qf, Kf, Vt);
        else
            layer_tail<1><<<544, 256, 0, stream>>>(Of, wp + (size_t)l * 16384, proj_b + l * 128,
                                                   ln2_s + l * 128, ln2_b + l * 128,
                                                   w1 + (size_t)l * 65536, ffn1_b + l * 512,
                                                   w2 + (size_t)l * 65536, ffn2_b + l * 128, X,
                                                   ln1_s, ln1_b, wq, qkv_b, Qf, Kf, Vt);
    }
    final_head<<<64, 64, 0, stream>>>(X, fn_s, fn_b, fc_w, fc_b, (float*)d_out);
}

// Round 12
// 712.863 us; speedup vs baseline: 2.7098x; 1.0062x over previous
//
#include <hip/hip_runtime.h>
#include <math.h>

// ---------------- dims ----------------
constexpr int NP_ = 272;               // padded tokens per batch (17 tiles of 16)
constexpr int MP_ = 64 * NP_;          // 17408 padded rows
constexpr int TPB_ = 17;               // tiles per batch

typedef short short8 __attribute__((ext_vector_type(8)));
typedef float f32x4 __attribute__((ext_vector_type(4)));

__device__ inline short f2bs(float f) {  // float -> bf16 bits, RNE
    unsigned u = __builtin_bit_cast(unsigned, f);
    unsigned r = (u + 0x7fffu + ((u >> 16) & 1u)) >> 16;
    return (short)r;
}

__device__ inline unsigned f2bs2(float a, float b) {  // packed bf16 pair
    unsigned ua = __builtin_bit_cast(unsigned, a);
    unsigned ub = __builtin_bit_cast(unsigned, b);
    unsigned ra = (ua + 0x7fffu + ((ua >> 16) & 1u)) >> 16;
    unsigned rb = (ub + 0x7fffu + ((ub >> 16) & 1u)) & 0xffff0000u;
    return ra | rb;
}

__device__ inline f32x4 mfma16(short8 a, short8 b, f32x4 c) {
    return __builtin_amdgcn_mfma_f32_16x16x32_bf16(a, b, c, 0, 0, 0);
}

// ---------------- one-shot weight repack ----------------
__global__ void repack_all(const float* __restrict__ qkvw, const float* __restrict__ projw,
                           const float* __restrict__ f1w, const float* __restrict__ f2w,
                           const float* __restrict__ convw,
                           short* __restrict__ wq, short* __restrict__ wp,
                           short* __restrict__ w1, short* __restrict__ w2,
                           short* __restrict__ wc) {
    int o = blockIdx.x * 256 + threadIdx.x;
    if (o < 589824) {                                  // qkv: Nn=384 K=128
        int l = o / 49152, r = o % 49152;
        int chunk = r / 3072, w = r % 3072;
        int n = w >> 3, k = chunk * 8 + (w & 7);
        wq[o] = f2bs(qkvw[(size_t)l * 49152 + n * 128 + k]);
        return;
    }
    o -= 589824;
    if (o < 196608) {                                  // proj: 128x128
        int l = o / 16384, r = o % 16384;
        int chunk = r / 1024, w = r % 1024;
        int n = w >> 3, k = chunk * 8 + (w & 7);
        wp[o] = f2bs(projw[(size_t)l * 16384 + n * 128 + k]);
        return;
    }
    o -= 196608;
    if (o < 786432) {                                  // ffn1: Nn=512 K=128
        int l = o / 65536, r = o % 65536;
        int chunk = r / 4096, w = r % 4096;
        int n = w >> 3, k = chunk * 8 + (w & 7);
        w1[o] = f2bs(f1w[(size_t)l * 65536 + n * 128 + k]);
        return;
    }
    o -= 786432;
    if (o < 786432) {                                  // ffn2: Nn=128 K=512
        int l = o / 65536, r = o % 65536;
        int chunk = r / 1024, w = r % 1024;
        int n = w >> 3, k = chunk * 8 + (w & 7);
        w2[o] = f2bs(f2w[(size_t)l * 65536 + n * 512 + k]);
        return;
    }
    o -= 786432;
    if (o < 294912) {                                  // conv
        int j = o & 7;
        int col = (o >> 3) & 127;
        int c = o >> 10;
        int qd = c & 3, cscb = c >> 2;
        int cs = cscb & 7, kykx = cscb >> 3;
        int cin = cs * 32 + qd * 8 + j;
        int ky = kykx / 3, kx = kykx % 3;
        wc[o] = f2bs(convw[((col * 256 + cin) * 3 + ky) * 3 + kx]);
    }
}

// conv as GEMM: block = (b, oy). One input row staged at a time (25.9 KB LDS -> ~5 blocks/CU):
// coalesced fp32 loads -> tmp[64][33] -> transposed vec8 bf16 writes into swizzled Ain row.
__global__ __launch_bounds__(256, 5) void conv_gemm(const float* __restrict__ feat, const short* __restrict__ wr,
                                                    const float* __restrict__ cb, const float* __restrict__ pos,
                                                    const float* __restrict__ cls, float* __restrict__ X) {
    __shared__ __align__(16) short Ain[34 * 256];      // one row, swizzled (17.4 KB)
    __shared__ float tmp[64 * 33];                     // 8.4 KB
    int b = blockIdx.x >> 4, oy = blockIdx.x & 15;
    int tid = threadIdx.x;
    for (int idx = tid; idx < 512; idx += 256) {       // zero px=0 and px=33 columns (once)
        int c = idx & 255;
        int px = (idx >> 8) ? 33 : 0;
        Ain[px * 256 + c] = 0;
    }
    int wave = tid >> 6, lane = tid & 63;
    int ng = wave, lo = lane & 15, qd = lane >> 4;
    auto load_slice = [&](int r, int s, float4& A, float4& B) {
        int cbase = s * 64;
        int y = 2 * oy + r - 1;
        A = make_float4(0.f, 0.f, 0.f, 0.f);
        B = A;
        if (y >= 0 && y < 32) {
            int cl = tid >> 3, x4 = tid & 7;
            A = *(const float4*)(feat + (((size_t)(b * 256 + cbase + cl) * 32 + y) * 32 + x4 * 4));
            int i2 = tid + 256;
            int cl2 = i2 >> 3, x42 = i2 & 7;
            B = *(const float4*)(feat + (((size_t)(b * 256 + cbase + cl2) * 32 + y) * 32 + x42 * 4));
        }
    };
    f32x4 acc[2] = {};
    float4 ra, rb;
    load_slice(0, 0, ra, rb);
    for (int ky = 0; ky < 3; ++ky) {
        for (int s = 0; s < 4; ++s) {
            {   // regs -> tmp (conflict-free)
                int cl = tid >> 3, x4 = tid & 7;
                tmp[cl * 33 + x4 * 4 + 0] = ra.x;
                tmp[cl * 33 + x4 * 4 + 1] = ra.y;
                tmp[cl * 33 + x4 * 4 + 2] = ra.z;
                tmp[cl * 33 + x4 * 4 + 3] = ra.w;
                int i2 = tid + 256;
                int cl2 = i2 >> 3, x42 = i2 & 7;
                tmp[cl2 * 33 + x42 * 4 + 0] = rb.x;
                tmp[cl2 * 33 + x42 * 4 + 1] = rb.y;
                tmp[cl2 * 33 + x42 * 4 + 2] = rb.z;
                tmp[cl2 * 33 + x42 * 4 + 3] = rb.w;
            }
            __syncthreads();
            float4 na, nb;
            int nxt = ky * 4 + s + 1;
            if (nxt < 12) load_slice(nxt >> 2, nxt & 3, na, nb);
            {   // transposed read (bank-step 1) -> one vec8 bf16 write into swizzled Ain
                int px = 1 + (tid & 31), g = tid >> 5;
                int sw = (px >> 1) & 7;
                int cg = s * 8 + g;
                float f[8];
#pragma unroll
                for (int j = 0; j < 8; ++j) f[j] = tmp[(g * 8 + j) * 33 + (px - 1)];
                uint4 ov;
                ov.x = f2bs2(f[0], f[1]);
                ov.y = f2bs2(f[2], f[3]);
                ov.z = f2bs2(f[4], f[5]);
                ov.w = f2bs2(f[6], f[7]);
                *(uint4*)(Ain + px * 256 + ((cg ^ sw) * 8)) = ov;
            }
            __syncthreads();
            ra = na;
            rb = nb;
        }
        // MFMA over this row (acc carries across ky)
#pragma unroll
        for (int kx = 0; kx < 3; ++kx) {
            int sx = 2 * lo + kx;
            int arow = sx * 256;
            int sw = (sx >> 1) & 7;
            const short* wb = wr + (((size_t)((ky * 3 + kx) * 8) * 4 + qd) * 128 + ng * 32 + lo) * 8;
#pragma unroll
            for (int cs = 0; cs < 8; ++cs) {
                short8 af = *(const short8*)(Ain + arow + (((cs * 4 + qd) ^ sw) * 8));
                short8 b0 = *(const short8*)(wb + (size_t)cs * 4096);
                short8 b1 = *(const short8*)(wb + (size_t)cs * 4096 + 128);
                acc[0] = mfma16(af, b0, acc[0]);
                acc[1] = mfma16(af, b1, acc[1]);
            }
        }
        // no extra barrier needed: next row's Ain write happens only after the next tmp-sync,
        // by which point every wave has finished this row's MFMA (program order).
    }
#pragma unroll
    for (int t = 0; t < 2; ++t) {
        int e = ng * 32 + t * 16 + lo;
        float bias = cb[e];
#pragma unroll
        for (int r = 0; r < 4; ++r) {
            int tok = 1 + oy * 16 + qd * 4 + r;
            X[((size_t)b * NP_ + tok) * 128 + e] = acc[t][r] + bias + pos[tok * 128 + e];
        }
    }
    if (oy == 0) {                                     // cls token + pad rows
        if (tid < 128) X[(size_t)b * NP_ * 128 + tid] = cls[tid] + pos[tid];
        for (int idx = tid; idx < 15 * 128; idx += 256)
            X[((size_t)b * NP_ + 257) * 128 + idx] = 0.f;
    }
}

// LN of a 16-row slab of Xl (stride 132) -> A-frag tile SB[kq(16)][m(16)][8]. 256 threads.
__device__ inline void ln_tile16(const float* Xl, const float* __restrict__ s, const float* __restrict__ bb,
                                 short* SB, int tid, float eps) {
    int wv = tid >> 6, lane = tid & 63;
    int r4 = lane & 3, c32 = lane >> 2;
    int row = wv * 4 + r4;
    const float* xr = Xl + row * 132 + c32 * 8;
    float4 a = *(const float4*)(xr);
    float4 b = *(const float4*)(xr + 4);
    float v[8] = {a.x, a.y, a.z, a.w, b.x, b.y, b.z, b.w};
    float sum = v[0] + v[1] + v[2] + v[3] + v[4] + v[5] + v[6] + v[7];
    sum += __shfl_xor(sum, 4); sum += __shfl_xor(sum, 8);
    sum += __shfl_xor(sum, 16); sum += __shfl_xor(sum, 32);
    float mean = sum * (1.f / 128.f);
    float vs = 0.f;
#pragma unroll
    for (int j = 0; j < 8; ++j) { float d = v[j] - mean; vs += d * d; }
    vs += __shfl_xor(vs, 4); vs += __shfl_xor(vs, 8);
    vs += __shfl_xor(vs, 16); vs += __shfl_xor(vs, 32);
    float rs = rsqrtf(vs * (1.f / 128.f) + eps);
    float4 s0 = *(const float4*)(s + c32 * 8), s1 = *(const float4*)(s + c32 * 8 + 4);
    float4 b0 = *(const float4*)(bb + c32 * 8), b1 = *(const float4*)(bb + c32 * 8 + 4);
    float sv[8] = {s0.x, s0.y, s0.z, s0.w, s1.x, s1.y, s1.z, s1.w};
    float bv[8] = {b0.x, b0.y, b0.z, b0.w, b1.x, b1.y, b1.z, b1.w};
    float y[8];
#pragma unroll
    for (int j = 0; j < 8; ++j) y[j] = (v[j] - mean) * rs * sv[j] + bv[j];
    uint4 ov;
    ov.x = f2bs2(y[0], y[1]);
    ov.y = f2bs2(y[2], y[3]);
    ov.z = f2bs2(y[4], y[5]);
    ov.w = f2bs2(y[6], y[7]);
    *(uint4*)(SB + (c32 * 16 + row) * 8) = ov;
}

// qkv GEMM from SB frags (2 m-tiles); ki=0 B-frags prefetched; Q pre-scaled; V packed 8B stores.
__device__ inline void qkv_stage32(const short* SB, const short* __restrict__ wq, const float* __restrict__ qb,
                                   const short8* pre, int mg, int wv, int lo, int qd,
                                   short* __restrict__ Qf, short* __restrict__ Kf, short* __restrict__ Vt) {
    int n0 = wv * 96;
    f32x4 acc[2][6] = {};
#pragma unroll
    for (int ki = 0; ki < 4; ++ki) {
        int kq = ki * 4 + qd;
        short8 a0 = *(const short8*)(SB + (kq * 16 + lo) * 8);
        short8 a1 = *(const short8*)(SB + 2048 + (kq * 16 + lo) * 8);
#pragma unroll
        for (int t = 0; t < 6; ++t) {
            short8 bf = (ki == 0) ? pre[t]
                                  : *(const short8*)(wq + ((size_t)kq * 384 + n0 + t * 16 + lo) * 8);
            acc[0][t] = mfma16(a0, bf, acc[0][t]);
            acc[1][t] = mfma16(a1, bf, acc[1][t]);
        }
    }
#pragma unroll
    for (int mt = 0; mt < 2; ++mt)
#pragma unroll
        for (int t = 0; t < 6; ++t) {
            int n = n0 + t * 16 + lo;
            float bvv = qb[n];
            int seg = n >> 7, m = n & 127, h = m >> 5, d = m & 31;
            int row0 = mg * 32 + mt * 16 + qd * 4;
            int bb2 = row0 / NP_, q0 = row0 - bb2 * NP_;
            if (seg == 2) {
                uint2 u;
                u.x = f2bs2(acc[mt][t][0] + bvv, acc[mt][t][1] + bvv);
                u.y = f2bs2(acc[mt][t][2] + bvv, acc[mt][t][3] + bvv);
                *(uint2*)(Vt + ((size_t)(bb2 * 4 + h) * 32 + d) * NP_ + q0) = u;
            } else {
                float qs = (seg == 0) ? 0.17677669529663687f : 1.f;  // fold softmax scale into Q
#pragma unroll
                for (int r = 0; r < 4; ++r) {
                    short val = f2bs((acc[mt][t][r] + bvv) * qs);
                    (seg ? Kf : Qf)[((size_t)(bb2 * 4 + h) * 4 + (d >> 3)) * (NP_ * 8) + (q0 + r) * 8 + (d & 7)] = val;
                }
            }
        }
}

// layer-0 qkv: LN1(X) -> frags -> qkv  (32 tokens/block)
__global__ __launch_bounds__(256, 3) void qkv0(const float* __restrict__ X, const short* __restrict__ wq,
                                               const float* __restrict__ qb, const float* __restrict__ ls,
                                               const float* __restrict__ lb,
                                               short* __restrict__ Qf, short* __restrict__ Kf,
                                               short* __restrict__ Vt) {
    __shared__ __align__(16) float Xl[32 * 132];
    __shared__ __align__(16) short SB[2 * 2048];
    int mg = blockIdx.x, tid = threadIdx.x;
    int wv = tid >> 6, lane = tid & 63, lo = lane & 15, qd = lane >> 4;
    for (int idx = tid; idx < 1024; idx += 256) {
        int tok = idx >> 5, c = idx & 31;
        *(float4*)(Xl + tok * 132 + c * 4) = *(const float4*)(X + (size_t)(mg * 32 + tok) * 128 + c * 4);
    }
    short8 preq[6];
#pragma unroll
    for (int t = 0; t < 6; ++t)
        preq[t] = *(const short8*)(wq + ((size_t)qd * 384 + wv * 96 + t * 16 + lo) * 8);
    __syncthreads();
    ln_tile16(Xl, ls, lb, SB, tid, 1e-5f);
    ln_tile16(Xl + 16 * 132, ls, lb, SB + 2048, tid, 1e-5f);
    __syncthreads();
    qkv_stage32(SB, wq, qb, preq, mg, wv, lo, qd, Qf, Kf, Vt);
}

// Fused layer tail, 32 tokens/block (2 m-tiles), stage-entry weights prefetched.
template <int LAST>
__global__ __launch_bounds__(256, 3) void layer_tail(
    const short* __restrict__ Of, const short* __restrict__ wp, const float* __restrict__ pb,
    const float* __restrict__ l2s, const float* __restrict__ l2b,
    const short* __restrict__ w1, const float* __restrict__ b1,
    const short* __restrict__ w2, const float* __restrict__ b2,
    float* __restrict__ X,
    const float* __restrict__ l1s, const float* __restrict__ l1b,
    const short* __restrict__ wq, const float* __restrict__ qb,
    short* __restrict__ Qf, short* __restrict__ Kf, short* __restrict__ Vt) {
    __shared__ __align__(16) short SB[2 * 2048];       // 8 KB
    __shared__ __align__(16) float Xl[32 * 132];       // 16.9 KB
    __shared__ __align__(16) short Uh[2 * 32 * 136];   // 17.4 KB
    int mg = blockIdx.x, tid = threadIdx.x;
    int wv = tid >> 6, lane = tid & 63, lo = lane & 15, qd = lane >> 4;
    const short* osrc = Of + (size_t)mg * 4096;
    for (int idx = tid; idx < 512; idx += 256)
        *(short8*)(SB + idx * 8) = *(const short8*)(osrc + idx * 8);
    for (int idx = tid; idx < 1024; idx += 256) {
        int tok = idx >> 5, c = idx & 31;
        *(float4*)(Xl + tok * 132 + c * 4) = *(const float4*)(X + (size_t)(mg * 32 + tok) * 128 + c * 4);
    }
    int n0 = wv * 32;
    short8 prep[8];
#pragma unroll
    for (int ki = 0; ki < 4; ++ki) {
        int kq = ki * 4 + qd;
        prep[ki * 2] = *(const short8*)(wp + ((size_t)kq * 128 + n0 + lo) * 8);
        prep[ki * 2 + 1] = *(const short8*)(wp + ((size_t)kq * 128 + n0 + 16 + lo) * 8);
    }
    __syncthreads();
    // ---- proj: wave owns 32 cols, 2 m-tiles ----
    {
        f32x4 pa[2][2] = {};
#pragma unroll
        for (int ki = 0; ki < 4; ++ki) {
            int kq = ki * 4 + qd;
            short8 a0 = *(const short8*)(SB + (kq * 16 + lo) * 8);
            short8 a1 = *(const short8*)(SB + 2048 + (kq * 16 + lo) * 8);
            pa[0][0] = mfma16(a0, prep[ki * 2], pa[0][0]);
            pa[0][1] = mfma16(a0, prep[ki * 2 + 1], pa[0][1]);
            pa[1][0] = mfma16(a1, prep[ki * 2], pa[1][0]);
            pa[1][1] = mfma16(a1, prep[ki * 2 + 1], pa[1][1]);
        }
        float pb0 = pb[n0 + lo], pb1 = pb[n0 + 16 + lo];
#pragma unroll
        for (int mt = 0; mt < 2; ++mt)
#pragma unroll
            for (int r = 0; r < 4; ++r) {
                Xl[(mt * 16 + qd * 4 + r) * 132 + n0 + lo] += pa[mt][0][r] + pb0;
                Xl[(mt * 16 + qd * 4 + r) * 132 + n0 + 16 + lo] += pa[mt][1][r] + pb1;
            }
    }
    int n0h = wv * 64;
    short8 pre1[4];                                    // ffn1 h0 ki=0
#pragma unroll
    for (int t = 0; t < 4; ++t)
        pre1[t] = *(const short8*)(w1 + ((size_t)qd * 512 + n0h + t * 16 + lo) * 8);
    __syncthreads();
    ln_tile16(Xl, l2s, l2b, SB, tid, 1e-5f);
    ln_tile16(Xl + 16 * 132, l2s, l2b, SB + 2048, tid, 1e-5f);
    __syncthreads();
    f32x4 facc[2][2] = {};
    // ---- ffn1 h0 ----
    {
        f32x4 fa[2][4] = {};
#pragma unroll
        for (int ki = 0; ki < 4; ++ki) {
            int kq = ki * 4 + qd;
            short8 a0 = *(const short8*)(SB + (kq * 16 + lo) * 8);
            short8 a1 = *(const short8*)(SB + 2048 + (kq * 16 + lo) * 8);
#pragma unroll
            for (int t = 0; t < 4; ++t) {
                short8 bf = (ki == 0) ? pre1[t]
                                      : *(const short8*)(w1 + ((size_t)kq * 512 + n0h + t * 16 + lo) * 8);
                fa[0][t] = mfma16(a0, bf, fa[0][t]);
                fa[1][t] = mfma16(a1, bf, fa[1][t]);
            }
        }
#pragma unroll
        for (int t = 0; t < 4; ++t) {
            int nl = n0h + t * 16 + lo;
            float bvv = b1[nl];
#pragma unroll
            for (int mt = 0; mt < 2; ++mt)
#pragma unroll
                for (int r = 0; r < 4; ++r) {
                    float x = fa[mt][t][r] + bvv;
                    float u = x * (0.7978845608f + 0.0356774081f * x * x);
                    x = x / (1.f + __expf(-2.f * u));
                    Uh[(mt * 32 + (nl >> 3)) * 136 + (qd * 4 + r) * 8 + (nl & 7)] = f2bs(x);
                }
        }
    }
    short8 pre2a = *(const short8*)(w2 + ((size_t)qd * 128 + n0 + lo) * 8);       // ffn2 h0 ki=0
    short8 pre2b = *(const short8*)(w2 + ((size_t)qd * 128 + n0 + 16 + lo) * 8);
    short8 pre1b[4];                                   // ffn1 h1 ki=0
#pragma unroll
    for (int t = 0; t < 4; ++t)
        pre1b[t] = *(const short8*)(w1 + ((size_t)qd * 512 + 256 + n0h + t * 16 + lo) * 8);
    __syncthreads();
    // ---- ffn2 h0 ----
#pragma unroll
    for (int ki = 0; ki < 8; ++ki) {
        int kq2 = ki * 4 + qd;
        short8 a0 = *(const short8*)(Uh + kq2 * 136 + lo * 8);
        short8 a1 = *(const short8*)(Uh + (32 + kq2) * 136 + lo * 8);
        short8 b0 = (ki == 0) ? pre2a : *(const short8*)(w2 + ((size_t)kq2 * 128 + n0 + lo) * 8);
        short8 b1 = (ki == 0) ? pre2b : *(const short8*)(w2 + ((size_t)kq2 * 128 + n0 + 16 + lo) * 8);
        facc[0][0] = mfma16(a0, b0, facc[0][0]);
        facc[0][1] = mfma16(a0, b1, facc[0][1]);
        facc[1][0] = mfma16(a1, b0, facc[1][0]);
        facc[1][1] = mfma16(a1, b1, facc[1][1]);
    }
    short8 pre3a = *(const short8*)(w2 + ((size_t)(32 + qd) * 128 + n0 + lo) * 8); // ffn2 h1 ki=0
    short8 pre3b = *(const short8*)(w2 + ((size_t)(32 + qd) * 128 + n0 + 16 + lo) * 8);
    __syncthreads();
    // ---- ffn1 h1 ----
    {
        f32x4 fa[2][4] = {};
#pragma unroll
        for (int ki = 0; ki < 4; ++ki) {
            int kq = ki * 4 + qd;
            short8 a0 = *(const short8*)(SB + (kq * 16 + lo) * 8);
            short8 a1 = *(const short8*)(SB + 2048 + (kq * 16 + lo) * 8);
#pragma unroll
            for (int t = 0; t < 4; ++t) {
                short8 bf = (ki == 0) ? pre1b[t]
                                      : *(const short8*)(w1 + ((size_t)kq * 512 + 256 + n0h + t * 16 + lo) * 8);
                fa[0][t] = mfma16(a0, bf, fa[0][t]);
                fa[1][t] = mfma16(a1, bf, fa[1][t]);
            }
        }
#pragma unroll
        for (int t = 0; t < 4; ++t) {
            int nl = n0h + t * 16 + lo;
            float bvv = b1[256 + nl];
#pragma unroll
            for (int mt = 0; mt < 2; ++mt)
#pragma unroll
                for (int r = 0; r < 4; ++r) {
                    float x = fa[mt][t][r] + bvv;
                    float u = x * (0.7978845608f + 0.0356774081f * x * x);
                    x = x / (1.f + __expf(-2.f * u));
                    Uh[(mt * 32 + (nl >> 3)) * 136 + (qd * 4 + r) * 8 + (nl & 7)] = f2bs(x);
                }
        }
    }
    __syncthreads();
    // ---- ffn2 h1 ----
#pragma unroll
    for (int ki = 0; ki < 8; ++ki) {
        int kq2 = ki * 4 + qd;
        short8 a0 = *(const short8*)(Uh + kq2 * 136 + lo * 8);
        short8 a1 = *(const short8*)(Uh + (32 + kq2) * 136 + lo * 8);
        short8 b0 = (ki == 0) ? pre3a : *(const short8*)(w2 + ((size_t)(32 + kq2) * 128 + n0 + lo) * 8);
        short8 b1 = (ki == 0) ? pre3b : *(const short8*)(w2 + ((size_t)(32 + kq2) * 128 + n0 + 16 + lo) * 8);
        facc[0][0] = mfma16(a0, b0, facc[0][0]);
        facc[0][1] = mfma16(a0, b1, facc[0][1]);
        facc[1][0] = mfma16(a1, b0, facc[1][0]);
        facc[1][1] = mfma16(a1, b1, facc[1][1]);
    }
    // ---- residual ----
    {
        float b20 = b2[n0 + lo], b21 = b2[n0 + 16 + lo];
#pragma unroll
        for (int mt = 0; mt < 2; ++mt)
#pragma unroll
            for (int r = 0; r < 4; ++r) {
                Xl[(mt * 16 + qd * 4 + r) * 132 + n0 + lo] += facc[mt][0][r] + b20;
                Xl[(mt * 16 + qd * 4 + r) * 132 + n0 + 16 + lo] += facc[mt][1][r] + b21;
            }
    }
    short8 preq[6];
    if (!LAST) {
#pragma unroll
        for (int t = 0; t < 6; ++t)
            preq[t] = *(const short8*)(wq + ((size_t)qd * 384 + wv * 96 + t * 16 + lo) * 8);
    }
    __syncthreads();
    for (int idx = tid; idx < 1024; idx += 256) {
        int tok = idx >> 5, c = idx & 31;
        *(float4*)(X + (size_t)(mg * 32 + tok) * 128 + c * 4) = *(const float4*)(Xl + tok * 132 + c * 4);
    }
    if (LAST) return;
    ln_tile16(Xl, l1s, l1b, SB, tid, 1e-5f);
    ln_tile16(Xl + 16 * 132, l1s, l1b, SB + 2048, tid, 1e-5f);
    __syncthreads();
    qkv_stage32(SB, wq, qb, preq, mg, wv, lo, qd, Qf, Kf, Vt);
}

// Fused attention: block = (b,h,quarter); Q pre-scaled; P stores raw exp, 1/l folded into O.
__global__ __launch_bounds__(256, 4) void attn(const short* __restrict__ Qf, const short* __restrict__ Kf,
                                               const short* __restrict__ Vt, short* __restrict__ Of) {
    __shared__ __align__(16) short Vl[32 * 296];       // 18.9 KB
    __shared__ __align__(16) short Pl[4][544];         // per-wave 32-key P chunk
    int b = blockIdx.x >> 4, h = (blockIdx.x >> 2) & 3, qc = blockIdx.x & 3;
    int tid = threadIdx.x;
    const short* kf = Kf + (size_t)(b * 4 + h) * (4 * NP_ * 8);
    const short* qf = Qf + (size_t)(b * 4 + h) * (4 * NP_ * 8);
    const short* vt = Vt + (size_t)(b * 4 + h) * (32 * NP_);
    for (int idx = tid; idx < 32 * 37; idx += 256) {
        int d = idx / 37, c8 = idx - d * 37;
        short8 v = {};
        if (c8 < 34) v = *(const short8*)(vt + d * NP_ + c8 * 8);
        *(short8*)(Vl + d * 296 + c8 * 8) = v;
    }
    __syncthreads();
    int wv = tid >> 6, lane = tid & 63, lo = lane & 15, qd = lane >> 4;
    short* Pw = Pl[wv];
    for (int it = 0; it < 2; ++it) {
        int qt;
        if (it == 0) qt = qc * 4 + wv;
        else { if ((qc | wv) != 0) break; qt = 16; }   // wave-uniform
        short8 qfr = *(const short8*)(qf + ((size_t)qd * NP_ + qt * 16 + lo) * 8);
        f32x4 sc[17];
#pragma unroll
        for (int kt = 0; kt < 17; ++kt) {
            short8 kfr = *(const short8*)(kf + ((size_t)qd * NP_ + kt * 16 + lo) * 8);
            f32x4 z = {};
            sc[kt] = mfma16(qfr, kfr, z);
        }
        float mx[4] = {-1e30f, -1e30f, -1e30f, -1e30f};
#pragma unroll
        for (int kt = 0; kt < 17; ++kt) {
            bool valid = (kt * 16 + lo) < 257;
#pragma unroll
            for (int r = 0; r < 4; ++r) {
                float v2 = valid ? sc[kt][r] : -1e30f;
                sc[kt][r] = v2;
                mx[r] = fmaxf(mx[r], v2);
            }
        }
#pragma unroll
        for (int r = 0; r < 4; ++r) {
            mx[r] = fmaxf(mx[r], __shfl_xor(mx[r], 1));
            mx[r] = fmaxf(mx[r], __shfl_xor(mx[r], 2));
            mx[r] = fmaxf(mx[r], __shfl_xor(mx[r], 4));
            mx[r] = fmaxf(mx[r], __shfl_xor(mx[r], 8));
        }
        float l[4] = {0.f, 0.f, 0.f, 0.f};
#pragma unroll
        for (int kt = 0; kt < 17; ++kt)
#pragma unroll
            for (int r = 0; r < 4; ++r) {
                float p = __expf(sc[kt][r] - mx[r]);
                sc[kt][r] = p;
                l[r] += p;
            }
#pragma unroll
        for (int r = 0; r < 4; ++r) {
            l[r] += __shfl_xor(l[r], 1);
            l[r] += __shfl_xor(l[r], 2);
            l[r] += __shfl_xor(l[r], 4);
            l[r] += __shfl_xor(l[r], 8);
        }
        float rl[4];
#pragma unroll
        for (int r = 0; r < 4; ++r) rl[r] = 1.f / l[r];
        f32x4 oa[2] = {};
#pragma unroll
        for (int ks = 0; ks < 9; ++ks) {
#pragma unroll
            for (int kt2 = 0; kt2 < 2; ++kt2) {
                int kt = ks * 2 + kt2;
                int lkey = kt2 * 16 + lo;
#pragma unroll
                for (int r = 0; r < 4; ++r) {
                    short pv = (kt < 17) ? f2bs(sc[kt][r]) : (short)0;
                    Pw[(lkey >> 3) * 128 + (qd * 4 + r) * 8 + (lkey & 7)] = pv;
                }
            }
            short8 pf = *(const short8*)(Pw + (qd * 16 + lo) * 8);
#pragma unroll
            for (int nt = 0; nt < 2; ++nt) {
                short8 vfr = *(const short8*)(Vl + (nt * 16 + lo) * 296 + ks * 32 + qd * 8);
                oa[nt] = mfma16(pf, vfr, oa[nt]);
            }
        }
        int tile = b * TPB_ + qt;
#pragma unroll
        for (int nt = 0; nt < 2; ++nt)
#pragma unroll
            for (int r = 0; r < 4; ++r) {
                int qq = qt * 16 + qd * 4 + r;
                if (qq <= 256) {
                    int col = h * 32 + nt * 16 + lo;
                    Of[(size_t)tile * 2048 + (col >> 3) * 128 + (qd * 4 + r) * 8 + (col & 7)] = f2bs(oa[nt][r] * rl[r]);
                }
            }
    }
}

// final LN (token 0 only, eps 1e-6) + fc head
__global__ __launch_bounds__(64) void final_head(const float* __restrict__ X, const float* __restrict__ fs,
                                                 const float* __restrict__ fb, const float* __restrict__ fcw,
                                                 const float* __restrict__ fcb, float* __restrict__ out) {
    int b = blockIdx.x, lane = threadIdx.x;
    float2 v = *(const float2*)(X + (size_t)b * NP_ * 128 + lane * 2);
    float sum = v.x + v.y;
#pragma unroll
    for (int m = 1; m < 64; m <<= 1) sum += __shfl_xor(sum, m);
    float mean = sum * (1.f / 128.f);
    float d0 = v.x - mean, d1 = v.y - mean;
    float vs = d0 * d0 + d1 * d1;
#pragma unroll
    for (int m = 1; m < 64; m <<= 1) vs += __shfl_xor(vs, m);
    float rs = rsqrtf(vs * (1.f / 128.f) + 1e-6f);
    int e = lane * 2;
    float f0 = d0 * rs * fs[e] + fb[e];
    float f1 = d1 * rs * fs[e + 1] + fb[e + 1];
    out[128 + b * 128 + e] = f0;
    out[128 + b * 128 + e + 1] = f1;
    float p0 = f0 * fcw[e] + f1 * fcw[e + 1];
    float p1 = f0 * fcw[128 + e] + f1 * fcw[128 + e + 1];
#pragma unroll
    for (int m = 1; m < 64; m <<= 1) {
        p0 += __shfl_xor(p0, m);
        p1 += __shfl_xor(p1, m);
    }
    if (lane == 0) {
        out[b * 2 + 0] = p0 + fcb[0];
        out[b * 2 + 1] = p1 + fcb[1];
    }
}

extern "C" void kernel_launch(void* const* d_in, const int* in_sizes, int n_in,
                              void* d_out, int out_size, void* d_ws, size_t ws_size,
                              hipStream_t stream) {
    const float* feat    = (const float*)d_in[0];
    const float* conv_w  = (const float*)d_in[1];
    const float* conv_b  = (const float*)d_in[2];
    const float* pos_emb = (const float*)d_in[3];
    const float* cls_tok = (const float*)d_in[4];
    const float* ln1_s   = (const float*)d_in[5];
    const float* ln1_b   = (const float*)d_in[6];
    const float* qkv_w   = (const float*)d_in[7];
    const float* qkv_b   = (const float*)d_in[8];
    const float* proj_w  = (const float*)d_in[9];
    const float* proj_b  = (const float*)d_in[10];
    const float* ln2_s   = (const float*)d_in[11];
    const float* ln2_b   = (const float*)d_in[12];
    const float* ffn1_w  = (const float*)d_in[13];
    const float* ffn1_b  = (const float*)d_in[14];
    const float* ffn2_w  = (const float*)d_in[15];
    const float* ffn2_b  = (const float*)d_in[16];
    const float* fn_s    = (const float*)d_in[17];
    const float* fn_b    = (const float*)d_in[18];
    const float* fc_w    = (const float*)d_in[19];
    const float* fc_b    = (const float*)d_in[20];

    char* p = (char*)d_ws;
    auto alloc = [&](size_t bytes) { char* r = p; p += (bytes + 255) & ~(size_t)255; return r; };
    short* wq  = (short*)alloc((size_t)589824 * 2);
    short* wp  = (short*)alloc((size_t)196608 * 2);
    short* w1  = (short*)alloc((size_t)786432 * 2);
    short* w2  = (short*)alloc((size_t)786432 * 2);
    short* wc  = (short*)alloc((size_t)294912 * 2);
    float* X   = (float*)alloc((size_t)MP_ * 128 * 4);
    short* Qf  = (short*)alloc((size_t)64 * 16 * NP_ * 8 * 2);
    short* Kf  = (short*)alloc((size_t)64 * 16 * NP_ * 8 * 2);
    short* Vt  = (short*)alloc((size_t)64 * 4 * 32 * NP_ * 2);
    short* Of  = (short*)alloc((size_t)(MP_ / 16) * 2048 * 2);

    repack_all<<<10368, 256, 0, stream>>>(qkv_w, proj_w, ffn1_w, ffn2_w, conv_w, wq, wp, w1, w2, wc);
    conv_gemm<<<1024, 256, 0, stream>>>(feat, wc, conv_b, pos_emb, cls_tok, X);

    qkv0<<<544, 256, 0, stream>>>(X, wq, qkv_b, ln1_s, ln1_b, Qf, Kf, Vt);
    for (int l = 0; l < 12; ++l) {
        attn<<<1024, 256, 0, stream>>>(Qf, Kf, Vt, Of);
        if (l < 11)
            layer_tail<0><<<544, 256, 0, stream>>>(Of, wp + (size_t)l * 16384, proj_b + l * 128,
                                                   ln2_s + l * 128, ln2_b + l * 128,
                                                   w1 + (size_t)l * 65536, ffn1_b + l * 512,
                                                   w2 + (size_t)l * 65536, ffn2_b + l * 128, X,
                                                   ln1_s + (l + 1) * 128, ln1_b + (l + 1) * 128,
                                                   wq + (size_t)(l + 1) * 49152, qkv_b + (l + 1) * 384,
                                                   Qf, Kf, Vt);
        else
            layer_tail<1><<<544, 256, 0, stream>>>(Of, wp + (size_t)l * 16384, proj_b + l * 128,
                                                   ln2_s + l * 128, ln2_b + l * 128,
                                                   w1 + (size_t)l * 65536, ffn1_b + l * 512,
                                                   w2 + (size_t)l * 65536, ffn2_b + l * 128, X,
                                                   ln1_s, ln1_b, wq, qkv_b, Qf, Kf, Vt);
    }
    final_head<<<64, 64, 0, stream>>>(X, fn_s, fn_b, fc_w, fc_b, (float*)d_out);
}